// Round 5
// baseline (448.609 us; speedup 1.0000x reference)
//
#include <hip/hip_runtime.h>
#include <math.h>

#define NB 8
#define NC 128

typedef _Float16 hf8 __attribute__((ext_vector_type(8)));
typedef _Float16 hf4 __attribute__((ext_vector_type(4)));
typedef float fx4 __attribute__((ext_vector_type(4)));

// ---------------- LUT: lut[d2] = dw * (1/(sqrt(d2)+1e-6)) -------------------
__global__ void lut_kernel(float* __restrict__ lut, const float* __restrict__ dwp,
                           int n) {
  int i = blockIdx.x * 256 + threadIdx.x;
  if (i < n) {
    float r = 1.0f / (sqrtf((float)i) + 1e-6f);
    lut[i] = dwp[0] * r;
  }
}

// ---- prep: x (B,C,4096) -> xf1 (B,4096,128), nrm1, ext1 (B,4096,384 fp16) --
// ext row: a-token [hi | 2048*lo | hi], b-token [hi | hi | 2048*lo]
__global__ void prep_kernel(const float* __restrict__ x, float* __restrict__ xf,
                            float* __restrict__ nrm, _Float16* __restrict__ ext) {
  __shared__ float tile[64][129];
  __shared__ float part[64][4];
  __shared__ float rn_s[64];
  const int b = blockIdx.y;
  const int p0 = blockIdx.x * 64;
  const int tid = threadIdx.x;
  const int lane = tid & 63;
  const int q = tid >> 6;
  for (int cc = 0; cc < 32; ++cc) {
    int c = q * 32 + cc;
    tile[lane][c] = x[((size_t)(b * NC + c)) * 4096 + p0 + lane];
  }
  __syncthreads();
  float s = 0.f;
  for (int cc = 0; cc < 32; ++cc) {
    float v = tile[lane][q * 32 + cc];
    s += v * v;
  }
  part[lane][q] = s;
  __syncthreads();
  if (tid < 64) {
    float n = sqrtf(part[tid][0] + part[tid][1] + part[tid][2] + part[tid][3]);
    nrm[b * 4096 + p0 + tid] = n;
    rn_s[tid] = n;
  }
  __syncthreads();
  for (int it = 0; it < 8; ++it) {
    int idx = it * 256 + tid;
    int r = idx >> 5, e = (idx & 31) * 4;
    float4 v = make_float4(tile[r][e], tile[r][e + 1], tile[r][e + 2], tile[r][e + 3]);
    size_t o = (((size_t)b * 4096 + p0 + r) << 7) + e;
    *(float4*)&xf[o] = v;
    if (ext != nullptr) {
      float n = rn_s[r];
      float m0 = v.x / n, m1 = v.y / n, m2 = v.z / n, m3 = v.w / n;
      hf4 hi = {(_Float16)m0, (_Float16)m1, (_Float16)m2, (_Float16)m3};
      hf4 lo = {(_Float16)((m0 - (float)hi[0]) * 2048.0f),
                (_Float16)((m1 - (float)hi[1]) * 2048.0f),
                (_Float16)((m2 - (float)hi[2]) * 2048.0f),
                (_Float16)((m3 - (float)hi[3]) * 2048.0f)};
      int tok = p0 + r;
      _Float16* rw = ext + ((size_t)b * 4096 + tok) * 384;
      bool isA = tok < 2048;
      *(hf4*)&rw[e] = hi;
      *(hf4*)&rw[128 + e] = isA ? lo : hi;
      *(hf4*)&rw[256 + e] = isA ? hi : lo;
    }
  }
}

// -------- MFMA fp16x2 candidate kernel: top-2 per (row, 64-j chunk) ---------
// Block: 128 i x 256 j panel (4 jt chunks of 64). Waves 2x2: 64i x 32j each.
// Race-free: per-wave top-2 -> LDS -> 128-thread cross-wave merge -> pidx.
template <int WIDTH, int TT, int HH, int JBN>
__global__ __launch_bounds__(256, 2) void argmax_mfma_kernel(
    const _Float16* __restrict__ ext, const float* __restrict__ swp,
    const float* __restrict__ lut, int* __restrict__ pidx) {
  constexpr int W = JBN * 8;  // pidx row width = (JBN*4 chunks) * 2 ranks
  __shared__ _Float16 At[128][40];
  __shared__ _Float16 Bt[64][40];
  __shared__ int ico0[128], ico1[128];
  __shared__ int jco0[256], jco1[256];
  __shared__ float sval[128][2][2];
  __shared__ int sidx[128][2][2];

  const int b = blockIdx.z;
  const int it0 = blockIdx.x * 128;
  const int jb = blockIdx.y;
  const int j0g = jb * 256;
  const int tid = threadIdx.x;
  const int w = tid >> 6, l = tid & 63;
  const int wi0 = (w >> 1) * 64;  // row half: 0 / 64
  const int wh = w & 1;           // j half within 64-chunk
  const int wj0 = wh * 32;
  const int lg = l >> 4, lm = l & 15;
  const float sw = swp[0];
  const _Float16* extb = ext + (size_t)b * TT * 384;

  for (int t = tid; t < 128; t += 256) {
    int tok = it0 + t;
    ico0[t] = tok / WIDTH;
    ico1[t] = tok % WIDTH;
  }
  for (int t = tid; t < 256; t += 256) {
    int tok = HH + j0g + t;
    jco0[t] = tok / WIDTH;
    jco1[t] = tok % WIDTH;
  }

  for (int jt = 0; jt < 4; ++jt) {
    const int tokB0 = HH + j0g + jt * 64;
    fx4 acc_hh[4][2], acc_x[4][2];
#pragma unroll
    for (int i4 = 0; i4 < 4; ++i4)
#pragma unroll
      for (int j4 = 0; j4 < 2; ++j4) {
        acc_hh[i4][j4] = 0.f;
        acc_x[i4][j4] = 0.f;
      }

    for (int kc = 0; kc < 12; ++kc) {
      __syncthreads();  // protect LDS from previous chunk's readers
#pragma unroll
      for (int it2 = 0; it2 < 2; ++it2) {
        int idx = it2 * 256 + tid;
        int r = idx >> 2, qq = idx & 3;
        *(float4*)&At[r][qq * 8] =
            *(const float4*)&extb[(size_t)(it0 + r) * 384 + kc * 32 + qq * 8];
      }
      {
        int r = tid >> 2, qq = tid & 3;
        *(float4*)&Bt[r][qq * 8] =
            *(const float4*)&extb[(size_t)(tokB0 + r) * 384 + kc * 32 + qq * 8];
      }
      __syncthreads();
      hf8 af[4], bf[2];
#pragma unroll
      for (int s = 0; s < 4; ++s)
        af[s] = *(const hf8*)&At[wi0 + s * 16 + lm][lg * 8];
#pragma unroll
      for (int s = 0; s < 2; ++s)
        bf[s] = *(const hf8*)&Bt[wj0 + s * 16 + lm][lg * 8];
      if (kc < 4) {
#pragma unroll
        for (int j4 = 0; j4 < 2; ++j4)
#pragma unroll
          for (int i4 = 0; i4 < 4; ++i4)
            acc_hh[i4][j4] = __builtin_amdgcn_mfma_f32_16x16x32_f16(
                af[i4], bf[j4], acc_hh[i4][j4], 0, 0, 0);
      } else {
#pragma unroll
        for (int j4 = 0; j4 < 2; ++j4)
#pragma unroll
          for (int i4 = 0; i4 < 4; ++i4)
            acc_x[i4][j4] = __builtin_amdgcn_mfma_f32_16x16x32_f16(
                af[i4], bf[j4], acc_x[i4][j4], 0, 0, 0);
      }
    }

    // ---- per-wave epilogue: top-2 over this wave's 32 j's, per row ----
    // C/D layout (verified): col = lane&15, row = (lane>>4)*4 + reg.
#pragma unroll
    for (int m = 0; m < 16; ++m) {
      const int i4 = m >> 2, rg = m & 3;
      const int il = wi0 + i4 * 16 + lg * 4 + rg;
      const int ir = ico0[il], ic = ico1[il];
      float s0, s1;
      int g0, g1;
      {
        int jl = jt * 64 + wj0 + lm;  // j4 = 0
        int dr = ir - jco0[jl], dc = ic - jco1[jl];
        float sim = acc_hh[i4][0][rg] + 4.8828125e-4f * acc_x[i4][0][rg];
        s0 = sw * sim + lut[dr * dr + dc * dc];
        g0 = j0g + jl;
      }
      {
        int jl = jt * 64 + wj0 + 16 + lm;  // j4 = 1
        int dr = ir - jco0[jl], dc = ic - jco1[jl];
        float sim = acc_hh[i4][1][rg] + 4.8828125e-4f * acc_x[i4][1][rg];
        s1 = sw * sim + lut[dr * dr + dc * dc];
        g1 = j0g + jl;
      }
      float bv;
      int bj;
      if (s0 >= s1) { bv = s0; bj = g0; } else { bv = s1; bj = g1; }
#pragma unroll
      for (int r = 1; r < 16; r <<= 1) {
        float ov = __shfl_xor(bv, r, 16);
        int oj = __shfl_xor(bj, r, 16);
        if (ov > bv || (ov == bv && oj < bj)) { bv = ov; bj = oj; }
      }
      // per-lane best excluding winner (exclude by unique index)
      float b2 = -3.0e38f;
      int j2 = 0x7fffffff;
      if (g0 != bj) { b2 = s0; j2 = g0; }
      if (g1 != bj && (s1 > b2 || (s1 == b2 && g1 < j2))) { b2 = s1; j2 = g1; }
#pragma unroll
      for (int r = 1; r < 16; r <<= 1) {
        float ov = __shfl_xor(b2, r, 16);
        int oj = __shfl_xor(j2, r, 16);
        if (ov > b2 || (ov == b2 && oj < j2)) { b2 = ov; j2 = oj; }
      }
      if (lm == m) {
        sval[il][wh][0] = bv; sidx[il][wh][0] = bj;
        sval[il][wh][1] = b2; sidx[il][wh][1] = j2;
      }
    }
    __syncthreads();
    // ---- cross-wave (j-half) merge: one thread per row ----
    if (tid < 128) {
      float lv0 = sval[tid][0][0]; int lj0 = sidx[tid][0][0];
      float lv1 = sval[tid][0][1]; int lj1 = sidx[tid][0][1];
      float rv0 = sval[tid][1][0]; int rj0 = sidx[tid][1][0];
      float rv1 = sval[tid][1][1]; int rj1 = sidx[tid][1][1];
      int t1j, t2j;
      bool lwin = (lv0 > rv0) || (lv0 == rv0 && lj0 < rj0);
      if (lwin) {
        t1j = lj0;
        bool s2 = (lv1 > rv0) || (lv1 == rv0 && lj1 < rj0);
        t2j = s2 ? lj1 : rj0;
      } else {
        t1j = rj0;
        bool s2 = (rv1 > lv0) || (rv1 == lv0 && rj1 < lj0);
        t2j = s2 ? rj1 : lj0;
      }
      size_t row = (size_t)b * HH + it0 + tid;
      int cb = jb * 4 + jt;
      pidx[row * W + cb * 2 + 0] = t1j;
      pidx[row * W + cb * 2 + 1] = t2j;
    }
  }
}

// ------ exact fp32 refinement over candidates: dst = first-argmax -----------
template <int WIDTH, int TT, int HH, int NCAND>
__global__ __launch_bounds__(256) void refine_kernel(
    const float* __restrict__ xf, const float* __restrict__ nrm,
    const int* __restrict__ pidx, const float* __restrict__ swp,
    const float* __restrict__ lut, int* __restrict__ dst) {
  const int rowl = blockIdx.x * 4 + (threadIdx.x >> 6);
  const int lane = threadIdx.x & 63;
  const int half = lane >> 5, ln = lane & 31;
  const int b = rowl / HH, i = rowl - b * HH;
  const float sw = swp[0];
  const float na = nrm[b * TT + i];
  float4 a4 = *(const float4*)&xf[((size_t)b * TT + i) * NC + ln * 4];
  a4.x /= na; a4.y /= na; a4.z /= na; a4.w /= na;
  const int ir = i / WIDTH, ic = i % WIDTH;
  const int* cand = pidx + (size_t)rowl * NCAND;
  float bv = -3.0e38f;
  int bj = 0x7fffffff;
  for (int c = 0; c < NCAND; c += 2) {
    int j = cand[c + half];
    float4 b4 = *(const float4*)&xf[((size_t)b * TT + HH + j) * NC + ln * 4];
    float p = a4.x * b4.x + a4.y * b4.y + a4.z * b4.z + a4.w * b4.w;
#pragma unroll
    for (int off = 1; off < 32; off <<= 1) p += __shfl_xor(p, off, 32);
    float nb = nrm[b * TT + HH + j];
    int tj = HH + j;
    int jr = tj / WIDTH;
    int dr = ir - jr, dc = ic - (tj - jr * WIDTH);
    float sc = sw * (p / nb) + lut[dr * dr + dc * dc];
    if (sc > bv || (sc == bv && j < bj)) { bv = sc; bj = j; }
  }
  {  // merge the two half-wave streams
    float ov = __shfl_xor(bv, 32, 64);
    int oj = __shfl_xor(bj, 32, 64);
    if (ov > bv || (ov == bv && oj < bj)) { bv = ov; bj = oj; }
  }
  if (lane == 0) dst[rowl] = bj;
}

// ---------------- FALLBACK fp32 path (round-1 structure) --------------------
template <int WIDTH, int TT, int HH, int IT, int JC>
__global__ __launch_bounds__(256, 4) void argmax2_kernel(
    const float* __restrict__ xf, const float* __restrict__ nrm,
    const float* __restrict__ swp, const float* __restrict__ lut,
    float* __restrict__ pval, int* __restrict__ pidx) {
  constexpr int MI = IT / 16;
  constexpr int NTILE = JC / 128;
  __shared__ float At[32][IT + 4];
  __shared__ float Bt[32][132];
  __shared__ int ico[2][IT];
  __shared__ int jco[2][JC];

  const int b = blockIdx.z;
  const int it0 = blockIdx.x * IT;
  const int jb = blockIdx.y;
  const int j0g = jb * JC;
  const int tid = threadIdx.x;

  for (int t = tid; t < IT; t += 256) {
    int tok = it0 + t;
    ico[0][t] = tok / WIDTH;
    ico[1][t] = tok % WIDTH;
  }
  for (int t = tid; t < JC; t += 256) {
    int tok = HH + j0g + t;
    jco[0][t] = tok / WIDTH;
    jco[1][t] = tok % WIDTH;
  }
  const float sw = swp[0];
  const float* srcb = xf + (size_t)b * TT * NC;

  const int ty = tid >> 4, tx = tid & 15;
  const int i0l = ty * MI;
  const int j0l = tx * 8;

  float best[MI];
  int bidx[MI];
#pragma unroll
  for (int ii = 0; ii < MI; ++ii) { best[ii] = -1e30f; bidx[ii] = 0; }

  for (int jt = 0; jt < NTILE; ++jt) {
    float acc[MI][8];
#pragma unroll
    for (int ii = 0; ii < MI; ++ii)
#pragma unroll
      for (int jj = 0; jj < 8; ++jj) acc[ii][jj] = 0.f;

    for (int kc = 0; kc < 4; ++kc) {
      __syncthreads();
#pragma unroll
      for (int p = 0; p < IT / 32; ++p) {
        int f = p * 256 + tid;
        int r = f >> 3, kq = (f & 7) * 4;
        const float* row = srcb + (size_t)(it0 + r) * NC + kc * 32 + kq;
        float4 v = *(const float4*)row;
        float n = nrm[b * TT + it0 + r];
        v.x /= n; v.y /= n; v.z /= n; v.w /= n;
        At[kq + 0][r] = v.x; At[kq + 1][r] = v.y;
        At[kq + 2][r] = v.z; At[kq + 3][r] = v.w;
      }
#pragma unroll
      for (int p = 0; p < 4; ++p) {
        int f = p * 256 + tid;
        int r = f >> 3, kq = (f & 7) * 4;
        int tok = HH + j0g + jt * 128 + r;
        const float* row = srcb + (size_t)tok * NC + kc * 32 + kq;
        float4 v = *(const float4*)row;
        float n = nrm[b * TT + tok];
        v.x /= n; v.y /= n; v.z /= n; v.w /= n;
        Bt[kq + 0][r] = v.x; Bt[kq + 1][r] = v.y;
        Bt[kq + 2][r] = v.z; Bt[kq + 3][r] = v.w;
      }
      __syncthreads();

#pragma unroll 4
      for (int k = 0; k < 32; ++k) {
        float a[MI], bb[8];
#pragma unroll
        for (int qv = 0; qv < MI / 4; ++qv)
          *(float4*)&a[qv * 4] = *(const float4*)&At[k][i0l + qv * 4];
        *(float4*)&bb[0] = *(const float4*)&Bt[k][j0l];
        *(float4*)&bb[4] = *(const float4*)&Bt[k][j0l + 4];
#pragma unroll
        for (int ii = 0; ii < MI; ++ii)
#pragma unroll
          for (int jj = 0; jj < 8; ++jj) acc[ii][jj] += a[ii] * bb[jj];
      }
    }

#pragma unroll
    for (int ii = 0; ii < MI; ++ii) {
      int ir = ico[0][i0l + ii], ic = ico[1][i0l + ii];
#pragma unroll
      for (int jj = 0; jj < 8; ++jj) {
        int jl = jt * 128 + j0l + jj;
        int dr = ir - jco[0][jl];
        int dc = ic - jco[1][jl];
        float sc = sw * acc[ii][jj] + lut[dr * dr + dc * dc];
        if (sc > best[ii]) {
          best[ii] = sc;
          bidx[ii] = j0g + jl;
        }
      }
    }
  }

  __syncthreads();
  float* rv = &At[0][0];
  int* rj = (int*)&Bt[0][0];
#pragma unroll
  for (int ii = 0; ii < MI; ++ii) {
    rv[(i0l + ii) * 17 + tx] = best[ii];
    rj[(i0l + ii) * 17 + tx] = bidx[ii];
  }
  __syncthreads();
  if (tid < IT) {
    float bv = rv[tid * 17];
    int bj = rj[tid * 17];
    for (int t = 1; t < 16; ++t) {
      float v = rv[tid * 17 + t];
      int j = rj[tid * 17 + t];
      if (v > bv || (v == bv && j < bj)) { bv = v; bj = j; }
    }
    int row = b * HH + it0 + tid;
    pval[(size_t)row * 8 + jb] = bv;
    pidx[(size_t)row * 8 + jb] = bj;
  }
}

__global__ void argreduce_kernel(const float* __restrict__ pv,
                                 const int* __restrict__ pj,
                                 int* __restrict__ dst, int nrows, int w) {
  int r = blockIdx.x * 256 + threadIdx.x;
  if (r >= nrows) return;
  const float* vv = pv + (size_t)r * w;
  const int* jj = pj + (size_t)r * w;
  float bv = vv[0];
  int bj = jj[0];
  for (int t = 1; t < w; ++t) {
    float v = vv[t];
    int j = jj[t];
    if (v > bv || (v == bv && j < bj)) { bv = v; bj = j; }
  }
  dst[r] = bj;
}

// -------- merge: out = b-half copy, then atomic scatter of a rows, divide ---
__global__ void copy_init_kernel(const float* __restrict__ src,
                                 float* __restrict__ dstbuf,
                                 float* __restrict__ cnt, int HH, int TT) {
  size_t idx = (size_t)blockIdx.x * 256 + threadIdx.x;
  size_t total = (size_t)NB * HH * 32;
  if (idx >= total) return;
  size_t row = idx >> 5;
  int e = (int)(idx & 31) * 4;
  int b = (int)(row / HH), j = (int)(row % HH);
  float4 v = *(const float4*)&src[((size_t)b * TT + HH + j) * NC + e];
  *(float4*)&dstbuf[row * NC + e] = v;
  if (e == 0) cnt[row] = 1.0f;
}

__global__ void scatter_kernel(const float* __restrict__ src,
                               const int* __restrict__ dst,
                               float* __restrict__ accbuf,
                               float* __restrict__ cnt, int HH, int TT) {
  size_t idx = (size_t)blockIdx.x * 256 + threadIdx.x;
  size_t total = (size_t)NB * HH * 32;
  if (idx >= total) return;
  size_t row = idx >> 5;
  int e = (int)(idx & 31) * 4;
  int b = (int)(row / HH), i = (int)(row % HH);
  float4 v = *(const float4*)&src[((size_t)b * TT + i) * NC + e];
  int d = dst[row];
  float* base = &accbuf[((size_t)b * HH + d) * NC + e];
  atomicAdd(base + 0, v.x);
  atomicAdd(base + 1, v.y);
  atomicAdd(base + 2, v.z);
  atomicAdd(base + 3, v.w);
  if (e == 0) atomicAdd(&cnt[(size_t)b * HH + d], 1.0f);
}

// finalize: divide by counts; optionally emit nrm + ext rows for next merge --
__global__ void finalize_kernel(float* __restrict__ buf,
                                const float* __restrict__ cnt,
                                float* __restrict__ nrm,
                                _Float16* __restrict__ ext, int HH2) {
  int row = blockIdx.x * 2 + (threadIdx.x >> 7);
  int c = threadIdx.x & 127;
  float v = buf[(size_t)row * NC + c] / cnt[row];
  buf[(size_t)row * NC + c] = v;
  if (nrm != nullptr) {  // uniform branch
    float s = v * v;
    for (int off = 32; off > 0; off >>= 1) s += __shfl_down(s, off, 64);
    __shared__ float p[4];
    __shared__ float ns[2];
    int w = threadIdx.x >> 6;
    if ((threadIdx.x & 63) == 0) p[w] = s;
    __syncthreads();
    if ((threadIdx.x & 127) == 0) {
      float n = sqrtf(p[w] + p[w + 1]);
      nrm[row] = n;
      ns[threadIdx.x >> 7] = n;
    }
    __syncthreads();
    if (ext != nullptr) {
      float n = ns[threadIdx.x >> 7];
      float m = v / n;
      _Float16 hi = (_Float16)m;
      _Float16 lo = (_Float16)((m - (float)hi) * 2048.0f);
      int t = row & (2 * HH2 - 1);  // tokens/batch is pow2
      bool isA = t < HH2;
      _Float16* rw = ext + (size_t)row * 384;
      rw[c] = hi;
      rw[128 + c] = isA ? lo : hi;
      rw[256 + c] = isA ? hi : lo;
    }
  }
}

// ---------------- 1x1 conv (128x128) + BN + SiLU -> out (B,128,32,32) -------
__global__ __launch_bounds__(256) void conv_bn_silu_kernel(
    const float* __restrict__ xf3, const float* __restrict__ w,
    const float* __restrict__ gamma, const float* __restrict__ beta,
    const float* __restrict__ mean, const float* __restrict__ var,
    float* __restrict__ out) {
  __shared__ float X[64][132];
  __shared__ float Wt[128][68];
  const int b = blockIdx.y, p0 = blockIdx.x * 64;
  const int tid = threadIdx.x, lane = tid & 63, q = tid >> 6;
  {
    const float* row = xf3 + ((size_t)b * 1024 + p0 + lane) * NC;
    for (int cc = 0; cc < 8; ++cc) {
      int c = q * 32 + cc * 4;
      *(float4*)&X[lane][c] = *(const float4*)&row[c];
    }
  }
  const int ti = tid >> 4, tj = tid & 15;
  const int i4 = ti * 4, j4 = tj * 4;
  for (int ot = 0; ot < 2; ++ot) {
    __syncthreads();
    {
      const float* row = w + (size_t)(ot * 64 + lane) * NC;
      for (int cc = 0; cc < 8; ++cc) {
        int c = q * 32 + cc * 4;
        float4 v = *(const float4*)&row[c];
        Wt[c + 0][lane] = v.x;
        Wt[c + 1][lane] = v.y;
        Wt[c + 2][lane] = v.z;
        Wt[c + 3][lane] = v.w;
      }
    }
    __syncthreads();
    float acc[4][4];
#pragma unroll
    for (int ii = 0; ii < 4; ++ii)
#pragma unroll
      for (int jj = 0; jj < 4; ++jj) acc[ii][jj] = 0.f;

    for (int k = 0; k < NC; k += 4) {
      float4 a0 = *(const float4*)&X[i4 + 0][k];
      float4 a1 = *(const float4*)&X[i4 + 1][k];
      float4 a2 = *(const float4*)&X[i4 + 2][k];
      float4 a3 = *(const float4*)&X[i4 + 3][k];
      float4 b0 = *(const float4*)&Wt[k + 0][j4];
      float4 b1 = *(const float4*)&Wt[k + 1][j4];
      float4 b2 = *(const float4*)&Wt[k + 2][j4];
      float4 b3 = *(const float4*)&Wt[k + 3][j4];
#define FMA16(AX, BV)                                                     \
  acc[0][0] += a0.AX * BV.x; acc[0][1] += a0.AX * BV.y;                   \
  acc[0][2] += a0.AX * BV.z; acc[0][3] += a0.AX * BV.w;                   \
  acc[1][0] += a1.AX * BV.x; acc[1][1] += a1.AX * BV.y;                   \
  acc[1][2] += a1.AX * BV.z; acc[1][3] += a1.AX * BV.w;                   \
  acc[2][0] += a2.AX * BV.x; acc[2][1] += a2.AX * BV.y;                   \
  acc[2][2] += a2.AX * BV.z; acc[2][3] += a2.AX * BV.w;                   \
  acc[3][0] += a3.AX * BV.x; acc[3][1] += a3.AX * BV.y;                   \
  acc[3][2] += a3.AX * BV.z; acc[3][3] += a3.AX * BV.w;
      FMA16(x, b0)
      FMA16(y, b1)
      FMA16(z, b2)
      FMA16(w, b3)
#undef FMA16
    }

#pragma unroll
    for (int jj = 0; jj < 4; ++jj) {
      int o = ot * 64 + j4 + jj;
      float sc = gamma[o] / sqrtf(var[o] + 1e-5f);
      float mn = mean[o], bt = beta[o];
      float4 r;
      float z;
      z = (acc[0][jj] - mn) * sc + bt; r.x = z / (1.f + expf(-z));
      z = (acc[1][jj] - mn) * sc + bt; r.y = z / (1.f + expf(-z));
      z = (acc[2][jj] - mn) * sc + bt; r.z = z / (1.f + expf(-z));
      z = (acc[3][jj] - mn) * sc + bt; r.w = z / (1.f + expf(-z));
      *(float4*)&out[((size_t)(b * NC + o)) * 1024 + p0 + i4] = r;
    }
  }
}

extern "C" void kernel_launch(void* const* d_in, const int* in_sizes, int n_in,
                              void* d_out, int out_size, void* d_ws,
                              size_t ws_size, hipStream_t stream) {
  const float* x = (const float*)d_in[0];
  const float* swp = (const float*)d_in[1];
  const float* dwp = (const float*)d_in[2];
  const float* convw = (const float*)d_in[3];
  const float* gamma = (const float*)d_in[4];
  const float* beta = (const float*)d_in[5];
  const float* mean = (const float*)d_in[6];
  const float* var = (const float*)d_in[7];
  float* out = (float*)d_out;

  float* ws = (float*)d_ws;
  size_t o = 0;
  float* xf1 = ws + o;  o += (size_t)8 * 4096 * 128;   // also reused as xf3
  float* nrm1 = ws + o; o += 8 * 4096;
  float* xf2 = ws + o;  o += (size_t)8 * 2048 * 128;
  float* nrm2 = ws + o; o += 8 * 2048;
  float* cnt1 = ws + o; o += 8 * 2048;
  float* cnt2 = ws + o; o += 8 * 1024;
  int* dst1 = (int*)(ws + o); o += 8 * 2048;
  int* dst2 = (int*)(ws + o); o += 8 * 1024;
  float* pv1 = ws + o;  o += (size_t)8 * 2048 * 8;     // fallback only
  int* pj1 = (int*)(ws + o); o += (size_t)8 * 2048 * 64;
  float* pv2 = ws + o;  o += (size_t)8 * 1024 * 8;     // fallback only
  int* pj2 = (int*)(ws + o); o += (size_t)8 * 1024 * 32;
  float* lut = ws + o;  o += 8192;
  _Float16* ext1 = (_Float16*)(ws + o);
  _Float16* ext2 = ext1;  // ext1 dead after merge-1 candidates
  const size_t ext_floats = (size_t)8 * 4096 * 384 / 2;
  const bool mfma_ok = ws_size >= (o + ext_floats) * sizeof(float);
  float* xf3 = xf1;  // alias: xf1 dead before xf3 is written

  lut_kernel<<<32, 256, 0, stream>>>(lut, dwp, 7939);

  // ---- merge 1: T=4096, H=2048, width=64 ----
  prep_kernel<<<dim3(64, 8), 256, 0, stream>>>(x, xf1, nrm1,
                                               mfma_ok ? ext1 : nullptr);
  if (mfma_ok) {
    argmax_mfma_kernel<64, 4096, 2048, 8>
        <<<dim3(16, 8, 8), 256, 0, stream>>>(ext1, swp, lut, pj1);
    refine_kernel<64, 4096, 2048, 64>
        <<<4096, 256, 0, stream>>>(xf1, nrm1, pj1, swp, lut, dst1);
  } else {
    argmax2_kernel<64, 4096, 2048, 128, 256>
        <<<dim3(16, 8, 8), 256, 0, stream>>>(xf1, nrm1, swp, lut, pv1, pj1);
    argreduce_kernel<<<64, 256, 0, stream>>>(pv1, pj1, dst1, 8 * 2048, 8);
  }
  copy_init_kernel<<<2048, 256, 0, stream>>>(xf1, xf2, cnt1, 2048, 4096);
  scatter_kernel<<<2048, 256, 0, stream>>>(xf1, dst1, xf2, cnt1, 2048, 4096);
  finalize_kernel<<<8192, 256, 0, stream>>>(xf2, cnt1, nrm2,
                                            mfma_ok ? ext2 : nullptr, 1024);

  // ---- merge 2: T=2048, H=1024, width=int(sqrt(2048))=45 ----
  if (mfma_ok) {
    argmax_mfma_kernel<45, 2048, 1024, 4>
        <<<dim3(8, 4, 8), 256, 0, stream>>>(ext2, swp, lut, pj2);
    refine_kernel<45, 2048, 1024, 32>
        <<<2048, 256, 0, stream>>>(xf2, nrm2, pj2, swp, lut, dst2);
  } else {
    argmax2_kernel<45, 2048, 1024, 64, 128>
        <<<dim3(16, 8, 8), 256, 0, stream>>>(xf2, nrm2, swp, lut, pv2, pj2);
    argreduce_kernel<<<32, 256, 0, stream>>>(pv2, pj2, dst2, 8 * 1024, 8);
  }
  copy_init_kernel<<<1024, 256, 0, stream>>>(xf2, xf3, cnt2, 1024, 2048);
  scatter_kernel<<<1024, 256, 0, stream>>>(xf2, dst2, xf3, cnt2, 1024, 2048);
  finalize_kernel<<<4096, 256, 0, stream>>>(xf3, cnt2, nullptr, nullptr, 512);

  // ---- 1x1 conv + BN + SiLU ----
  conv_bn_silu_kernel<<<dim3(16, 8), 256, 0, stream>>>(
      xf3, convw, gamma, beta, mean, var, out);
}

// Round 6
// 234.542 us; speedup vs baseline: 1.9127x; 1.9127x over previous
//
#include <hip/hip_runtime.h>
#include <math.h>

#define NB 8
#define NC 128

typedef _Float16 hf8 __attribute__((ext_vector_type(8)));
typedef float fx4 __attribute__((ext_vector_type(4)));

// ---------------- LUT: lut[d2] = dw * (1/(sqrt(d2)+1e-6)) -------------------
__global__ void lut_kernel(float* __restrict__ lut, const float* __restrict__ dwp,
                           int n) {
  int i = blockIdx.x * 256 + threadIdx.x;
  if (i < n) {
    float r = 1.0f / (sqrtf((float)i) + 1e-6f);
    lut[i] = dwp[0] * r;
  }
}

// ---- prep: x (B,C,4096) -> xf1, nrm1, ext1 (B,4096,384 fp16, p=128 enc) ----
// a-token row: [h | 128e | h/128]   b-token row: [h | h/128 | 128e]
__global__ void prep_kernel(const float* __restrict__ x, float* __restrict__ xf,
                            float* __restrict__ nrm, _Float16* __restrict__ ext) {
  __shared__ float tile[64][129];
  __shared__ float part[64][4];
  __shared__ float rn_s[64];
  const int b = blockIdx.y;
  const int p0 = blockIdx.x * 64;
  const int tid = threadIdx.x;
  const int lane = tid & 63;
  const int q = tid >> 6;
  for (int cc = 0; cc < 32; ++cc) {
    int c = q * 32 + cc;
    tile[lane][c] = x[((size_t)(b * NC + c)) * 4096 + p0 + lane];
  }
  __syncthreads();
  float s = 0.f;
  for (int cc = 0; cc < 32; ++cc) {
    float v = tile[lane][q * 32 + cc];
    s += v * v;
  }
  part[lane][q] = s;
  __syncthreads();
  if (tid < 64) {
    float n = sqrtf(part[tid][0] + part[tid][1] + part[tid][2] + part[tid][3]);
    nrm[b * 4096 + p0 + tid] = n;
    rn_s[tid] = n;
  }
  __syncthreads();
  for (int it = 0; it < 8; ++it) {
    int idx = it * 256 + tid;
    int r = idx >> 5, e = (idx & 31) * 4;
    float4 v = make_float4(tile[r][e], tile[r][e + 1], tile[r][e + 2], tile[r][e + 3]);
    size_t o = (((size_t)b * 4096 + p0 + r) << 7) + e;
    *(float4*)&xf[o] = v;
    if (ext != nullptr) {
      float n = rn_s[r];
      int tok = p0 + r;
      bool isA = tok < 2048;
      _Float16* rw = ext + ((size_t)b * 4096 + tok) * 384;
      float mm[4] = {v.x / n, v.y / n, v.z / n, v.w / n};
#pragma unroll
      for (int u = 0; u < 4; ++u) {
        float m = mm[u];
        _Float16 h = (_Float16)m;
        float hf = (float)h;
        _Float16 ep = (_Float16)((m - hf) * 128.0f);
        _Float16 hs = (_Float16)(hf * 0.0078125f);
        rw[e + u] = h;
        rw[128 + e + u] = isA ? ep : hs;
        rw[256 + e + u] = isA ? hs : ep;
      }
    }
  }
}

// ------ MFMA candidate kernel: B-stationary LDS, A global->reg, no barriers -
// Block: 4 waves, each wave = 64i x 64j tile, K=384 single-acc p=128 encoding.
// Emits packed u64 top-2 per (row, 64-j chunk).
template <int WIDTH, int TT, int HH>
__global__ __launch_bounds__(256, 3) void argmax_mfma2_kernel(
    const _Float16* __restrict__ ext, const float* __restrict__ swp,
    const float* __restrict__ dwp, unsigned long long* __restrict__ pu) {
  __shared__ _Float16 Bt[64][392];  // 50176 B; reused as reduce buffer
  const int b = blockIdx.z;
  const int ib = blockIdx.x;
  const int jb = blockIdx.y;
  const int tid = threadIdx.x;
  const int w = tid >> 6, l = tid & 63;
  const int lg = l >> 4, lm = l & 15;
  const int ipan = ib * 256 + w * 64;
  const int j0 = jb * 64;
  const float sw = swp[0], dwv = dwp[0];
  const _Float16* extb = ext + (size_t)b * TT * 384;
  const _Float16* brow0 = extb + (size_t)(HH + j0) * 384;

  // stage B tile once: 64 rows x 384 halfs
  for (int f = tid; f < 64 * 48; f += 256) {
    int r = f / 48, c = f % 48;
    *(float4*)&Bt[r][c * 8] = *(const float4*)&brow0[(size_t)r * 384 + c * 8];
  }
  __syncthreads();

  fx4 acc[4][4];
#pragma unroll
  for (int i4 = 0; i4 < 4; ++i4)
#pragma unroll
    for (int j4 = 0; j4 < 4; ++j4) acc[i4][j4] = 0.f;

  const _Float16* ap0 = extb + (size_t)(ipan + 0 * 16 + lm) * 384 + lg * 8;
  const _Float16* ap1 = extb + (size_t)(ipan + 1 * 16 + lm) * 384 + lg * 8;
  const _Float16* ap2 = extb + (size_t)(ipan + 2 * 16 + lm) * 384 + lg * 8;
  const _Float16* ap3 = extb + (size_t)(ipan + 3 * 16 + lm) * 384 + lg * 8;
  const _Float16* bp0 = &Bt[0 * 16 + lm][lg * 8];
  const _Float16* bp1 = &Bt[1 * 16 + lm][lg * 8];
  const _Float16* bp2 = &Bt[2 * 16 + lm][lg * 8];
  const _Float16* bp3 = &Bt[3 * 16 + lm][lg * 8];

#pragma unroll
  for (int kc = 0; kc < 12; ++kc) {
    hf8 af[4], bf[4];
    af[0] = *(const hf8*)(ap0 + kc * 32);
    af[1] = *(const hf8*)(ap1 + kc * 32);
    af[2] = *(const hf8*)(ap2 + kc * 32);
    af[3] = *(const hf8*)(ap3 + kc * 32);
    bf[0] = *(const hf8*)(bp0 + kc * 32);
    bf[1] = *(const hf8*)(bp1 + kc * 32);
    bf[2] = *(const hf8*)(bp2 + kc * 32);
    bf[3] = *(const hf8*)(bp3 + kc * 32);
#pragma unroll
    for (int j4 = 0; j4 < 4; ++j4)
#pragma unroll
      for (int i4 = 0; i4 < 4; ++i4)
        acc[i4][j4] = __builtin_amdgcn_mfma_f32_16x16x32_f16(
            af[i4], bf[j4], acc[i4][j4], 0, 0, 0);
  }

  // ---- epilogue: per-lane first-max over its 4 cols, per row ----
  // C/D layout: row = lg*4 + reg (+i4*16), col = lm (+j4*16).
  int jr4[4], jc4[4];
#pragma unroll
  for (int j4 = 0; j4 < 4; ++j4) {
    int tj = HH + j0 + j4 * 16 + lm;
    jr4[j4] = tj / WIDTH;
    jc4[j4] = tj % WIDTH;
  }
  unsigned long long myred[16];
#pragma unroll
  for (int i4 = 0; i4 < 4; ++i4) {
#pragma unroll
    for (int rg = 0; rg < 4; ++rg) {
      int ti = ipan + i4 * 16 + lg * 4 + rg;
      int ir = ti / WIDTH, ic = ti % WIDTH;
      float bv = -1e30f;
      int bj = 0;
#pragma unroll
      for (int j4 = 0; j4 < 4; ++j4) {  // ascending j -> first-max kept
        int dr = ir - jr4[j4], dc = ic - jc4[j4];
        float d2 = (float)(dr * dr + dc * dc);
        float sc = sw * acc[i4][j4][rg] +
                   dwv * __builtin_amdgcn_rcpf(sqrtf(d2) + 1e-6f);
        int gj = j0 + j4 * 16 + lm;
        if (sc > bv) { bv = sc; bj = gj; }
      }
      myred[i4 * 4 + rg] =
          ((unsigned long long)__float_as_uint(bv + 1.0f) << 32) |
          (unsigned)(~(unsigned)bj);
    }
  }
  __syncthreads();  // all waves done reading Bt -> reuse as reduce buffer
  unsigned long long* rwv = (unsigned long long*)&Bt[0][0] + (size_t)w * 64 * 17;
#pragma unroll
  for (int m = 0; m < 16; ++m) {
    int il = (m >> 2) * 16 + lg * 4 + (m & 3);
    rwv[il * 17 + lm] = myred[m];
  }
  __syncthreads();
  // lane l owns row l: top-2 over 16 lane-maxima (u64 packed order)
  unsigned long long t1 = 0ull, t2 = 0ull;
#pragma unroll
  for (int c = 0; c < 16; ++c) {
    unsigned long long u = rwv[l * 17 + c];
    if (u > t1) { t2 = t1; t1 = u; }
    else if (u > t2) { t2 = u; }
  }
  size_t row = (size_t)b * HH + ipan + l;
  pu[row * (HH / 32) + jb * 2 + 0] = t1;
  pu[row * (HH / 32) + jb * 2 + 1] = t2;
}

// --------- top-4 over per-chunk packed candidates (wave per row) ------------
__global__ void topk4_kernel(const unsigned long long* __restrict__ pu,
                             int* __restrict__ cand, int nrows, int nch2) {
  int row = blockIdx.x * 4 + (threadIdx.x >> 6);
  int lane = threadIdx.x & 63;
  if (row >= nrows) return;
  unsigned long long v = (lane < nch2) ? pu[(size_t)row * nch2 + lane] : 0ull;
  for (int t = 0; t < 4; ++t) {
    unsigned long long m = v;
#pragma unroll
    for (int off = 1; off < 64; off <<= 1) {
      unsigned long long o = __shfl_xor(m, off, 64);
      if (o > m) m = o;
    }
    if (lane == t) cand[row * 4 + t] = (int)(~(unsigned)(m & 0xFFFFFFFFull));
    if (v == m) v = 0ull;  // packed u64 unique per j -> exact removal
  }
}

// ------ exact fp32 refinement over candidates: dst = first-argmax -----------
template <int WIDTH, int TT, int HH, int NCAND>
__global__ __launch_bounds__(256) void refine_kernel(
    const float* __restrict__ xf, const float* __restrict__ nrm,
    const int* __restrict__ pidx, const float* __restrict__ swp,
    const float* __restrict__ lut, int* __restrict__ dst) {
  const int rowl = blockIdx.x * 4 + (threadIdx.x >> 6);
  const int lane = threadIdx.x & 63;
  const int half = lane >> 5, ln = lane & 31;
  const int b = rowl / HH, i = rowl - b * HH;
  const float sw = swp[0];
  const float na = nrm[b * TT + i];
  float4 a4 = *(const float4*)&xf[((size_t)b * TT + i) * NC + ln * 4];
  a4.x /= na; a4.y /= na; a4.z /= na; a4.w /= na;
  const int ir = i / WIDTH, ic = i % WIDTH;
  const int* cand = pidx + (size_t)rowl * NCAND;
  float bv = -3.0e38f;
  int bj = 0x7fffffff;
  for (int c = 0; c < NCAND; c += 2) {
    int j = cand[c + half];
    float4 b4 = *(const float4*)&xf[((size_t)b * TT + HH + j) * NC + ln * 4];
    float p = a4.x * b4.x + a4.y * b4.y + a4.z * b4.z + a4.w * b4.w;
#pragma unroll
    for (int off = 1; off < 32; off <<= 1) p += __shfl_xor(p, off, 32);
    float nb = nrm[b * TT + HH + j];
    int tj = HH + j;
    int jr = tj / WIDTH;
    int dr = ir - jr, dc = ic - (tj - jr * WIDTH);
    float sc = sw * (p / nb) + lut[dr * dr + dc * dc];
    if (sc > bv || (sc == bv && j < bj)) { bv = sc; bj = j; }
  }
  {
    float ov = __shfl_xor(bv, 32, 64);
    int oj = __shfl_xor(bj, 32, 64);
    if (ov > bv || (ov == bv && oj < bj)) { bv = ov; bj = oj; }
  }
  if (lane == 0) dst[rowl] = bj;
}

// ---------------- FALLBACK fp32 path (round-1 structure, proven) ------------
template <int WIDTH, int TT, int HH, int IT, int JC>
__global__ __launch_bounds__(256, 4) void argmax2_kernel(
    const float* __restrict__ xf, const float* __restrict__ nrm,
    const float* __restrict__ swp, const float* __restrict__ lut,
    float* __restrict__ pval, int* __restrict__ pidx) {
  constexpr int MI = IT / 16;
  constexpr int NTILE = JC / 128;
  __shared__ float At[32][IT + 4];
  __shared__ float Bt[32][132];
  __shared__ int ico[2][IT];
  __shared__ int jco[2][JC];

  const int b = blockIdx.z;
  const int it0 = blockIdx.x * IT;
  const int jb = blockIdx.y;
  const int j0g = jb * JC;
  const int tid = threadIdx.x;

  for (int t = tid; t < IT; t += 256) {
    int tok = it0 + t;
    ico[0][t] = tok / WIDTH;
    ico[1][t] = tok % WIDTH;
  }
  for (int t = tid; t < JC; t += 256) {
    int tok = HH + j0g + t;
    jco[0][t] = tok / WIDTH;
    jco[1][t] = tok % WIDTH;
  }
  const float sw = swp[0];
  const float* srcb = xf + (size_t)b * TT * NC;

  const int ty = tid >> 4, tx = tid & 15;
  const int i0l = ty * MI;
  const int j0l = tx * 8;

  float best[MI];
  int bidx[MI];
#pragma unroll
  for (int ii = 0; ii < MI; ++ii) { best[ii] = -1e30f; bidx[ii] = 0; }

  for (int jt = 0; jt < NTILE; ++jt) {
    float acc[MI][8];
#pragma unroll
    for (int ii = 0; ii < MI; ++ii)
#pragma unroll
      for (int jj = 0; jj < 8; ++jj) acc[ii][jj] = 0.f;

    for (int kc = 0; kc < 4; ++kc) {
      __syncthreads();
#pragma unroll
      for (int p = 0; p < IT / 32; ++p) {
        int f = p * 256 + tid;
        int r = f >> 3, kq = (f & 7) * 4;
        const float* row = srcb + (size_t)(it0 + r) * NC + kc * 32 + kq;
        float4 v = *(const float4*)row;
        float n = nrm[b * TT + it0 + r];
        v.x /= n; v.y /= n; v.z /= n; v.w /= n;
        At[kq + 0][r] = v.x; At[kq + 1][r] = v.y;
        At[kq + 2][r] = v.z; At[kq + 3][r] = v.w;
      }
#pragma unroll
      for (int p = 0; p < 4; ++p) {
        int f = p * 256 + tid;
        int r = f >> 3, kq = (f & 7) * 4;
        int tok = HH + j0g + jt * 128 + r;
        const float* row = srcb + (size_t)tok * NC + kc * 32 + kq;
        float4 v = *(const float4*)row;
        float n = nrm[b * TT + tok];
        v.x /= n; v.y /= n; v.z /= n; v.w /= n;
        Bt[kq + 0][r] = v.x; Bt[kq + 1][r] = v.y;
        Bt[kq + 2][r] = v.z; Bt[kq + 3][r] = v.w;
      }
      __syncthreads();

#pragma unroll 4
      for (int k = 0; k < 32; ++k) {
        float a[MI], bb[8];
#pragma unroll
        for (int qv = 0; qv < MI / 4; ++qv)
          *(float4*)&a[qv * 4] = *(const float4*)&At[k][i0l + qv * 4];
        *(float4*)&bb[0] = *(const float4*)&Bt[k][j0l];
        *(float4*)&bb[4] = *(const float4*)&Bt[k][j0l + 4];
#pragma unroll
        for (int ii = 0; ii < MI; ++ii)
#pragma unroll
          for (int jj = 0; jj < 8; ++jj) acc[ii][jj] += a[ii] * bb[jj];
      }
    }

#pragma unroll
    for (int ii = 0; ii < MI; ++ii) {
      int ir = ico[0][i0l + ii], ic = ico[1][i0l + ii];
#pragma unroll
      for (int jj = 0; jj < 8; ++jj) {
        int jl = jt * 128 + j0l + jj;
        int dr = ir - jco[0][jl];
        int dc = ic - jco[1][jl];
        float sc = sw * acc[ii][jj] + lut[dr * dr + dc * dc];
        if (sc > best[ii]) {
          best[ii] = sc;
          bidx[ii] = j0g + jl;
        }
      }
    }
  }

  __syncthreads();
  float* rv = &At[0][0];
  int* rj = (int*)&Bt[0][0];
#pragma unroll
  for (int ii = 0; ii < MI; ++ii) {
    rv[(i0l + ii) * 17 + tx] = best[ii];
    rj[(i0l + ii) * 17 + tx] = bidx[ii];
  }
  __syncthreads();
  if (tid < IT) {
    float bv = rv[tid * 17];
    int bj = rj[tid * 17];
    for (int t = 1; t < 16; ++t) {
      float v = rv[tid * 17 + t];
      int j = rj[tid * 17 + t];
      if (v > bv || (v == bv && j < bj)) { bv = v; bj = j; }
    }
    int row = b * HH + it0 + tid;
    pval[(size_t)row * 8 + jb] = bv;
    pidx[(size_t)row * 8 + jb] = bj;
  }
}

__global__ void argreduce_kernel(const float* __restrict__ pv,
                                 const int* __restrict__ pj,
                                 int* __restrict__ dst, int nrows, int w) {
  int r = blockIdx.x * 256 + threadIdx.x;
  if (r >= nrows) return;
  const float* vv = pv + (size_t)r * w;
  const int* jj = pj + (size_t)r * w;
  float bv = vv[0];
  int bj = jj[0];
  for (int t = 1; t < w; ++t) {
    float v = vv[t];
    int j = jj[t];
    if (v > bv || (v == bv && j < bj)) { bv = v; bj = j; }
  }
  dst[r] = bj;
}

// -------- merge: out = b-half copy, then atomic scatter of a rows, divide ---
__global__ void copy_init_kernel(const float* __restrict__ src,
                                 float* __restrict__ dstbuf,
                                 float* __restrict__ cnt, int HH, int TT) {
  size_t idx = (size_t)blockIdx.x * 256 + threadIdx.x;
  size_t total = (size_t)NB * HH * 32;
  if (idx >= total) return;
  size_t row = idx >> 5;
  int e = (int)(idx & 31) * 4;
  int b = (int)(row / HH), j = (int)(row % HH);
  float4 v = *(const float4*)&src[((size_t)b * TT + HH + j) * NC + e];
  *(float4*)&dstbuf[row * NC + e] = v;
  if (e == 0) cnt[row] = 1.0f;
}

__global__ void scatter_kernel(const float* __restrict__ src,
                               const int* __restrict__ dst,
                               float* __restrict__ accbuf,
                               float* __restrict__ cnt, int HH, int TT) {
  size_t idx = (size_t)blockIdx.x * 256 + threadIdx.x;
  size_t total = (size_t)NB * HH * 32;
  if (idx >= total) return;
  size_t row = idx >> 5;
  int e = (int)(idx & 31) * 4;
  int b = (int)(row / HH), i = (int)(row % HH);
  float4 v = *(const float4*)&src[((size_t)b * TT + i) * NC + e];
  int d = dst[row];
  float* base = &accbuf[((size_t)b * HH + d) * NC + e];
  atomicAdd(base + 0, v.x);
  atomicAdd(base + 1, v.y);
  atomicAdd(base + 2, v.z);
  atomicAdd(base + 3, v.w);
  if (e == 0) atomicAdd(&cnt[(size_t)b * HH + d], 1.0f);
}

// finalize: divide by counts; optionally emit nrm + ext rows (p=128 enc) -----
__global__ void finalize_kernel(float* __restrict__ buf,
                                const float* __restrict__ cnt,
                                float* __restrict__ nrm,
                                _Float16* __restrict__ ext, int HH2) {
  int row = blockIdx.x * 2 + (threadIdx.x >> 7);
  int c = threadIdx.x & 127;
  float v = buf[(size_t)row * NC + c] / cnt[row];
  buf[(size_t)row * NC + c] = v;
  if (nrm != nullptr) {
    float s = v * v;
    for (int off = 32; off > 0; off >>= 1) s += __shfl_down(s, off, 64);
    __shared__ float p[4];
    __shared__ float ns[2];
    int w = threadIdx.x >> 6;
    if ((threadIdx.x & 63) == 0) p[w] = s;
    __syncthreads();
    if ((threadIdx.x & 127) == 0) {
      float n = sqrtf(p[w] + p[w + 1]);
      nrm[row] = n;
      ns[threadIdx.x >> 7] = n;
    }
    __syncthreads();
    if (ext != nullptr) {
      float n = ns[threadIdx.x >> 7];
      float m = v / n;
      _Float16 h = (_Float16)m;
      float hf = (float)h;
      _Float16 ep = (_Float16)((m - hf) * 128.0f);
      _Float16 hs = (_Float16)(hf * 0.0078125f);
      int t = row & (2 * HH2 - 1);
      bool isA = t < HH2;
      _Float16* rw = ext + (size_t)row * 384;
      rw[c] = h;
      rw[128 + c] = isA ? ep : hs;
      rw[256 + c] = isA ? hs : ep;
    }
  }
}

// ---------------- 1x1 conv (128x128) + BN + SiLU -> out (B,128,32,32) -------
__global__ __launch_bounds__(256) void conv_bn_silu_kernel(
    const float* __restrict__ xf3, const float* __restrict__ w,
    const float* __restrict__ gamma, const float* __restrict__ beta,
    const float* __restrict__ mean, const float* __restrict__ var,
    float* __restrict__ out) {
  __shared__ float X[64][132];
  __shared__ float Wt[128][68];
  const int b = blockIdx.y, p0 = blockIdx.x * 64;
  const int tid = threadIdx.x, lane = tid & 63, q = tid >> 6;
  {
    const float* row = xf3 + ((size_t)b * 1024 + p0 + lane) * NC;
    for (int cc = 0; cc < 8; ++cc) {
      int c = q * 32 + cc * 4;
      *(float4*)&X[lane][c] = *(const float4*)&row[c];
    }
  }
  const int ti = tid >> 4, tj = tid & 15;
  const int i4 = ti * 4, j4 = tj * 4;
  for (int ot = 0; ot < 2; ++ot) {
    __syncthreads();
    {
      const float* row = w + (size_t)(ot * 64 + lane) * NC;
      for (int cc = 0; cc < 8; ++cc) {
        int c = q * 32 + cc * 4;
        float4 v = *(const float4*)&row[c];
        Wt[c + 0][lane] = v.x;
        Wt[c + 1][lane] = v.y;
        Wt[c + 2][lane] = v.z;
        Wt[c + 3][lane] = v.w;
      }
    }
    __syncthreads();
    float acc[4][4];
#pragma unroll
    for (int ii = 0; ii < 4; ++ii)
#pragma unroll
      for (int jj = 0; jj < 4; ++jj) acc[ii][jj] = 0.f;

    for (int k = 0; k < NC; k += 4) {
      float4 a0 = *(const float4*)&X[i4 + 0][k];
      float4 a1 = *(const float4*)&X[i4 + 1][k];
      float4 a2 = *(const float4*)&X[i4 + 2][k];
      float4 a3 = *(const float4*)&X[i4 + 3][k];
      float4 b0 = *(const float4*)&Wt[k + 0][j4];
      float4 b1 = *(const float4*)&Wt[k + 1][j4];
      float4 b2 = *(const float4*)&Wt[k + 2][j4];
      float4 b3 = *(const float4*)&Wt[k + 3][j4];
#define FMA16(AX, BV)                                                     \
  acc[0][0] += a0.AX * BV.x; acc[0][1] += a0.AX * BV.y;                   \
  acc[0][2] += a0.AX * BV.z; acc[0][3] += a0.AX * BV.w;                   \
  acc[1][0] += a1.AX * BV.x; acc[1][1] += a1.AX * BV.y;                   \
  acc[1][2] += a1.AX * BV.z; acc[1][3] += a1.AX * BV.w;                   \
  acc[2][0] += a2.AX * BV.x; acc[2][1] += a2.AX * BV.y;                   \
  acc[2][2] += a2.AX * BV.z; acc[2][3] += a2.AX * BV.w;                   \
  acc[3][0] += a3.AX * BV.x; acc[3][1] += a3.AX * BV.y;                   \
  acc[3][2] += a3.AX * BV.z; acc[3][3] += a3.AX * BV.w;
      FMA16(x, b0)
      FMA16(y, b1)
      FMA16(z, b2)
      FMA16(w, b3)
#undef FMA16
    }

#pragma unroll
    for (int jj = 0; jj < 4; ++jj) {
      int o = ot * 64 + j4 + jj;
      float sc = gamma[o] / sqrtf(var[o] + 1e-5f);
      float mn = mean[o], bt = beta[o];
      float4 r;
      float z;
      z = (acc[0][jj] - mn) * sc + bt; r.x = z / (1.f + expf(-z));
      z = (acc[1][jj] - mn) * sc + bt; r.y = z / (1.f + expf(-z));
      z = (acc[2][jj] - mn) * sc + bt; r.z = z / (1.f + expf(-z));
      z = (acc[3][jj] - mn) * sc + bt; r.w = z / (1.f + expf(-z));
      *(float4*)&out[((size_t)(b * NC + o)) * 1024 + p0 + i4] = r;
    }
  }
}

extern "C" void kernel_launch(void* const* d_in, const int* in_sizes, int n_in,
                              void* d_out, int out_size, void* d_ws,
                              size_t ws_size, hipStream_t stream) {
  const float* x = (const float*)d_in[0];
  const float* swp = (const float*)d_in[1];
  const float* dwp = (const float*)d_in[2];
  const float* convw = (const float*)d_in[3];
  const float* gamma = (const float*)d_in[4];
  const float* beta = (const float*)d_in[5];
  const float* mean = (const float*)d_in[6];
  const float* var = (const float*)d_in[7];
  float* out = (float*)d_out;

  float* ws = (float*)d_ws;
  size_t o = 0;
  float* xf1 = ws + o;  o += (size_t)8 * 4096 * 128;  // reused as xf3
  float* nrm1 = ws + o; o += 8 * 4096;
  float* xf2 = ws + o;  o += (size_t)8 * 2048 * 128;
  float* nrm2 = ws + o; o += 8 * 2048;
  float* cnt1 = ws + o; o += 8 * 2048;
  float* cnt2 = ws + o; o += 8 * 1024;
  int* dst1 = (int*)(ws + o); o += 8 * 2048;
  int* dst2 = (int*)(ws + o); o += 8 * 1024;
  int* cand1 = (int*)(ws + o); o += (size_t)8 * 2048 * 4;
  int* cand2 = (int*)(ws + o); o += (size_t)8 * 1024 * 4;
  float* lut = ws + o;  o += 8192;
  _Float16* ext1 = (_Float16*)(ws + o);
  _Float16* ext2 = ext1;  // ext1 dead after merge-1 candidate pass
  const size_t ext_floats = (size_t)8 * 4096 * 384 / 2;
  const bool mfma_ok = ws_size >= (o + ext_floats) * sizeof(float);
  float* xf3 = xf1;  // alias: xf1 dead before xf3 written
  // aliases into dead regions (lifetimes verified):
  // pu1 (16384*64 u64 = 8.39MB) -> xf2 region (written later by copy_init)
  unsigned long long* pu1 = (unsigned long long*)xf2;
  // pu2 (8192*32 u64 = 2MB) -> xf1 region (dead after merge-1 scatter)
  unsigned long long* pu2 = (unsigned long long*)xf1;
  // fallback buffers alias the same dead regions
  float* pv1 = xf2;
  int* pj1 = (int*)(xf2 + 8 * 2048 * 8);
  float* pv2 = xf1;
  int* pj2 = (int*)(xf1 + 8 * 1024 * 8);

  lut_kernel<<<32, 256, 0, stream>>>(lut, dwp, 7939);

  // ---- merge 1: T=4096, H=2048, width=64 ----
  prep_kernel<<<dim3(64, 8), 256, 0, stream>>>(x, xf1, nrm1,
                                               mfma_ok ? ext1 : nullptr);
  if (mfma_ok) {
    argmax_mfma2_kernel<64, 4096, 2048>
        <<<dim3(8, 32, 8), 256, 0, stream>>>(ext1, swp, dwp, pu1);
    topk4_kernel<<<4096, 256, 0, stream>>>(pu1, cand1, 8 * 2048, 64);
    refine_kernel<64, 4096, 2048, 4>
        <<<4096, 256, 0, stream>>>(xf1, nrm1, cand1, swp, lut, dst1);
  } else {
    argmax2_kernel<64, 4096, 2048, 128, 256>
        <<<dim3(16, 8, 8), 256, 0, stream>>>(xf1, nrm1, swp, lut, pv1, pj1);
    argreduce_kernel<<<64, 256, 0, stream>>>(pv1, pj1, dst1, 8 * 2048, 8);
  }
  copy_init_kernel<<<2048, 256, 0, stream>>>(xf1, xf2, cnt1, 2048, 4096);
  scatter_kernel<<<2048, 256, 0, stream>>>(xf1, dst1, xf2, cnt1, 2048, 4096);
  finalize_kernel<<<8192, 256, 0, stream>>>(xf2, cnt1, nrm2,
                                            mfma_ok ? ext2 : nullptr, 1024);

  // ---- merge 2: T=2048, H=1024, width=int(sqrt(2048))=45 ----
  if (mfma_ok) {
    argmax_mfma2_kernel<45, 2048, 1024>
        <<<dim3(4, 16, 8), 256, 0, stream>>>(ext2, swp, dwp, pu2);
    topk4_kernel<<<2048, 256, 0, stream>>>(pu2, cand2, 8 * 1024, 32);
    refine_kernel<45, 2048, 1024, 4>
        <<<2048, 256, 0, stream>>>(xf2, nrm2, cand2, swp, lut, dst2);
  } else {
    argmax2_kernel<45, 2048, 1024, 64, 128>
        <<<dim3(16, 8, 8), 256, 0, stream>>>(xf2, nrm2, swp, lut, pv2, pj2);
    argreduce_kernel<<<32, 256, 0, stream>>>(pv2, pj2, dst2, 8 * 1024, 8);
  }
  copy_init_kernel<<<1024, 256, 0, stream>>>(xf2, xf3, cnt2, 1024, 2048);
  scatter_kernel<<<1024, 256, 0, stream>>>(xf2, dst2, xf3, cnt2, 1024, 2048);
  finalize_kernel<<<4096, 256, 0, stream>>>(xf3, cnt2, nullptr, nullptr, 512);

  // ---- 1x1 conv + BN + SiLU ----
  conv_bn_silu_kernel<<<dim3(16, 8), 256, 0, stream>>>(
      xf3, convw, gamma, beta, mean, var, out);
}

// Round 7
// 232.627 us; speedup vs baseline: 1.9284x; 1.0082x over previous
//
#include <hip/hip_runtime.h>
#include <math.h>

#define NB 8
#define NC 128

typedef _Float16 hf8 __attribute__((ext_vector_type(8)));
typedef float fx4 __attribute__((ext_vector_type(4)));

// ---------------- LUT: lut[d2] = dw * (1/(sqrt(d2)+1e-6)) -------------------
__global__ void lut_kernel(float* __restrict__ lut, const float* __restrict__ dwp,
                           int n) {
  int i = blockIdx.x * 256 + threadIdx.x;
  if (i < n) {
    float r = 1.0f / (sqrtf((float)i) + 1e-6f);
    lut[i] = dwp[0] * r;
  }
}

// ---- prep: x (B,C,4096) -> xf1, nrm1, ext1 (B,4096,384 fp16, p=128 enc) ----
// a-token row: [h | 128e | h/128]   b-token row: [h | h/128 | 128e]
__global__ void prep_kernel(const float* __restrict__ x, float* __restrict__ xf,
                            float* __restrict__ nrm, _Float16* __restrict__ ext) {
  __shared__ float tile[64][129];
  __shared__ float part[64][4];
  __shared__ float rn_s[64];
  const int b = blockIdx.y;
  const int p0 = blockIdx.x * 64;
  const int tid = threadIdx.x;
  const int lane = tid & 63;
  const int q = tid >> 6;
  for (int cc = 0; cc < 32; ++cc) {
    int c = q * 32 + cc;
    tile[lane][c] = x[((size_t)(b * NC + c)) * 4096 + p0 + lane];
  }
  __syncthreads();
  float s = 0.f;
  for (int cc = 0; cc < 32; ++cc) {
    float v = tile[lane][q * 32 + cc];
    s += v * v;
  }
  part[lane][q] = s;
  __syncthreads();
  if (tid < 64) {
    float n = sqrtf(part[tid][0] + part[tid][1] + part[tid][2] + part[tid][3]);
    nrm[b * 4096 + p0 + tid] = n;
    rn_s[tid] = n;
  }
  __syncthreads();
  for (int it = 0; it < 8; ++it) {
    int idx = it * 256 + tid;
    int r = idx >> 5, e = (idx & 31) * 4;
    float4 v = make_float4(tile[r][e], tile[r][e + 1], tile[r][e + 2], tile[r][e + 3]);
    size_t o = (((size_t)b * 4096 + p0 + r) << 7) + e;
    *(float4*)&xf[o] = v;
    if (ext != nullptr) {
      float n = rn_s[r];
      int tok = p0 + r;
      bool isA = tok < 2048;
      _Float16* rw = ext + ((size_t)b * 4096 + tok) * 384;
      float mm[4] = {v.x / n, v.y / n, v.z / n, v.w / n};
#pragma unroll
      for (int u = 0; u < 4; ++u) {
        float m = mm[u];
        _Float16 h = (_Float16)m;
        float hf = (float)h;
        _Float16 ep = (_Float16)((m - hf) * 128.0f);
        _Float16 hs = (_Float16)(hf * 0.0078125f);
        rw[e + u] = h;
        rw[128 + e + u] = isA ? ep : hs;
        rw[256 + e + u] = isA ? hs : ep;
      }
    }
  }
}

// ------ MFMA candidate kernel: B-stationary LDS, A global->reg, pipelined ---
// Block: 4 waves, each wave = 64i x 64j tile, K=384 single-acc p=128 encoding.
// Grid: x = jb (A-panel reuse across consecutive blocks), y = ib, z = batch.
// Emits packed u64 top-2 per (row, 64-j chunk).
template <int WIDTH, int TT, int HH>
__global__ __launch_bounds__(256, 3) void argmax_mfma3_kernel(
    const _Float16* __restrict__ ext, const float* __restrict__ swp,
    const float* __restrict__ dwp, unsigned long long* __restrict__ pu) {
  __shared__ _Float16 Bt[64][392];  // 50176 B; reused as reduce buffer
  const int b = blockIdx.z;
  const int ib = blockIdx.y;
  const int jb = blockIdx.x;
  const int tid = threadIdx.x;
  const int w = tid >> 6, l = tid & 63;
  const int lg = l >> 4, lm = l & 15;
  const int ipan = ib * 256 + w * 64;
  const int j0 = jb * 64;
  const float sw = swp[0], dwv = dwp[0];
  const _Float16* extb = ext + (size_t)b * TT * 384;
  const _Float16* brow0 = extb + (size_t)(HH + j0) * 384;

  const _Float16* ap0 = extb + (size_t)(ipan + 0 * 16 + lm) * 384 + lg * 8;
  const _Float16* ap1 = extb + (size_t)(ipan + 1 * 16 + lm) * 384 + lg * 8;
  const _Float16* ap2 = extb + (size_t)(ipan + 2 * 16 + lm) * 384 + lg * 8;
  const _Float16* ap3 = extb + (size_t)(ipan + 3 * 16 + lm) * 384 + lg * 8;

  // issue first A-fragment loads before staging B (overlap with staging)
  hf8 a0 = *(const hf8*)(ap0);
  hf8 a1 = *(const hf8*)(ap1);
  hf8 a2 = *(const hf8*)(ap2);
  hf8 a3 = *(const hf8*)(ap3);

  // stage B tile once: 64 rows x 384 halfs
  for (int f = tid; f < 64 * 48; f += 256) {
    int r = f / 48, c = f % 48;
    *(float4*)&Bt[r][c * 8] = *(const float4*)&brow0[(size_t)r * 384 + c * 8];
  }
  __syncthreads();

  const _Float16* bp0 = &Bt[0 * 16 + lm][lg * 8];
  const _Float16* bp1 = &Bt[1 * 16 + lm][lg * 8];
  const _Float16* bp2 = &Bt[2 * 16 + lm][lg * 8];
  const _Float16* bp3 = &Bt[3 * 16 + lm][lg * 8];
  hf8 b0 = *(const hf8*)(bp0);
  hf8 b1 = *(const hf8*)(bp1);
  hf8 b2 = *(const hf8*)(bp2);
  hf8 b3 = *(const hf8*)(bp3);

  fx4 acc[4][4];
#pragma unroll
  for (int i4 = 0; i4 < 4; ++i4)
#pragma unroll
    for (int j4 = 0; j4 < 4; ++j4) acc[i4][j4] = 0.f;

#pragma unroll
  for (int kc = 0; kc < 12; ++kc) {
    hf8 n0, n1, n2, n3, m0, m1, m2, m3;
    if (kc < 11) {  // prefetch next chunk (A: global, B: LDS) before MFMAs
      n0 = *(const hf8*)(ap0 + (kc + 1) * 32);
      n1 = *(const hf8*)(ap1 + (kc + 1) * 32);
      n2 = *(const hf8*)(ap2 + (kc + 1) * 32);
      n3 = *(const hf8*)(ap3 + (kc + 1) * 32);
      m0 = *(const hf8*)(bp0 + (kc + 1) * 32);
      m1 = *(const hf8*)(bp1 + (kc + 1) * 32);
      m2 = *(const hf8*)(bp2 + (kc + 1) * 32);
      m3 = *(const hf8*)(bp3 + (kc + 1) * 32);
    }
#define MF(I, J, A, B) \
  acc[I][J] = __builtin_amdgcn_mfma_f32_16x16x32_f16(A, B, acc[I][J], 0, 0, 0);
    MF(0, 0, a0, b0) MF(1, 0, a1, b0) MF(2, 0, a2, b0) MF(3, 0, a3, b0)
    MF(0, 1, a0, b1) MF(1, 1, a1, b1) MF(2, 1, a2, b1) MF(3, 1, a3, b1)
    MF(0, 2, a0, b2) MF(1, 2, a1, b2) MF(2, 2, a2, b2) MF(3, 2, a3, b2)
    MF(0, 3, a0, b3) MF(1, 3, a1, b3) MF(2, 3, a2, b3) MF(3, 3, a3, b3)
#undef MF
    if (kc < 11) {
      a0 = n0; a1 = n1; a2 = n2; a3 = n3;
      b0 = m0; b1 = m1; b2 = m2; b3 = m3;
    }
  }

  // ---- epilogue: per-lane first-max over its 4 cols, per row ----
  // C/D layout: row = lg*4 + reg (+i4*16), col = lm (+j4*16).
  int jr4[4], jc4[4];
#pragma unroll
  for (int j4 = 0; j4 < 4; ++j4) {
    int tj = HH + j0 + j4 * 16 + lm;
    jr4[j4] = tj / WIDTH;
    jc4[j4] = tj % WIDTH;
  }
  unsigned long long myred[16];
#pragma unroll
  for (int i4 = 0; i4 < 4; ++i4) {
#pragma unroll
    for (int rg = 0; rg < 4; ++rg) {
      int ti = ipan + i4 * 16 + lg * 4 + rg;
      int ir = ti / WIDTH, ic = ti % WIDTH;
      float bv = -1e30f;
      int bj = 0;
#pragma unroll
      for (int j4 = 0; j4 < 4; ++j4) {  // ascending j -> first-max kept
        int dr = ir - jr4[j4], dc = ic - jc4[j4];
        float d2 = (float)(dr * dr + dc * dc);
        float sc = sw * acc[i4][j4][rg] +
                   dwv * __builtin_amdgcn_rcpf(sqrtf(d2) + 1e-6f);
        int gj = j0 + j4 * 16 + lm;
        if (sc > bv) { bv = sc; bj = gj; }
      }
      myred[i4 * 4 + rg] =
          ((unsigned long long)__float_as_uint(bv + 1.0f) << 32) |
          (unsigned)(~(unsigned)bj);
    }
  }
  __syncthreads();  // all waves done reading Bt -> reuse as reduce buffer
  unsigned long long* rwv = (unsigned long long*)&Bt[0][0] + (size_t)w * 64 * 17;
#pragma unroll
  for (int m = 0; m < 16; ++m) {
    int il = (m >> 2) * 16 + lg * 4 + (m & 3);
    rwv[il * 17 + lm] = myred[m];
  }
  __syncthreads();
  // lane l owns row l: top-2 over 16 lane-maxima (u64 packed order)
  unsigned long long t1 = 0ull, t2 = 0ull;
#pragma unroll
  for (int c = 0; c < 16; ++c) {
    unsigned long long u = rwv[l * 17 + c];
    if (u > t1) { t2 = t1; t1 = u; }
    else if (u > t2) { t2 = u; }
  }
  size_t row = (size_t)b * HH + ipan + l;
  pu[row * (HH / 32) + jb * 2 + 0] = t1;
  pu[row * (HH / 32) + jb * 2 + 1] = t2;
}

// --------- top-4 over per-chunk packed candidates (wave per row) ------------
__global__ void topk4_kernel(const unsigned long long* __restrict__ pu,
                             int* __restrict__ cand, int nrows, int nch2) {
  int row = blockIdx.x * 4 + (threadIdx.x >> 6);
  int lane = threadIdx.x & 63;
  if (row >= nrows) return;
  unsigned long long v = (lane < nch2) ? pu[(size_t)row * nch2 + lane] : 0ull;
  for (int t = 0; t < 4; ++t) {
    unsigned long long m = v;
#pragma unroll
    for (int off = 1; off < 64; off <<= 1) {
      unsigned long long o = __shfl_xor(m, off, 64);
      if (o > m) m = o;
    }
    if (lane == t) cand[row * 4 + t] = (int)(~(unsigned)(m & 0xFFFFFFFFull));
    if (v == m) v = 0ull;  // packed u64 unique per j -> exact removal
  }
}

// ------ exact fp32 refinement over candidates: dst = first-argmax -----------
template <int WIDTH, int TT, int HH, int NCAND>
__global__ __launch_bounds__(256) void refine_kernel(
    const float* __restrict__ xf, const float* __restrict__ nrm,
    const int* __restrict__ pidx, const float* __restrict__ swp,
    const float* __restrict__ lut, int* __restrict__ dst) {
  const int rowl = blockIdx.x * 4 + (threadIdx.x >> 6);
  const int lane = threadIdx.x & 63;
  const int half = lane >> 5, ln = lane & 31;
  const int b = rowl / HH, i = rowl - b * HH;
  const float sw = swp[0];
  const float na = nrm[b * TT + i];
  float4 a4 = *(const float4*)&xf[((size_t)b * TT + i) * NC + ln * 4];
  a4.x /= na; a4.y /= na; a4.z /= na; a4.w /= na;
  const int ir = i / WIDTH, ic = i % WIDTH;
  const int* cand = pidx + (size_t)rowl * NCAND;
  float bv = -3.0e38f;
  int bj = 0x7fffffff;
  for (int c = 0; c < NCAND; c += 2) {
    int j = cand[c + half];
    float4 b4 = *(const float4*)&xf[((size_t)b * TT + HH + j) * NC + ln * 4];
    float p = a4.x * b4.x + a4.y * b4.y + a4.z * b4.z + a4.w * b4.w;
#pragma unroll
    for (int off = 1; off < 32; off <<= 1) p += __shfl_xor(p, off, 32);
    float nb = nrm[b * TT + HH + j];
    int tj = HH + j;
    int jr = tj / WIDTH;
    int dr = ir - jr, dc = ic - (tj - jr * WIDTH);
    float sc = sw * (p / nb) + lut[dr * dr + dc * dc];
    if (sc > bv || (sc == bv && j < bj)) { bv = sc; bj = j; }
  }
  {
    float ov = __shfl_xor(bv, 32, 64);
    int oj = __shfl_xor(bj, 32, 64);
    if (ov > bv || (ov == bv && oj < bj)) { bv = ov; bj = oj; }
  }
  if (lane == 0) dst[rowl] = bj;
}

// ---------------- FALLBACK fp32 path (round-1 structure, proven) ------------
template <int WIDTH, int TT, int HH, int IT, int JC>
__global__ __launch_bounds__(256, 4) void argmax2_kernel(
    const float* __restrict__ xf, const float* __restrict__ nrm,
    const float* __restrict__ swp, const float* __restrict__ lut,
    float* __restrict__ pval, int* __restrict__ pidx) {
  constexpr int MI = IT / 16;
  constexpr int NTILE = JC / 128;
  __shared__ float At[32][IT + 4];
  __shared__ float Bt[32][132];
  __shared__ int ico[2][IT];
  __shared__ int jco[2][JC];

  const int b = blockIdx.z;
  const int it0 = blockIdx.x * IT;
  const int jb = blockIdx.y;
  const int j0g = jb * JC;
  const int tid = threadIdx.x;

  for (int t = tid; t < IT; t += 256) {
    int tok = it0 + t;
    ico[0][t] = tok / WIDTH;
    ico[1][t] = tok % WIDTH;
  }
  for (int t = tid; t < JC; t += 256) {
    int tok = HH + j0g + t;
    jco[0][t] = tok / WIDTH;
    jco[1][t] = tok % WIDTH;
  }
  const float sw = swp[0];
  const float* srcb = xf + (size_t)b * TT * NC;

  const int ty = tid >> 4, tx = tid & 15;
  const int i0l = ty * MI;
  const int j0l = tx * 8;

  float best[MI];
  int bidx[MI];
#pragma unroll
  for (int ii = 0; ii < MI; ++ii) { best[ii] = -1e30f; bidx[ii] = 0; }

  for (int jt = 0; jt < NTILE; ++jt) {
    float acc[MI][8];
#pragma unroll
    for (int ii = 0; ii < MI; ++ii)
#pragma unroll
      for (int jj = 0; jj < 8; ++jj) acc[ii][jj] = 0.f;

    for (int kc = 0; kc < 4; ++kc) {
      __syncthreads();
#pragma unroll
      for (int p = 0; p < IT / 32; ++p) {
        int f = p * 256 + tid;
        int r = f >> 3, kq = (f & 7) * 4;
        const float* row = srcb + (size_t)(it0 + r) * NC + kc * 32 + kq;
        float4 v = *(const float4*)row;
        float n = nrm[b * TT + it0 + r];
        v.x /= n; v.y /= n; v.z /= n; v.w /= n;
        At[kq + 0][r] = v.x; At[kq + 1][r] = v.y;
        At[kq + 2][r] = v.z; At[kq + 3][r] = v.w;
      }
#pragma unroll
      for (int p = 0; p < 4; ++p) {
        int f = p * 256 + tid;
        int r = f >> 3, kq = (f & 7) * 4;
        int tok = HH + j0g + jt * 128 + r;
        const float* row = srcb + (size_t)tok * NC + kc * 32 + kq;
        float4 v = *(const float4*)row;
        float n = nrm[b * TT + tok];
        v.x /= n; v.y /= n; v.z /= n; v.w /= n;
        Bt[kq + 0][r] = v.x; Bt[kq + 1][r] = v.y;
        Bt[kq + 2][r] = v.z; Bt[kq + 3][r] = v.w;
      }
      __syncthreads();

#pragma unroll 4
      for (int k = 0; k < 32; ++k) {
        float a[MI], bb[8];
#pragma unroll
        for (int qv = 0; qv < MI / 4; ++qv)
          *(float4*)&a[qv * 4] = *(const float4*)&At[k][i0l + qv * 4];
        *(float4*)&bb[0] = *(const float4*)&Bt[k][j0l];
        *(float4*)&bb[4] = *(const float4*)&Bt[k][j0l + 4];
#pragma unroll
        for (int ii = 0; ii < MI; ++ii)
#pragma unroll
          for (int jj = 0; jj < 8; ++jj) acc[ii][jj] += a[ii] * bb[jj];
      }
    }

#pragma unroll
    for (int ii = 0; ii < MI; ++ii) {
      int ir = ico[0][i0l + ii], ic = ico[1][i0l + ii];
#pragma unroll
      for (int jj = 0; jj < 8; ++jj) {
        int jl = jt * 128 + j0l + jj;
        int dr = ir - jco[0][jl];
        int dc = ic - jco[1][jl];
        float sc = sw * acc[ii][jj] + lut[dr * dr + dc * dc];
        if (sc > best[ii]) {
          best[ii] = sc;
          bidx[ii] = j0g + jl;
        }
      }
    }
  }

  __syncthreads();
  float* rv = &At[0][0];
  int* rj = (int*)&Bt[0][0];
#pragma unroll
  for (int ii = 0; ii < MI; ++ii) {
    rv[(i0l + ii) * 17 + tx] = best[ii];
    rj[(i0l + ii) * 17 + tx] = bidx[ii];
  }
  __syncthreads();
  if (tid < IT) {
    float bv = rv[tid * 17];
    int bj = rj[tid * 17];
    for (int t = 1; t < 16; ++t) {
      float v = rv[tid * 17 + t];
      int j = rj[tid * 17 + t];
      if (v > bv || (v == bv && j < bj)) { bv = v; bj = j; }
    }
    int row = b * HH + it0 + tid;
    pval[(size_t)row * 8 + jb] = bv;
    pidx[(size_t)row * 8 + jb] = bj;
  }
}

__global__ void argreduce_kernel(const float* __restrict__ pv,
                                 const int* __restrict__ pj,
                                 int* __restrict__ dst, int nrows, int w) {
  int r = blockIdx.x * 256 + threadIdx.x;
  if (r >= nrows) return;
  const float* vv = pv + (size_t)r * w;
  const int* jj = pj + (size_t)r * w;
  float bv = vv[0];
  int bj = jj[0];
  for (int t = 1; t < w; ++t) {
    float v = vv[t];
    int j = jj[t];
    if (v > bv || (v == bv && j < bj)) { bv = v; bj = j; }
  }
  dst[r] = bj;
}

// -------- merge: out = b-half copy, then atomic scatter of a rows, divide ---
__global__ void copy_init_kernel(const float* __restrict__ src,
                                 float* __restrict__ dstbuf,
                                 float* __restrict__ cnt, int HH, int TT) {
  size_t idx = (size_t)blockIdx.x * 256 + threadIdx.x;
  size_t total = (size_t)NB * HH * 32;
  if (idx >= total) return;
  size_t row = idx >> 5;
  int e = (int)(idx & 31) * 4;
  int b = (int)(row / HH), j = (int)(row % HH);
  float4 v = *(const float4*)&src[((size_t)b * TT + HH + j) * NC + e];
  *(float4*)&dstbuf[row * NC + e] = v;
  if (e == 0) cnt[row] = 1.0f;
}

__global__ void scatter_kernel(const float* __restrict__ src,
                               const int* __restrict__ dst,
                               float* __restrict__ accbuf,
                               float* __restrict__ cnt, int HH, int TT) {
  size_t idx = (size_t)blockIdx.x * 256 + threadIdx.x;
  size_t total = (size_t)NB * HH * 32;
  if (idx >= total) return;
  size_t row = idx >> 5;
  int e = (int)(idx & 31) * 4;
  int b = (int)(row / HH), i = (int)(row % HH);
  float4 v = *(const float4*)&src[((size_t)b * TT + i) * NC + e];
  int d = dst[row];
  float* base = &accbuf[((size_t)b * HH + d) * NC + e];
  atomicAdd(base + 0, v.x);
  atomicAdd(base + 1, v.y);
  atomicAdd(base + 2, v.z);
  atomicAdd(base + 3, v.w);
  if (e == 0) atomicAdd(&cnt[(size_t)b * HH + d], 1.0f);
}

// finalize: divide by counts; optionally emit nrm + ext rows (p=128 enc) -----
__global__ void finalize_kernel(float* __restrict__ buf,
                                const float* __restrict__ cnt,
                                float* __restrict__ nrm,
                                _Float16* __restrict__ ext, int HH2) {
  int row = blockIdx.x * 2 + (threadIdx.x >> 7);
  int c = threadIdx.x & 127;
  float v = buf[(size_t)row * NC + c] / cnt[row];
  buf[(size_t)row * NC + c] = v;
  if (nrm != nullptr) {
    float s = v * v;
    for (int off = 32; off > 0; off >>= 1) s += __shfl_down(s, off, 64);
    __shared__ float p[4];
    __shared__ float ns[2];
    int w = threadIdx.x >> 6;
    if ((threadIdx.x & 63) == 0) p[w] = s;
    __syncthreads();
    if ((threadIdx.x & 127) == 0) {
      float n = sqrtf(p[w] + p[w + 1]);
      nrm[row] = n;
      ns[threadIdx.x >> 7] = n;
    }
    __syncthreads();
    if (ext != nullptr) {
      float n = ns[threadIdx.x >> 7];
      float m = v / n;
      _Float16 h = (_Float16)m;
      float hf = (float)h;
      _Float16 ep = (_Float16)((m - hf) * 128.0f);
      _Float16 hs = (_Float16)(hf * 0.0078125f);
      int t = row & (2 * HH2 - 1);
      bool isA = t < HH2;
      _Float16* rw = ext + (size_t)row * 384;
      rw[c] = h;
      rw[128 + c] = isA ? ep : hs;
      rw[256 + c] = isA ? hs : ep;
    }
  }
}

// ---------------- 1x1 conv (128x128) + BN + SiLU -> out (B,128,32,32) -------
__global__ __launch_bounds__(256) void conv_bn_silu_kernel(
    const float* __restrict__ xf3, const float* __restrict__ w,
    const float* __restrict__ gamma, const float* __restrict__ beta,
    const float* __restrict__ mean, const float* __restrict__ var,
    float* __restrict__ out) {
  __shared__ float X[64][132];
  __shared__ float Wt[128][68];
  const int b = blockIdx.y, p0 = blockIdx.x * 64;
  const int tid = threadIdx.x, lane = tid & 63, q = tid >> 6;
  {
    const float* row = xf3 + ((size_t)b * 1024 + p0 + lane) * NC;
    for (int cc = 0; cc < 8; ++cc) {
      int c = q * 32 + cc * 4;
      *(float4*)&X[lane][c] = *(const float4*)&row[c];
    }
  }
  const int ti = tid >> 4, tj = tid & 15;
  const int i4 = ti * 4, j4 = tj * 4;
  for (int ot = 0; ot < 2; ++ot) {
    __syncthreads();
    {
      const float* row = w + (size_t)(ot * 64 + lane) * NC;
      for (int cc = 0; cc < 8; ++cc) {
        int c = q * 32 + cc * 4;
        float4 v = *(const float4*)&row[c];
        Wt[c + 0][lane] = v.x;
        Wt[c + 1][lane] = v.y;
        Wt[c + 2][lane] = v.z;
        Wt[c + 3][lane] = v.w;
      }
    }
    __syncthreads();
    float acc[4][4];
#pragma unroll
    for (int ii = 0; ii < 4; ++ii)
#pragma unroll
      for (int jj = 0; jj < 4; ++jj) acc[ii][jj] = 0.f;

    for (int k = 0; k < NC; k += 4) {
      float4 a0 = *(const float4*)&X[i4 + 0][k];
      float4 a1 = *(const float4*)&X[i4 + 1][k];
      float4 a2 = *(const float4*)&X[i4 + 2][k];
      float4 a3 = *(const float4*)&X[i4 + 3][k];
      float4 b0 = *(const float4*)&Wt[k + 0][j4];
      float4 b1 = *(const float4*)&Wt[k + 1][j4];
      float4 b2 = *(const float4*)&Wt[k + 2][j4];
      float4 b3 = *(const float4*)&Wt[k + 3][j4];
#define FMA16(AX, BV)                                                     \
  acc[0][0] += a0.AX * BV.x; acc[0][1] += a0.AX * BV.y;                   \
  acc[0][2] += a0.AX * BV.z; acc[0][3] += a0.AX * BV.w;                   \
  acc[1][0] += a1.AX * BV.x; acc[1][1] += a1.AX * BV.y;                   \
  acc[1][2] += a1.AX * BV.z; acc[1][3] += a1.AX * BV.w;                   \
  acc[2][0] += a2.AX * BV.x; acc[2][1] += a2.AX * BV.y;                   \
  acc[2][2] += a2.AX * BV.z; acc[2][3] += a2.AX * BV.w;                   \
  acc[3][0] += a3.AX * BV.x; acc[3][1] += a3.AX * BV.y;                   \
  acc[3][2] += a3.AX * BV.z; acc[3][3] += a3.AX * BV.w;
      FMA16(x, b0)
      FMA16(y, b1)
      FMA16(z, b2)
      FMA16(w, b3)
#undef FMA16
    }

#pragma unroll
    for (int jj = 0; jj < 4; ++jj) {
      int o = ot * 64 + j4 + jj;
      float sc = gamma[o] / sqrtf(var[o] + 1e-5f);
      float mn = mean[o], bt = beta[o];
      float4 r;
      float z;
      z = (acc[0][jj] - mn) * sc + bt; r.x = z / (1.f + expf(-z));
      z = (acc[1][jj] - mn) * sc + bt; r.y = z / (1.f + expf(-z));
      z = (acc[2][jj] - mn) * sc + bt; r.z = z / (1.f + expf(-z));
      z = (acc[3][jj] - mn) * sc + bt; r.w = z / (1.f + expf(-z));
      *(float4*)&out[((size_t)(b * NC + o)) * 1024 + p0 + i4] = r;
    }
  }
}

extern "C" void kernel_launch(void* const* d_in, const int* in_sizes, int n_in,
                              void* d_out, int out_size, void* d_ws,
                              size_t ws_size, hipStream_t stream) {
  const float* x = (const float*)d_in[0];
  const float* swp = (const float*)d_in[1];
  const float* dwp = (const float*)d_in[2];
  const float* convw = (const float*)d_in[3];
  const float* gamma = (const float*)d_in[4];
  const float* beta = (const float*)d_in[5];
  const float* mean = (const float*)d_in[6];
  const float* var = (const float*)d_in[7];
  float* out = (float*)d_out;

  float* ws = (float*)d_ws;
  size_t o = 0;
  float* xf1 = ws + o;  o += (size_t)8 * 4096 * 128;  // reused as xf3
  float* nrm1 = ws + o; o += 8 * 4096;
  float* xf2 = ws + o;  o += (size_t)8 * 2048 * 128;
  float* nrm2 = ws + o; o += 8 * 2048;
  float* cnt1 = ws + o; o += 8 * 2048;
  float* cnt2 = ws + o; o += 8 * 1024;
  int* dst1 = (int*)(ws + o); o += 8 * 2048;
  int* dst2 = (int*)(ws + o); o += 8 * 1024;
  int* cand1 = (int*)(ws + o); o += (size_t)8 * 2048 * 4;
  int* cand2 = (int*)(ws + o); o += (size_t)8 * 1024 * 4;
  float* lut = ws + o;  o += 8192;
  _Float16* ext1 = (_Float16*)(ws + o);
  _Float16* ext2 = ext1;  // ext1 dead after merge-1 candidate pass
  const size_t ext_floats = (size_t)8 * 4096 * 384 / 2;
  const bool mfma_ok = ws_size >= (o + ext_floats) * sizeof(float);
  float* xf3 = xf1;  // alias: xf1 dead before xf3 written
  // aliases into dead regions (lifetimes verified):
  unsigned long long* pu1 = (unsigned long long*)xf2;
  unsigned long long* pu2 = (unsigned long long*)xf1;
  float* pv1 = xf2;
  int* pj1 = (int*)(xf2 + 8 * 2048 * 8);
  float* pv2 = xf1;
  int* pj2 = (int*)(xf1 + 8 * 1024 * 8);

  lut_kernel<<<32, 256, 0, stream>>>(lut, dwp, 7939);

  // ---- merge 1: T=4096, H=2048, width=64 ----
  prep_kernel<<<dim3(64, 8), 256, 0, stream>>>(x, xf1, nrm1,
                                               mfma_ok ? ext1 : nullptr);
  if (mfma_ok) {
    argmax_mfma3_kernel<64, 4096, 2048>
        <<<dim3(32, 8, 8), 256, 0, stream>>>(ext1, swp, dwp, pu1);
    topk4_kernel<<<4096, 256, 0, stream>>>(pu1, cand1, 8 * 2048, 64);
    refine_kernel<64, 4096, 2048, 4>
        <<<4096, 256, 0, stream>>>(xf1, nrm1, cand1, swp, lut, dst1);
  } else {
    argmax2_kernel<64, 4096, 2048, 128, 256>
        <<<dim3(16, 8, 8), 256, 0, stream>>>(xf1, nrm1, swp, lut, pv1, pj1);
    argreduce_kernel<<<64, 256, 0, stream>>>(pv1, pj1, dst1, 8 * 2048, 8);
  }
  copy_init_kernel<<<2048, 256, 0, stream>>>(xf1, xf2, cnt1, 2048, 4096);
  scatter_kernel<<<2048, 256, 0, stream>>>(xf1, dst1, xf2, cnt1, 2048, 4096);
  finalize_kernel<<<8192, 256, 0, stream>>>(xf2, cnt1, nrm2,
                                            mfma_ok ? ext2 : nullptr, 1024);

  // ---- merge 2: T=2048, H=1024, width=int(sqrt(2048))=45 ----
  if (mfma_ok) {
    argmax_mfma3_kernel<45, 2048, 1024>
        <<<dim3(16, 4, 8), 256, 0, stream>>>(ext2, swp, dwp, pu2);
    topk4_kernel<<<2048, 256, 0, stream>>>(pu2, cand2, 8 * 1024, 32);
    refine_kernel<45, 2048, 1024, 4>
        <<<2048, 256, 0, stream>>>(xf2, nrm2, cand2, swp, lut, dst2);
  } else {
    argmax2_kernel<45, 2048, 1024, 64, 128>
        <<<dim3(16, 8, 8), 256, 0, stream>>>(xf2, nrm2, swp, lut, pv2, pj2);
    argreduce_kernel<<<32, 256, 0, stream>>>(pv2, pj2, dst2, 8 * 1024, 8);
  }
  copy_init_kernel<<<1024, 256, 0, stream>>>(xf2, xf3, cnt2, 1024, 2048);
  scatter_kernel<<<1024, 256, 0, stream>>>(xf2, dst2, xf3, cnt2, 1024, 2048);
  finalize_kernel<<<4096, 256, 0, stream>>>(xf3, cnt2, nullptr, nullptr, 512);

  // ---- 1x1 conv + BN + SiLU ----
  conv_bn_silu_kernel<<<dim3(16, 8), 256, 0, stream>>>(
      xf3, convw, gamma, beta, mean, var, out);
}

// Round 8
// 203.158 us; speedup vs baseline: 2.2082x; 1.1451x over previous
//
#include <hip/hip_runtime.h>
#include <math.h>

#define NB 8
#define NC 128

typedef _Float16 hf8 __attribute__((ext_vector_type(8)));
typedef float fx4 __attribute__((ext_vector_type(4)));

// ---------------- LUT: lut[d2] = dw * (1/(sqrt(d2)+1e-6)) (fallback only) ---
__global__ void lut_kernel(float* __restrict__ lut, const float* __restrict__ dwp,
                           int n) {
  int i = blockIdx.x * 256 + threadIdx.x;
  if (i < n) {
    float r = 1.0f / (sqrtf((float)i) + 1e-6f);
    lut[i] = dwp[0] * r;
  }
}

// ---- prep: x (B,C,4096) -> xf1, nrm1, ext1 (B,4096,384 fp16, p=128 enc) ----
// a-token row: [h | 128e | h/128]   b-token row: [h | h/128 | 128e]
__global__ void prep_kernel(const float* __restrict__ x, float* __restrict__ xf,
                            float* __restrict__ nrm, _Float16* __restrict__ ext) {
  __shared__ float tile[64][129];
  __shared__ float part[64][4];
  __shared__ float rn_s[64];
  const int b = blockIdx.y;
  const int p0 = blockIdx.x * 64;
  const int tid = threadIdx.x;
  const int lane = tid & 63;
  const int q = tid >> 6;
  for (int cc = 0; cc < 32; ++cc) {
    int c = q * 32 + cc;
    tile[lane][c] = x[((size_t)(b * NC + c)) * 4096 + p0 + lane];
  }
  __syncthreads();
  float s = 0.f;
  for (int cc = 0; cc < 32; ++cc) {
    float v = tile[lane][q * 32 + cc];
    s += v * v;
  }
  part[lane][q] = s;
  __syncthreads();
  if (tid < 64) {
    float n = sqrtf(part[tid][0] + part[tid][1] + part[tid][2] + part[tid][3]);
    nrm[b * 4096 + p0 + tid] = n;
    rn_s[tid] = n;
  }
  __syncthreads();
  for (int it = 0; it < 8; ++it) {
    int idx = it * 256 + tid;
    int r = idx >> 5, e = (idx & 31) * 4;
    float4 v = make_float4(tile[r][e], tile[r][e + 1], tile[r][e + 2], tile[r][e + 3]);
    size_t o = (((size_t)b * 4096 + p0 + r) << 7) + e;
    *(float4*)&xf[o] = v;
    if (ext != nullptr) {
      float n = rn_s[r];
      int tok = p0 + r;
      bool isA = tok < 2048;
      _Float16* rw = ext + ((size_t)b * 4096 + tok) * 384;
      float mm[4] = {v.x / n, v.y / n, v.z / n, v.w / n};
#pragma unroll
      for (int u = 0; u < 4; ++u) {
        float m = mm[u];
        _Float16 h = (_Float16)m;
        float hf = (float)h;
        _Float16 ep = (_Float16)((m - hf) * 128.0f);
        _Float16 hs = (_Float16)(hf * 0.0078125f);
        rw[e + u] = h;
        rw[128 + e + u] = isA ? ep : hs;
        rw[256 + e + u] = isA ? hs : ep;
      }
    }
  }
}

// ------ MFMA candidate kernel: B-stationary LDS, A global->reg depth-2 ------
// Block: 4 waves, each wave = 64i x 64j, K=384 single-acc p=128 encoding.
// Grid: x = jb (A-panel L2 reuse), y = ib, z = batch.
// Emits packed u64 top-2 per (row, 64-j chunk).
template <int WIDTH, int TT, int HH>
__global__ __launch_bounds__(256, 3) void argmax_mfma4_kernel(
    const _Float16* __restrict__ ext, const float* __restrict__ swp,
    const float* __restrict__ dwp, unsigned long long* __restrict__ pu) {
  __shared__ _Float16 Bt[64][392];  // 50176 B; reused as reduce buffer
  const int b = blockIdx.z;
  const int ib = blockIdx.y;
  const int jb = blockIdx.x;
  const int tid = threadIdx.x;
  const int w = tid >> 6, l = tid & 63;
  const int lg = l >> 4, lm = l & 15;
  const int ipan = ib * 256 + w * 64;
  const int j0 = jb * 64;
  const float sw = swp[0], dwv = dwp[0];
  const _Float16* extb = ext + (size_t)b * TT * 384;
  const _Float16* brow0 = extb + (size_t)(HH + j0) * 384;

  const _Float16* ap[4];
#pragma unroll
  for (int s = 0; s < 4; ++s)
    ap[s] = extb + (size_t)(ipan + s * 16 + lm) * 384 + lg * 8;

  // prologue: issue A stages for kc=0,1 (depth-2 pipeline, 3 stages)
  hf8 aS[3][4];
#pragma unroll
  for (int st = 0; st < 2; ++st)
#pragma unroll
    for (int s = 0; s < 4; ++s)
      aS[st][s] = *(const hf8*)(ap[s] + st * 32);

  // stage B tile once: 64 rows x 384 halfs (pad 392 -> 2-way banks on read)
  for (int f = tid; f < 64 * 48; f += 256) {
    int r = f / 48, c = f % 48;
    *(float4*)&Bt[r][c * 8] = *(const float4*)&brow0[(size_t)r * 384 + c * 8];
  }
  __syncthreads();

  fx4 acc[4][4];
#pragma unroll
  for (int i4 = 0; i4 < 4; ++i4)
#pragma unroll
    for (int j4 = 0; j4 < 4; ++j4) acc[i4][j4] = 0.f;

#pragma unroll
  for (int kc = 0; kc < 12; ++kc) {
    if (kc + 2 < 12) {  // issue A loads 2 chunks ahead (before this kc's MFMAs)
#pragma unroll
      for (int s = 0; s < 4; ++s)
        aS[(kc + 2) % 3][s] = *(const hf8*)(ap[s] + (kc + 2) * 32);
    }
    hf8 bf[4];
#pragma unroll
    for (int s = 0; s < 4; ++s)
      bf[s] = *(const hf8*)&Bt[s * 16 + lm][kc * 32 + lg * 8];
    __builtin_amdgcn_s_setprio(1);
#pragma unroll
    for (int j4 = 0; j4 < 4; ++j4)
#pragma unroll
      for (int i4 = 0; i4 < 4; ++i4)
        acc[i4][j4] = __builtin_amdgcn_mfma_f32_16x16x32_f16(
            aS[kc % 3][i4], bf[j4], acc[i4][j4], 0, 0, 0);
    __builtin_amdgcn_s_setprio(0);
  }

  // ---- epilogue: per-lane first-max over its 4 cols, per row ----
  // C/D layout: row = lg*4 + reg (+i4*16), col = lm (+j4*16).
  // d2 >= 1 always (a/b coords disjoint) -> rsq is finite; candidates only,
  // exact refine downstream fixes any ~1e-7 ordering slips.
  int jr4[4], jc4[4];
#pragma unroll
  for (int j4 = 0; j4 < 4; ++j4) {
    int tj = HH + j0 + j4 * 16 + lm;
    jr4[j4] = tj / WIDTH;
    jc4[j4] = tj % WIDTH;
  }
  unsigned long long myred[16];
#pragma unroll
  for (int i4 = 0; i4 < 4; ++i4) {
#pragma unroll
    for (int rg = 0; rg < 4; ++rg) {
      int ti = ipan + i4 * 16 + lg * 4 + rg;
      int ir = ti / WIDTH, ic = ti % WIDTH;
      float bv = -1e30f;
      int bj = 0;
#pragma unroll
      for (int j4 = 0; j4 < 4; ++j4) {  // ascending j -> first-max kept
        int dr = ir - jr4[j4], dc = ic - jc4[j4];
        float d2 = (float)(dr * dr + dc * dc);
        float sc = sw * acc[i4][j4][rg] + dwv * __builtin_amdgcn_rsqf(d2);
        int gj = j0 + j4 * 16 + lm;
        if (sc > bv) { bv = sc; bj = gj; }
      }
      myred[i4 * 4 + rg] =
          ((unsigned long long)__float_as_uint(bv + 1.0f) << 32) |
          (unsigned)(~(unsigned)bj);
    }
  }
  __syncthreads();  // all waves done reading Bt -> reuse as reduce buffer
  unsigned long long* rwv = (unsigned long long*)&Bt[0][0] + (size_t)w * 64 * 17;
#pragma unroll
  for (int m = 0; m < 16; ++m) {
    int il = (m >> 2) * 16 + lg * 4 + (m & 3);
    rwv[il * 17 + lm] = myred[m];
  }
  __syncthreads();
  // lane l owns row l: top-2 over 16 lane-maxima (u64 packed order)
  unsigned long long t1 = 0ull, t2 = 0ull;
#pragma unroll
  for (int c = 0; c < 16; ++c) {
    unsigned long long u = rwv[l * 17 + c];
    if (u > t1) { t2 = t1; t1 = u; }
    else if (u > t2) { t2 = u; }
  }
  size_t row = (size_t)b * HH + ipan + l;
  pu[row * (HH / 32) + jb * 2 + 0] = t1;
  pu[row * (HH / 32) + jb * 2 + 1] = t2;
}

// --- fused top-4 + exact fp32 refine: one wave per row -> dst --------------
template <int WIDTH, int TT, int HH, int NCH2>
__global__ __launch_bounds__(256) void topkrefine_kernel(
    const unsigned long long* __restrict__ pu, const float* __restrict__ xf,
    const float* __restrict__ nrm, const float* __restrict__ swp,
    const float* __restrict__ dwp, int* __restrict__ dst) {
  const int row = blockIdx.x * 4 + (threadIdx.x >> 6);
  const int lane = threadIdx.x & 63;
  // ---- top-4 candidates across chunks (packed u64 order) ----
  unsigned long long v = (lane < NCH2) ? pu[(size_t)row * NCH2 + lane] : 0ull;
  int candv[4];
#pragma unroll
  for (int t = 0; t < 4; ++t) {
    unsigned long long m = v;
#pragma unroll
    for (int off = 1; off < 64; off <<= 1) {
      unsigned long long o = __shfl_xor(m, off, 64);
      if (o > m) m = o;
    }
    candv[t] = (int)(~(unsigned)(m & 0xFFFFFFFFull));
    if (v == m) v = 0ull;  // packed u64 unique per j -> exact removal
  }
  // ---- exact fp32 scores for the 4 candidates; first-argmax semantics ----
  const int half = lane >> 5, ln = lane & 31;
  const int b = row / HH, i = row - b * HH;
  const float sw = swp[0], dwv = dwp[0];
  const float na = nrm[b * TT + i];
  float4 a4 = *(const float4*)&xf[((size_t)b * TT + i) * NC + ln * 4];
  a4.x /= na; a4.y /= na; a4.z /= na; a4.w /= na;
  const int ir = i / WIDTH, ic = i % WIDTH;
  float bv = -3.0e38f;
  int bj = 0x7fffffff;
#pragma unroll
  for (int c = 0; c < 4; c += 2) {
    int j = candv[c + half];
    float4 b4 = *(const float4*)&xf[((size_t)b * TT + HH + j) * NC + ln * 4];
    float p = a4.x * b4.x + a4.y * b4.y + a4.z * b4.z + a4.w * b4.w;
#pragma unroll
    for (int off = 1; off < 32; off <<= 1) p += __shfl_xor(p, off, 32);
    float nb = nrm[b * TT + HH + j];
    int tj = HH + j;
    int jr = tj / WIDTH;
    int dr = ir - jr, dc = ic - (tj - jr * WIDTH);
    float r = 1.0f / (sqrtf((float)(dr * dr + dc * dc)) + 1e-6f);
    float sc = sw * (p / nb) + dwv * r;
    if (sc > bv || (sc == bv && j < bj)) { bv = sc; bj = j; }
  }
  {
    float ov = __shfl_xor(bv, 32, 64);
    int oj = __shfl_xor(bj, 32, 64);
    if (ov > bv || (ov == bv && oj < bj)) { bv = ov; bj = oj; }
  }
  if (lane == 0) dst[row] = bj;
}

// ---------------- FALLBACK fp32 path (round-1 structure, proven) ------------
template <int WIDTH, int TT, int HH, int IT, int JC>
__global__ __launch_bounds__(256, 4) void argmax2_kernel(
    const float* __restrict__ xf, const float* __restrict__ nrm,
    const float* __restrict__ swp, const float* __restrict__ lut,
    float* __restrict__ pval, int* __restrict__ pidx) {
  constexpr int MI = IT / 16;
  constexpr int NTILE = JC / 128;
  __shared__ float At[32][IT + 4];
  __shared__ float Bt[32][132];
  __shared__ int ico[2][IT];
  __shared__ int jco[2][JC];

  const int b = blockIdx.z;
  const int it0 = blockIdx.x * IT;
  const int jb = blockIdx.y;
  const int j0g = jb * JC;
  const int tid = threadIdx.x;

  for (int t = tid; t < IT; t += 256) {
    int tok = it0 + t;
    ico[0][t] = tok / WIDTH;
    ico[1][t] = tok % WIDTH;
  }
  for (int t = tid; t < JC; t += 256) {
    int tok = HH + j0g + t;
    jco[0][t] = tok / WIDTH;
    jco[1][t] = tok % WIDTH;
  }
  const float sw = swp[0];
  const float* srcb = xf + (size_t)b * TT * NC;

  const int ty = tid >> 4, tx = tid & 15;
  const int i0l = ty * MI;
  const int j0l = tx * 8;

  float best[MI];
  int bidx[MI];
#pragma unroll
  for (int ii = 0; ii < MI; ++ii) { best[ii] = -1e30f; bidx[ii] = 0; }

  for (int jt = 0; jt < NTILE; ++jt) {
    float acc[MI][8];
#pragma unroll
    for (int ii = 0; ii < MI; ++ii)
#pragma unroll
      for (int jj = 0; jj < 8; ++jj) acc[ii][jj] = 0.f;

    for (int kc = 0; kc < 4; ++kc) {
      __syncthreads();
#pragma unroll
      for (int p = 0; p < IT / 32; ++p) {
        int f = p * 256 + tid;
        int r = f >> 3, kq = (f & 7) * 4;
        const float* row = srcb + (size_t)(it0 + r) * NC + kc * 32 + kq;
        float4 v = *(const float4*)row;
        float n = nrm[b * TT + it0 + r];
        v.x /= n; v.y /= n; v.z /= n; v.w /= n;
        At[kq + 0][r] = v.x; At[kq + 1][r] = v.y;
        At[kq + 2][r] = v.z; At[kq + 3][r] = v.w;
      }
#pragma unroll
      for (int p = 0; p < 4; ++p) {
        int f = p * 256 + tid;
        int r = f >> 3, kq = (f & 7) * 4;
        int tok = HH + j0g + jt * 128 + r;
        const float* row = srcb + (size_t)tok * NC + kc * 32 + kq;
        float4 v = *(const float4*)row;
        float n = nrm[b * TT + tok];
        v.x /= n; v.y /= n; v.z /= n; v.w /= n;
        Bt[kq + 0][r] = v.x; Bt[kq + 1][r] = v.y;
        Bt[kq + 2][r] = v.z; Bt[kq + 3][r] = v.w;
      }
      __syncthreads();

#pragma unroll 4
      for (int k = 0; k < 32; ++k) {
        float a[MI], bb[8];
#pragma unroll
        for (int qv = 0; qv < MI / 4; ++qv)
          *(float4*)&a[qv * 4] = *(const float4*)&At[k][i0l + qv * 4];
        *(float4*)&bb[0] = *(const float4*)&Bt[k][j0l];
        *(float4*)&bb[4] = *(const float4*)&Bt[k][j0l + 4];
#pragma unroll
        for (int ii = 0; ii < MI; ++ii)
#pragma unroll
          for (int jj = 0; jj < 8; ++jj) acc[ii][jj] += a[ii] * bb[jj];
      }
    }

#pragma unroll
    for (int ii = 0; ii < MI; ++ii) {
      int ir = ico[0][i0l + ii], ic = ico[1][i0l + ii];
#pragma unroll
      for (int jj = 0; jj < 8; ++jj) {
        int jl = jt * 128 + j0l + jj;
        int dr = ir - jco[0][jl];
        int dc = ic - jco[1][jl];
        float sc = sw * acc[ii][jj] + lut[dr * dr + dc * dc];
        if (sc > best[ii]) {
          best[ii] = sc;
          bidx[ii] = j0g + jl;
        }
      }
    }
  }

  __syncthreads();
  float* rv = &At[0][0];
  int* rj = (int*)&Bt[0][0];
#pragma unroll
  for (int ii = 0; ii < MI; ++ii) {
    rv[(i0l + ii) * 17 + tx] = best[ii];
    rj[(i0l + ii) * 17 + tx] = bidx[ii];
  }
  __syncthreads();
  if (tid < IT) {
    float bv = rv[tid * 17];
    int bj = rj[tid * 17];
    for (int t = 1; t < 16; ++t) {
      float v = rv[tid * 17 + t];
      int j = rj[tid * 17 + t];
      if (v > bv || (v == bv && j < bj)) { bv = v; bj = j; }
    }
    int row = b * HH + it0 + tid;
    pval[(size_t)row * 8 + jb] = bv;
    pidx[(size_t)row * 8 + jb] = bj;
  }
}

__global__ void argreduce_kernel(const float* __restrict__ pv,
                                 const int* __restrict__ pj,
                                 int* __restrict__ dst, int nrows, int w) {
  int r = blockIdx.x * 256 + threadIdx.x;
  if (r >= nrows) return;
  const float* vv = pv + (size_t)r * w;
  const int* jj = pj + (size_t)r * w;
  float bv = vv[0];
  int bj = jj[0];
  for (int t = 1; t < w; ++t) {
    float v = vv[t];
    int j = jj[t];
    if (v > bv || (v == bv && j < bj)) { bv = v; bj = j; }
  }
  dst[r] = bj;
}

// -------- merge: out = b-half copy, then atomic scatter of a rows, divide ---
__global__ void copy_init_kernel(const float* __restrict__ src,
                                 float* __restrict__ dstbuf,
                                 float* __restrict__ cnt, int HH, int TT) {
  size_t idx = (size_t)blockIdx.x * 256 + threadIdx.x;
  size_t total = (size_t)NB * HH * 32;
  if (idx >= total) return;
  size_t row = idx >> 5;
  int e = (int)(idx & 31) * 4;
  int b = (int)(row / HH), j = (int)(row % HH);
  float4 v = *(const float4*)&src[((size_t)b * TT + HH + j) * NC + e];
  *(float4*)&dstbuf[row * NC + e] = v;
  if (e == 0) cnt[row] = 1.0f;
}

__global__ void scatter_kernel(const float* __restrict__ src,
                               const int* __restrict__ dst,
                               float* __restrict__ accbuf,
                               float* __restrict__ cnt, int HH, int TT) {
  size_t idx = (size_t)blockIdx.x * 256 + threadIdx.x;
  size_t total = (size_t)NB * HH * 32;
  if (idx >= total) return;
  size_t row = idx >> 5;
  int e = (int)(idx & 31) * 4;
  int b = (int)(row / HH), i = (int)(row % HH);
  float4 v = *(const float4*)&src[((size_t)b * TT + i) * NC + e];
  int d = dst[row];
  float* base = &accbuf[((size_t)b * HH + d) * NC + e];
  atomicAdd(base + 0, v.x);
  atomicAdd(base + 1, v.y);
  atomicAdd(base + 2, v.z);
  atomicAdd(base + 3, v.w);
  if (e == 0) atomicAdd(&cnt[(size_t)b * HH + d], 1.0f);
}

// finalize: divide by counts; optionally emit nrm + ext rows (p=128 enc) -----
__global__ void finalize_kernel(float* __restrict__ buf,
                                const float* __restrict__ cnt,
                                float* __restrict__ nrm,
                                _Float16* __restrict__ ext, int HH2) {
  int row = blockIdx.x * 2 + (threadIdx.x >> 7);
  int c = threadIdx.x & 127;
  float v = buf[(size_t)row * NC + c] / cnt[row];
  buf[(size_t)row * NC + c] = v;
  if (nrm != nullptr) {
    float s = v * v;
    for (int off = 32; off > 0; off >>= 1) s += __shfl_down(s, off, 64);
    __shared__ float p[4];
    __shared__ float ns[2];
    int w = threadIdx.x >> 6;
    if ((threadIdx.x & 63) == 0) p[w] = s;
    __syncthreads();
    if ((threadIdx.x & 127) == 0) {
      float n = sqrtf(p[w] + p[w + 1]);
      nrm[row] = n;
      ns[threadIdx.x >> 7] = n;
    }
    __syncthreads();
    if (ext != nullptr) {
      float n = ns[threadIdx.x >> 7];
      float m = v / n;
      _Float16 h = (_Float16)m;
      float hf = (float)h;
      _Float16 ep = (_Float16)((m - hf) * 128.0f);
      _Float16 hs = (_Float16)(hf * 0.0078125f);
      int t = row & (2 * HH2 - 1);
      bool isA = t < HH2;
      _Float16* rw = ext + (size_t)row * 384;
      rw[c] = h;
      rw[128 + c] = isA ? ep : hs;
      rw[256 + c] = isA ? hs : ep;
    }
  }
}

// ---------------- 1x1 conv (128x128) + BN + SiLU -> out (B,128,32,32) -------
__global__ __launch_bounds__(256) void conv_bn_silu_kernel(
    const float* __restrict__ xf3, const float* __restrict__ w,
    const float* __restrict__ gamma, const float* __restrict__ beta,
    const float* __restrict__ mean, const float* __restrict__ var,
    float* __restrict__ out) {
  __shared__ float X[64][132];
  __shared__ float Wt[128][68];
  const int b = blockIdx.y, p0 = blockIdx.x * 64;
  const int tid = threadIdx.x, lane = tid & 63, q = tid >> 6;
  {
    const float* row = xf3 + ((size_t)b * 1024 + p0 + lane) * NC;
    for (int cc = 0; cc < 8; ++cc) {
      int c = q * 32 + cc * 4;
      *(float4*)&X[lane][c] = *(const float4*)&row[c];
    }
  }
  const int ti = tid >> 4, tj = tid & 15;
  const int i4 = ti * 4, j4 = tj * 4;
  for (int ot = 0; ot < 2; ++ot) {
    __syncthreads();
    {
      const float* row = w + (size_t)(ot * 64 + lane) * NC;
      for (int cc = 0; cc < 8; ++cc) {
        int c = q * 32 + cc * 4;
        float4 v = *(const float4*)&row[c];
        Wt[c + 0][lane] = v.x;
        Wt[c + 1][lane] = v.y;
        Wt[c + 2][lane] = v.z;
        Wt[c + 3][lane] = v.w;
      }
    }
    __syncthreads();
    float acc[4][4];
#pragma unroll
    for (int ii = 0; ii < 4; ++ii)
#pragma unroll
      for (int jj = 0; jj < 4; ++jj) acc[ii][jj] = 0.f;

    for (int k = 0; k < NC; k += 4) {
      float4 a0 = *(const float4*)&X[i4 + 0][k];
      float4 a1 = *(const float4*)&X[i4 + 1][k];
      float4 a2 = *(const float4*)&X[i4 + 2][k];
      float4 a3 = *(const float4*)&X[i4 + 3][k];
      float4 b0 = *(const float4*)&Wt[k + 0][j4];
      float4 b1 = *(const float4*)&Wt[k + 1][j4];
      float4 b2 = *(const float4*)&Wt[k + 2][j4];
      float4 b3 = *(const float4*)&Wt[k + 3][j4];
#define FMA16(AX, BV)                                                     \
  acc[0][0] += a0.AX * BV.x; acc[0][1] += a0.AX * BV.y;                   \
  acc[0][2] += a0.AX * BV.z; acc[0][3] += a0.AX * BV.w;                   \
  acc[1][0] += a1.AX * BV.x; acc[1][1] += a1.AX * BV.y;                   \
  acc[1][2] += a1.AX * BV.z; acc[1][3] += a1.AX * BV.w;                   \
  acc[2][0] += a2.AX * BV.x; acc[2][1] += a2.AX * BV.y;                   \
  acc[2][2] += a2.AX * BV.z; acc[2][3] += a2.AX * BV.w;                   \
  acc[3][0] += a3.AX * BV.x; acc[3][1] += a3.AX * BV.y;                   \
  acc[3][2] += a3.AX * BV.z; acc[3][3] += a3.AX * BV.w;
      FMA16(x, b0)
      FMA16(y, b1)
      FMA16(z, b2)
      FMA16(w, b3)
#undef FMA16
    }

#pragma unroll
    for (int jj = 0; jj < 4; ++jj) {
      int o = ot * 64 + j4 + jj;
      float sc = gamma[o] / sqrtf(var[o] + 1e-5f);
      float mn = mean[o], bt = beta[o];
      float4 r;
      float z;
      z = (acc[0][jj] - mn) * sc + bt; r.x = z / (1.f + expf(-z));
      z = (acc[1][jj] - mn) * sc + bt; r.y = z / (1.f + expf(-z));
      z = (acc[2][jj] - mn) * sc + bt; r.z = z / (1.f + expf(-z));
      z = (acc[3][jj] - mn) * sc + bt; r.w = z / (1.f + expf(-z));
      *(float4*)&out[((size_t)(b * NC + o)) * 1024 + p0 + i4] = r;
    }
  }
}

extern "C" void kernel_launch(void* const* d_in, const int* in_sizes, int n_in,
                              void* d_out, int out_size, void* d_ws,
                              size_t ws_size, hipStream_t stream) {
  const float* x = (const float*)d_in[0];
  const float* swp = (const float*)d_in[1];
  const float* dwp = (const float*)d_in[2];
  const float* convw = (const float*)d_in[3];
  const float* gamma = (const float*)d_in[4];
  const float* beta = (const float*)d_in[5];
  const float* mean = (const float*)d_in[6];
  const float* var = (const float*)d_in[7];
  float* out = (float*)d_out;

  float* ws = (float*)d_ws;
  size_t o = 0;
  float* xf1 = ws + o;  o += (size_t)8 * 4096 * 128;  // reused as xf3
  float* nrm1 = ws + o; o += 8 * 4096;
  float* xf2 = ws + o;  o += (size_t)8 * 2048 * 128;
  float* nrm2 = ws + o; o += 8 * 2048;
  float* cnt1 = ws + o; o += 8 * 2048;
  float* cnt2 = ws + o; o += 8 * 1024;
  int* dst1 = (int*)(ws + o); o += 8 * 2048;
  int* dst2 = (int*)(ws + o); o += 8 * 1024;
  int* cand1 = (int*)(ws + o); o += (size_t)8 * 2048 * 4;
  int* cand2 = (int*)(ws + o); o += (size_t)8 * 1024 * 4;
  float* lut = ws + o;  o += 8192;
  _Float16* ext1 = (_Float16*)(ws + o);
  _Float16* ext2 = ext1;  // ext1 dead after merge-1 candidate pass
  const size_t ext_floats = (size_t)8 * 4096 * 384 / 2;
  const bool mfma_ok = ws_size >= (o + ext_floats) * sizeof(float);
  float* xf3 = xf1;  // alias: xf1 dead before xf3 written
  (void)cand1; (void)cand2;
  // aliases into dead regions (lifetimes verified):
  // pu1 -> xf2 region (xf2 written only later, by copy_init after topkrefine)
  unsigned long long* pu1 = (unsigned long long*)xf2;
  // pu2 -> xf1 region (xf1/a-rows dead after merge-1 scatter; xf3 written later)
  unsigned long long* pu2 = (unsigned long long*)xf1;
  float* pv1 = xf2;
  int* pj1 = (int*)(xf2 + 8 * 2048 * 8);
  float* pv2 = xf1;
  int* pj2 = (int*)(xf1 + 8 * 1024 * 8);

  // ---- merge 1: T=4096, H=2048, width=64 ----
  prep_kernel<<<dim3(64, 8), 256, 0, stream>>>(x, xf1, nrm1,
                                               mfma_ok ? ext1 : nullptr);
  if (mfma_ok) {
    argmax_mfma4_kernel<64, 4096, 2048>
        <<<dim3(32, 8, 8), 256, 0, stream>>>(ext1, swp, dwp, pu1);
    topkrefine_kernel<64, 4096, 2048, 64>
        <<<4096, 256, 0, stream>>>(pu1, xf1, nrm1, swp, dwp, dst1);
  } else {
    lut_kernel<<<32, 256, 0, stream>>>(lut, dwp, 7939);
    argmax2_kernel<64, 4096, 2048, 128, 256>
        <<<dim3(16, 8, 8), 256, 0, stream>>>(xf1, nrm1, swp, lut, pv1, pj1);
    argreduce_kernel<<<64, 256, 0, stream>>>(pv1, pj1, dst1, 8 * 2048, 8);
  }
  copy_init_kernel<<<2048, 256, 0, stream>>>(xf1, xf2, cnt1, 2048, 4096);
  scatter_kernel<<<2048, 256, 0, stream>>>(xf1, dst1, xf2, cnt1, 2048, 4096);
  finalize_kernel<<<8192, 256, 0, stream>>>(xf2, cnt1, nrm2,
                                            mfma_ok ? ext2 : nullptr, 1024);

  // ---- merge 2: T=2048, H=1024, width=int(sqrt(2048))=45 ----
  if (mfma_ok) {
    argmax_mfma4_kernel<45, 2048, 1024>
        <<<dim3(16, 4, 8), 256, 0, stream>>>(ext2, swp, dwp, pu2);
    topkrefine_kernel<45, 2048, 1024, 32>
        <<<2048, 256, 0, stream>>>(pu2, xf2, nrm2, swp, dwp, dst2);
  } else {
    argmax2_kernel<45, 2048, 1024, 64, 128>
        <<<dim3(16, 8, 8), 256, 0, stream>>>(xf2, nrm2, swp, lut, pv2, pj2);
    argreduce_kernel<<<32, 256, 0, stream>>>(pv2, pj2, dst2, 8 * 1024, 8);
  }
  copy_init_kernel<<<1024, 256, 0, stream>>>(xf2, xf3, cnt2, 1024, 2048);
  scatter_kernel<<<1024, 256, 0, stream>>>(xf2, dst2, xf3, cnt2, 1024, 2048);
  finalize_kernel<<<4096, 256, 0, stream>>>(xf3, cnt2, nullptr, nullptr, 512);

  // ---- 1x1 conv + BN + SiLU ----
  conv_bn_silu_kernel<<<dim3(16, 8), 256, 0, stream>>>(
      xf3, convw, gamma, beta, mean, var, out);
}

// Round 9
// 178.742 us; speedup vs baseline: 2.5098x; 1.1366x over previous
//
#include <hip/hip_runtime.h>
#include <math.h>

#define NB 8
#define NC 128

typedef _Float16 hf8 __attribute__((ext_vector_type(8)));
typedef float fx4 __attribute__((ext_vector_type(4)));

// ---------------- LUT: lut[d2] = dw * (1/(sqrt(d2)+1e-6)) (fallback only) ---
__global__ void lut_kernel(float* __restrict__ lut, const float* __restrict__ dwp,
                           int n) {
  int i = blockIdx.x * 256 + threadIdx.x;
  if (i < n) {
    float r = 1.0f / (sqrtf((float)i) + 1e-6f);
    lut[i] = dwp[0] * r;
  }
}

// ---- prep: x (B,C,4096) -> xf1, nrm1, ext1 (B,4096,256 fp16, K=256 enc) ----
// a-token row: [h | e] (e=(m-h)*128)   b-token row: [h | h/128]
__global__ void prep_kernel(const float* __restrict__ x, float* __restrict__ xf,
                            float* __restrict__ nrm, _Float16* __restrict__ ext) {
  __shared__ float tile[64][129];
  __shared__ float part[64][4];
  __shared__ float rn_s[64];
  const int b = blockIdx.y;
  const int p0 = blockIdx.x * 64;
  const int tid = threadIdx.x;
  const int lane = tid & 63;
  const int q = tid >> 6;
  for (int cc = 0; cc < 32; ++cc) {
    int c = q * 32 + cc;
    tile[lane][c] = x[((size_t)(b * NC + c)) * 4096 + p0 + lane];
  }
  __syncthreads();
  float s = 0.f;
  for (int cc = 0; cc < 32; ++cc) {
    float v = tile[lane][q * 32 + cc];
    s += v * v;
  }
  part[lane][q] = s;
  __syncthreads();
  if (tid < 64) {
    float n = sqrtf(part[tid][0] + part[tid][1] + part[tid][2] + part[tid][3]);
    nrm[b * 4096 + p0 + tid] = n;
    rn_s[tid] = n;
  }
  __syncthreads();
  for (int it = 0; it < 8; ++it) {
    int idx = it * 256 + tid;
    int r = idx >> 5, e = (idx & 31) * 4;
    float4 v = make_float4(tile[r][e], tile[r][e + 1], tile[r][e + 2], tile[r][e + 3]);
    size_t o = (((size_t)b * 4096 + p0 + r) << 7) + e;
    *(float4*)&xf[o] = v;
    if (ext != nullptr) {
      float n = rn_s[r];
      int tok = p0 + r;
      bool isA = tok < 2048;
      _Float16* rw = ext + ((size_t)b * 4096 + tok) * 256;
      float mm[4] = {v.x / n, v.y / n, v.z / n, v.w / n};
#pragma unroll
      for (int u = 0; u < 4; ++u) {
        float m = mm[u];
        _Float16 h = (_Float16)m;
        float hf = (float)h;
        _Float16 ep = (_Float16)((m - hf) * 128.0f);
        _Float16 hs = (_Float16)(hf * 0.0078125f);
        rw[e + u] = h;
        rw[128 + e + u] = isA ? ep : hs;
      }
    }
  }
}

// ------ MFMA candidate kernel: B-stationary LDS, A global->reg, K=256 -------
// Block: 4 waves, each wave = 64i x 64j. 4 blocks/CU (35.8KB LDS, <=128 VGPR).
// Grid: x = jb (A-panel L2 reuse), y = ib, z = batch.
// Emits packed u64 top-2 per (row, 64-j chunk).
template <int WIDTH, int TT, int HH>
__global__ __launch_bounds__(256, 4) void argmax_mfma5_kernel(
    const _Float16* __restrict__ ext, const float* __restrict__ swp,
    const float* __restrict__ dwp, unsigned long long* __restrict__ pu) {
  __shared__ _Float16 Bt[64][280];  // 35840 B; reused as reduce buffer
  const int b = blockIdx.z;
  const int ib = blockIdx.y;
  const int jb = blockIdx.x;
  const int tid = threadIdx.x;
  const int w = tid >> 6, l = tid & 63;
  const int lg = l >> 4, lm = l & 15;
  const int ipan = ib * 256 + w * 64;
  const int j0 = jb * 64;
  const float sw = swp[0], dwv = dwp[0];
  const _Float16* extb = ext + (size_t)b * TT * 256;
  const _Float16* brow0 = extb + (size_t)(HH + j0) * 256;

  const _Float16* ap[4];
#pragma unroll
  for (int s = 0; s < 4; ++s)
    ap[s] = extb + (size_t)(ipan + s * 16 + lm) * 256 + lg * 8;

  // stage B tile once: 64 rows x 256 halfs
  for (int f = tid; f < 64 * 32; f += 256) {
    int r = f >> 5, c = f & 31;
    *(float4*)&Bt[r][c * 8] = *(const float4*)&brow0[(size_t)r * 256 + c * 8];
  }
  __syncthreads();

  fx4 acc[4][4];
#pragma unroll
  for (int i4 = 0; i4 < 4; ++i4)
#pragma unroll
    for (int j4 = 0; j4 < 4; ++j4) acc[i4][j4] = 0.f;

#pragma unroll
  for (int kc = 0; kc < 8; ++kc) {
    hf8 af[4], bf[4];
#pragma unroll
    for (int s = 0; s < 4; ++s)
      af[s] = *(const hf8*)(ap[s] + kc * 32);
#pragma unroll
    for (int s = 0; s < 4; ++s)
      bf[s] = *(const hf8*)&Bt[s * 16 + lm][kc * 32 + lg * 8];
    __builtin_amdgcn_s_setprio(1);
#pragma unroll
    for (int j4 = 0; j4 < 4; ++j4)
#pragma unroll
      for (int i4 = 0; i4 < 4; ++i4)
        acc[i4][j4] = __builtin_amdgcn_mfma_f32_16x16x32_f16(
            af[i4], bf[j4], acc[i4][j4], 0, 0, 0);
    __builtin_amdgcn_s_setprio(0);
  }

  // ---- epilogue: per-lane first-max over its 4 cols, per row ----
  // C/D layout: row = lg*4 + reg (+i4*16), col = lm (+j4*16).
  // d2 >= 1 always (distinct integer coords) -> rsq finite; candidates only,
  // exact refine downstream fixes any tiny ordering slips.
  int jr4[4], jc4[4];
#pragma unroll
  for (int j4 = 0; j4 < 4; ++j4) {
    int tj = HH + j0 + j4 * 16 + lm;
    jr4[j4] = tj / WIDTH;
    jc4[j4] = tj % WIDTH;
  }
  __syncthreads();  // all waves done reading Bt -> reuse as reduce buffer
  unsigned long long* rwv = (unsigned long long*)&Bt[0][0] + (size_t)w * 64 * 17;
#pragma unroll
  for (int i4 = 0; i4 < 4; ++i4) {
#pragma unroll
    for (int rg = 0; rg < 4; ++rg) {
      int il = i4 * 16 + lg * 4 + rg;
      int ti = ipan + il;
      int ir = ti / WIDTH, ic = ti % WIDTH;
      float bv = -1e30f;
      int bj = 0;
#pragma unroll
      for (int j4 = 0; j4 < 4; ++j4) {  // ascending j -> first-max kept
        int dr = ir - jr4[j4], dc = ic - jc4[j4];
        float d2 = (float)(dr * dr + dc * dc);
        float sc = sw * acc[i4][j4][rg] + dwv * __builtin_amdgcn_rsqf(d2);
        int gj = j0 + j4 * 16 + lm;
        if (sc > bv) { bv = sc; bj = gj; }
      }
      rwv[il * 17 + lm] =
          ((unsigned long long)__float_as_uint(bv + 1.0f) << 32) |
          (unsigned)(~(unsigned)bj);
    }
  }
  __syncthreads();
  // lane l owns row l: top-2 over 16 lane-maxima (u64 packed order)
  unsigned long long t1 = 0ull, t2 = 0ull;
#pragma unroll
  for (int c = 0; c < 16; ++c) {
    unsigned long long u = rwv[l * 17 + c];
    if (u > t1) { t2 = t1; t1 = u; }
    else if (u > t2) { t2 = u; }
  }
  size_t row = (size_t)b * HH + ipan + l;
  pu[row * (HH / 32) + jb * 2 + 0] = t1;
  pu[row * (HH / 32) + jb * 2 + 1] = t2;
}

// --- fused top-4 + exact fp32 refine: one wave per row -> dst --------------
template <int WIDTH, int TT, int HH, int NCH2>
__global__ __launch_bounds__(256) void topkrefine_kernel(
    const unsigned long long* __restrict__ pu, const float* __restrict__ xf,
    const float* __restrict__ nrm, const float* __restrict__ swp,
    const float* __restrict__ dwp, int* __restrict__ dst) {
  const int row = blockIdx.x * 4 + (threadIdx.x >> 6);
  const int lane = threadIdx.x & 63;
  // ---- top-4 candidates across chunks (packed u64 order) ----
  unsigned long long v = (lane < NCH2) ? pu[(size_t)row * NCH2 + lane] : 0ull;
  int candv[4];
#pragma unroll
  for (int t = 0; t < 4; ++t) {
    unsigned long long m = v;
#pragma unroll
    for (int off = 1; off < 64; off <<= 1) {
      unsigned long long o = __shfl_xor(m, off, 64);
      if (o > m) m = o;
    }
    candv[t] = (int)(~(unsigned)(m & 0xFFFFFFFFull));
    if (v == m) v = 0ull;  // packed u64 unique per j -> exact removal
  }
  // ---- exact fp32 scores for the 4 candidates; first-argmax semantics ----
  const int half = lane >> 5, ln = lane & 31;
  const int b = row / HH, i = row - b * HH;
  const float sw = swp[0], dwv = dwp[0];
  const float na = nrm[b * TT + i];
  float4 a4 = *(const float4*)&xf[((size_t)b * TT + i) * NC + ln * 4];
  a4.x /= na; a4.y /= na; a4.z /= na; a4.w /= na;
  const int ir = i / WIDTH, ic = i % WIDTH;
  float bv = -3.0e38f;
  int bj = 0x7fffffff;
#pragma unroll
  for (int c = 0; c < 4; c += 2) {
    int j = candv[c + half];
    float4 b4 = *(const float4*)&xf[((size_t)b * TT + HH + j) * NC + ln * 4];
    float p = a4.x * b4.x + a4.y * b4.y + a4.z * b4.z + a4.w * b4.w;
#pragma unroll
    for (int off = 1; off < 32; off <<= 1) p += __shfl_xor(p, off, 32);
    float nb = nrm[b * TT + HH + j];
    int tj = HH + j;
    int jr = tj / WIDTH;
    int dr = ir - jr, dc = ic - (tj - jr * WIDTH);
    float r = 1.0f / (sqrtf((float)(dr * dr + dc * dc)) + 1e-6f);
    float sc = sw * (p / nb) + dwv * r;
    if (sc > bv || (sc == bv && j < bj)) { bv = sc; bj = j; }
  }
  {
    float ov = __shfl_xor(bv, 32, 64);
    int oj = __shfl_xor(bj, 32, 64);
    if (ov > bv || (ov == bv && oj < bj)) { bv = ov; bj = oj; }
  }
  if (lane == 0) dst[row] = bj;
}

// ---------------- FALLBACK fp32 path (round-1 structure, proven) ------------
template <int WIDTH, int TT, int HH, int IT, int JC>
__global__ __launch_bounds__(256, 4) void argmax2_kernel(
    const float* __restrict__ xf, const float* __restrict__ nrm,
    const float* __restrict__ swp, const float* __restrict__ lut,
    float* __restrict__ pval, int* __restrict__ pidx) {
  constexpr int MI = IT / 16;
  constexpr int NTILE = JC / 128;
  __shared__ float At[32][IT + 4];
  __shared__ float Bt[32][132];
  __shared__ int ico[2][IT];
  __shared__ int jco[2][JC];

  const int b = blockIdx.z;
  const int it0 = blockIdx.x * IT;
  const int jb = blockIdx.y;
  const int j0g = jb * JC;
  const int tid = threadIdx.x;

  for (int t = tid; t < IT; t += 256) {
    int tok = it0 + t;
    ico[0][t] = tok / WIDTH;
    ico[1][t] = tok % WIDTH;
  }
  for (int t = tid; t < JC; t += 256) {
    int tok = HH + j0g + t;
    jco[0][t] = tok / WIDTH;
    jco[1][t] = tok % WIDTH;
  }
  const float sw = swp[0];
  const float* srcb = xf + (size_t)b * TT * NC;

  const int ty = tid >> 4, tx = tid & 15;
  const int i0l = ty * MI;
  const int j0l = tx * 8;

  float best[MI];
  int bidx[MI];
#pragma unroll
  for (int ii = 0; ii < MI; ++ii) { best[ii] = -1e30f; bidx[ii] = 0; }

  for (int jt = 0; jt < NTILE; ++jt) {
    float acc[MI][8];
#pragma unroll
    for (int ii = 0; ii < MI; ++ii)
#pragma unroll
      for (int jj = 0; jj < 8; ++jj) acc[ii][jj] = 0.f;

    for (int kc = 0; kc < 4; ++kc) {
      __syncthreads();
#pragma unroll
      for (int p = 0; p < IT / 32; ++p) {
        int f = p * 256 + tid;
        int r = f >> 3, kq = (f & 7) * 4;
        const float* row = srcb + (size_t)(it0 + r) * NC + kc * 32 + kq;
        float4 v = *(const float4*)row;
        float n = nrm[b * TT + it0 + r];
        v.x /= n; v.y /= n; v.z /= n; v.w /= n;
        At[kq + 0][r] = v.x; At[kq + 1][r] = v.y;
        At[kq + 2][r] = v.z; At[kq + 3][r] = v.w;
      }
#pragma unroll
      for (int p = 0; p < 4; ++p) {
        int f = p * 256 + tid;
        int r = f >> 3, kq = (f & 7) * 4;
        int tok = HH + j0g + jt * 128 + r;
        const float* row = srcb + (size_t)tok * NC + kc * 32 + kq;
        float4 v = *(const float4*)row;
        float n = nrm[b * TT + tok];
        v.x /= n; v.y /= n; v.z /= n; v.w /= n;
        Bt[kq + 0][r] = v.x; Bt[kq + 1][r] = v.y;
        Bt[kq + 2][r] = v.z; Bt[kq + 3][r] = v.w;
      }
      __syncthreads();

#pragma unroll 4
      for (int k = 0; k < 32; ++k) {
        float a[MI], bb[8];
#pragma unroll
        for (int qv = 0; qv < MI / 4; ++qv)
          *(float4*)&a[qv * 4] = *(const float4*)&At[k][i0l + qv * 4];
        *(float4*)&bb[0] = *(const float4*)&Bt[k][j0l];
        *(float4*)&bb[4] = *(const float4*)&Bt[k][j0l + 4];
#pragma unroll
        for (int ii = 0; ii < MI; ++ii)
#pragma unroll
          for (int jj = 0; jj < 8; ++jj) acc[ii][jj] += a[ii] * bb[jj];
      }
    }

#pragma unroll
    for (int ii = 0; ii < MI; ++ii) {
      int ir = ico[0][i0l + ii], ic = ico[1][i0l + ii];
#pragma unroll
      for (int jj = 0; jj < 8; ++jj) {
        int jl = jt * 128 + j0l + jj;
        int dr = ir - jco[0][jl];
        int dc = ic - jco[1][jl];
        float sc = sw * acc[ii][jj] + lut[dr * dr + dc * dc];
        if (sc > best[ii]) {
          best[ii] = sc;
          bidx[ii] = j0g + jl;
        }
      }
    }
  }

  __syncthreads();
  float* rv = &At[0][0];
  int* rj = (int*)&Bt[0][0];
#pragma unroll
  for (int ii = 0; ii < MI; ++ii) {
    rv[(i0l + ii) * 17 + tx] = best[ii];
    rj[(i0l + ii) * 17 + tx] = bidx[ii];
  }
  __syncthreads();
  if (tid < IT) {
    float bv = rv[tid * 17];
    int bj = rj[tid * 17];
    for (int t = 1; t < 16; ++t) {
      float v = rv[tid * 17 + t];
      int j = rj[tid * 17 + t];
      if (v > bv || (v == bv && j < bj)) { bv = v; bj = j; }
    }
    int row = b * HH + it0 + tid;
    pval[(size_t)row * 8 + jb] = bv;
    pidx[(size_t)row * 8 + jb] = bj;
  }
}

__global__ void argreduce_kernel(const float* __restrict__ pv,
                                 const int* __restrict__ pj,
                                 int* __restrict__ dst, int nrows, int w) {
  int r = blockIdx.x * 256 + threadIdx.x;
  if (r >= nrows) return;
  const float* vv = pv + (size_t)r * w;
  const int* jj = pj + (size_t)r * w;
  float bv = vv[0];
  int bj = jj[0];
  for (int t = 1; t < w; ++t) {
    float v = vv[t];
    int j = jj[t];
    if (v > bv || (v == bv && j < bj)) { bv = v; bj = j; }
  }
  dst[r] = bj;
}

// -------- merge: out = b-half copy, then atomic scatter of a rows, divide ---
__global__ void copy_init_kernel(const float* __restrict__ src,
                                 float* __restrict__ dstbuf,
                                 float* __restrict__ cnt, int HH, int TT) {
  size_t idx = (size_t)blockIdx.x * 256 + threadIdx.x;
  size_t total = (size_t)NB * HH * 32;
  if (idx >= total) return;
  size_t row = idx >> 5;
  int e = (int)(idx & 31) * 4;
  int b = (int)(row / HH), j = (int)(row % HH);
  float4 v = *(const float4*)&src[((size_t)b * TT + HH + j) * NC + e];
  *(float4*)&dstbuf[row * NC + e] = v;
  if (e == 0) cnt[row] = 1.0f;
}

__global__ void scatter_kernel(const float* __restrict__ src,
                               const int* __restrict__ dst,
                               float* __restrict__ accbuf,
                               float* __restrict__ cnt, int HH, int TT) {
  size_t idx = (size_t)blockIdx.x * 256 + threadIdx.x;
  size_t total = (size_t)NB * HH * 32;
  if (idx >= total) return;
  size_t row = idx >> 5;
  int e = (int)(idx & 31) * 4;
  int b = (int)(row / HH), i = (int)(row % HH);
  float4 v = *(const float4*)&src[((size_t)b * TT + i) * NC + e];
  int d = dst[row];
  float* base = &accbuf[((size_t)b * HH + d) * NC + e];
  atomicAdd(base + 0, v.x);
  atomicAdd(base + 1, v.y);
  atomicAdd(base + 2, v.z);
  atomicAdd(base + 3, v.w);
  if (e == 0) atomicAdd(&cnt[(size_t)b * HH + d], 1.0f);
}

// finalize: divide by counts; optionally emit nrm + ext rows (K=256 enc) -----
__global__ void finalize_kernel(float* __restrict__ buf,
                                const float* __restrict__ cnt,
                                float* __restrict__ nrm,
                                _Float16* __restrict__ ext, int HH2) {
  int row = blockIdx.x * 2 + (threadIdx.x >> 7);
  int c = threadIdx.x & 127;
  float v = buf[(size_t)row * NC + c] / cnt[row];
  buf[(size_t)row * NC + c] = v;
  if (nrm != nullptr) {
    float s = v * v;
    for (int off = 32; off > 0; off >>= 1) s += __shfl_down(s, off, 64);
    __shared__ float p[4];
    __shared__ float ns[2];
    int w = threadIdx.x >> 6;
    if ((threadIdx.x & 63) == 0) p[w] = s;
    __syncthreads();
    if ((threadIdx.x & 127) == 0) {
      float n = sqrtf(p[w] + p[w + 1]);
      nrm[row] = n;
      ns[threadIdx.x >> 7] = n;
    }
    __syncthreads();
    if (ext != nullptr) {
      float n = ns[threadIdx.x >> 7];
      float m = v / n;
      _Float16 h = (_Float16)m;
      float hf = (float)h;
      _Float16 ep = (_Float16)((m - hf) * 128.0f);
      _Float16 hs = (_Float16)(hf * 0.0078125f);
      int t = row & (2 * HH2 - 1);
      bool isA = t < HH2;
      _Float16* rw = ext + (size_t)row * 256;
      rw[c] = h;
      rw[128 + c] = isA ? ep : hs;
    }
  }
}

// ---------------- 1x1 conv (128x128) + BN + SiLU -> out (B,128,32,32) -------
__global__ __launch_bounds__(256) void conv_bn_silu_kernel(
    const float* __restrict__ xf3, const float* __restrict__ w,
    const float* __restrict__ gamma, const float* __restrict__ beta,
    const float* __restrict__ mean, const float* __restrict__ var,
    float* __restrict__ out) {
  __shared__ float X[64][132];
  __shared__ float Wt[128][68];
  const int b = blockIdx.y, p0 = blockIdx.x * 64;
  const int tid = threadIdx.x, lane = tid & 63, q = tid >> 6;
  {
    const float* row = xf3 + ((size_t)b * 1024 + p0 + lane) * NC;
    for (int cc = 0; cc < 8; ++cc) {
      int c = q * 32 + cc * 4;
      *(float4*)&X[lane][c] = *(const float4*)&row[c];
    }
  }
  const int ti = tid >> 4, tj = tid & 15;
  const int i4 = ti * 4, j4 = tj * 4;
  for (int ot = 0; ot < 2; ++ot) {
    __syncthreads();
    {
      const float* row = w + (size_t)(ot * 64 + lane) * NC;
      for (int cc = 0; cc < 8; ++cc) {
        int c = q * 32 + cc * 4;
        float4 v = *(const float4*)&row[c];
        Wt[c + 0][lane] = v.x;
        Wt[c + 1][lane] = v.y;
        Wt[c + 2][lane] = v.z;
        Wt[c + 3][lane] = v.w;
      }
    }
    __syncthreads();
    float acc[4][4];
#pragma unroll
    for (int ii = 0; ii < 4; ++ii)
#pragma unroll
      for (int jj = 0; jj < 4; ++jj) acc[ii][jj] = 0.f;

    for (int k = 0; k < NC; k += 4) {
      float4 a0 = *(const float4*)&X[i4 + 0][k];
      float4 a1 = *(const float4*)&X[i4 + 1][k];
      float4 a2 = *(const float4*)&X[i4 + 2][k];
      float4 a3 = *(const float4*)&X[i4 + 3][k];
      float4 b0 = *(const float4*)&Wt[k + 0][j4];
      float4 b1 = *(const float4*)&Wt[k + 1][j4];
      float4 b2 = *(const float4*)&Wt[k + 2][j4];
      float4 b3 = *(const float4*)&Wt[k + 3][j4];
#define FMA16(AX, BV)                                                     \
  acc[0][0] += a0.AX * BV.x; acc[0][1] += a0.AX * BV.y;                   \
  acc[0][2] += a0.AX * BV.z; acc[0][3] += a0.AX * BV.w;                   \
  acc[1][0] += a1.AX * BV.x; acc[1][1] += a1.AX * BV.y;                   \
  acc[1][2] += a1.AX * BV.z; acc[1][3] += a1.AX * BV.w;                   \
  acc[2][0] += a2.AX * BV.x; acc[2][1] += a2.AX * BV.y;                   \
  acc[2][2] += a2.AX * BV.z; acc[2][3] += a2.AX * BV.w;                   \
  acc[3][0] += a3.AX * BV.x; acc[3][1] += a3.AX * BV.y;                   \
  acc[3][2] += a3.AX * BV.z; acc[3][3] += a3.AX * BV.w;
      FMA16(x, b0)
      FMA16(y, b1)
      FMA16(z, b2)
      FMA16(w, b3)
#undef FMA16
    }

#pragma unroll
    for (int jj = 0; jj < 4; ++jj) {
      int o = ot * 64 + j4 + jj;
      float sc = gamma[o] / sqrtf(var[o] + 1e-5f);
      float mn = mean[o], bt = beta[o];
      float4 r;
      float z;
      z = (acc[0][jj] - mn) * sc + bt; r.x = z / (1.f + expf(-z));
      z = (acc[1][jj] - mn) * sc + bt; r.y = z / (1.f + expf(-z));
      z = (acc[2][jj] - mn) * sc + bt; r.z = z / (1.f + expf(-z));
      z = (acc[3][jj] - mn) * sc + bt; r.w = z / (1.f + expf(-z));
      *(float4*)&out[((size_t)(b * NC + o)) * 1024 + p0 + i4] = r;
    }
  }
}

extern "C" void kernel_launch(void* const* d_in, const int* in_sizes, int n_in,
                              void* d_out, int out_size, void* d_ws,
                              size_t ws_size, hipStream_t stream) {
  const float* x = (const float*)d_in[0];
  const float* swp = (const float*)d_in[1];
  const float* dwp = (const float*)d_in[2];
  const float* convw = (const float*)d_in[3];
  const float* gamma = (const float*)d_in[4];
  const float* beta = (const float*)d_in[5];
  const float* mean = (const float*)d_in[6];
  const float* var = (const float*)d_in[7];
  float* out = (float*)d_out;

  float* ws = (float*)d_ws;
  size_t o = 0;
  float* xf1 = ws + o;  o += (size_t)8 * 4096 * 128;  // reused as xf3
  float* nrm1 = ws + o; o += 8 * 4096;
  float* xf2 = ws + o;  o += (size_t)8 * 2048 * 128;
  float* nrm2 = ws + o; o += 8 * 2048;
  float* cnt1 = ws + o; o += 8 * 2048;
  float* cnt2 = ws + o; o += 8 * 1024;
  int* dst1 = (int*)(ws + o); o += 8 * 2048;
  int* dst2 = (int*)(ws + o); o += 8 * 1024;
  float* lut = ws + o;  o += 8192;
  _Float16* ext1 = (_Float16*)(ws + o);
  _Float16* ext2 = ext1;  // ext1 dead after merge-1 candidate pass
  const size_t ext_floats = (size_t)8 * 4096 * 256 / 2;
  const bool mfma_ok = ws_size >= (o + ext_floats) * sizeof(float);
  float* xf3 = xf1;  // alias: xf1 dead before xf3 written
  // aliases into dead regions (lifetimes verified):
  // pu1 -> xf2 region (xf2 written only later, by copy_init after topkrefine)
  unsigned long long* pu1 = (unsigned long long*)xf2;
  // pu2 -> xf1 region (xf1/a-rows dead after merge-1 scatter; xf3 written later)
  unsigned long long* pu2 = (unsigned long long*)xf1;
  float* pv1 = xf2;
  int* pj1 = (int*)(xf2 + 8 * 2048 * 8);
  float* pv2 = xf1;
  int* pj2 = (int*)(xf1 + 8 * 1024 * 8);

  // ---- merge 1: T=4096, H=2048, width=64 ----
  prep_kernel<<<dim3(64, 8), 256, 0, stream>>>(x, xf1, nrm1,
                                               mfma_ok ? ext1 : nullptr);
  if (mfma_ok) {
    argmax_mfma5_kernel<64, 4096, 2048>
        <<<dim3(32, 8, 8), 256, 0, stream>>>(ext1, swp, dwp, pu1);
    topkrefine_kernel<64, 4096, 2048, 64>
        <<<4096, 256, 0, stream>>>(pu1, xf1, nrm1, swp, dwp, dst1);
  } else {
    lut_kernel<<<32, 256, 0, stream>>>(lut, dwp, 7939);
    argmax2_kernel<64, 4096, 2048, 128, 256>
        <<<dim3(16, 8, 8), 256, 0, stream>>>(xf1, nrm1, swp, lut, pv1, pj1);
    argreduce_kernel<<<64, 256, 0, stream>>>(pv1, pj1, dst1, 8 * 2048, 8);
  }
  copy_init_kernel<<<2048, 256, 0, stream>>>(xf1, xf2, cnt1, 2048, 4096);
  scatter_kernel<<<2048, 256, 0, stream>>>(xf1, dst1, xf2, cnt1, 2048, 4096);
  finalize_kernel<<<8192, 256, 0, stream>>>(xf2, cnt1, nrm2,
                                            mfma_ok ? ext2 : nullptr, 1024);

  // ---- merge 2: T=2048, H=1024, width=int(sqrt(2048))=45 ----
  if (mfma_ok) {
    argmax_mfma5_kernel<45, 2048, 1024>
        <<<dim3(16, 4, 8), 256, 0, stream>>>(ext2, swp, dwp, pu2);
    topkrefine_kernel<45, 2048, 1024, 32>
        <<<2048, 256, 0, stream>>>(pu2, xf2, nrm2, swp, dwp, dst2);
  } else {
    argmax2_kernel<45, 2048, 1024, 64, 128>
        <<<dim3(16, 8, 8), 256, 0, stream>>>(xf2, nrm2, swp, lut, pv2, pj2);
    argreduce_kernel<<<32, 256, 0, stream>>>(pv2, pj2, dst2, 8 * 1024, 8);
  }
  copy_init_kernel<<<1024, 256, 0, stream>>>(xf2, xf3, cnt2, 1024, 2048);
  scatter_kernel<<<1024, 256, 0, stream>>>(xf2, dst2, xf3, cnt2, 1024, 2048);
  finalize_kernel<<<4096, 256, 0, stream>>>(xf3, cnt2, nullptr, nullptr, 512);

  // ---- 1x1 conv + BN + SiLU ----
  conv_bn_silu_kernel<<<dim3(16, 8), 256, 0, stream>>>(
      xf3, convw, gamma, beta, mean, var, out);
}

// Round 10
// 176.772 us; speedup vs baseline: 2.5378x; 1.0111x over previous
//
#include <hip/hip_runtime.h>
#include <math.h>

#define NB 8
#define NC 128

typedef _Float16 hf8 __attribute__((ext_vector_type(8)));
typedef _Float16 hf4 __attribute__((ext_vector_type(4)));
typedef float fx4 __attribute__((ext_vector_type(4)));

// ---------------- LUT: lut[d2] = dw * (1/(sqrt(d2)+1e-6)) (fallback only) ---
__global__ void lut_kernel(float* __restrict__ lut, const float* __restrict__ dwp,
                           int n) {
  int i = blockIdx.x * 256 + threadIdx.x;
  if (i < n) {
    float r = 1.0f / (sqrtf((float)i) + 1e-6f);
    lut[i] = dwp[0] * r;
  }
}

// ---- prep: x (B,C,4096) -> xf1, nrm1, ext1 (B,4096,256 fp16, K=256 enc) ----
// a-token row: [h | e] (e=(m-h)*128)   b-token row: [h | h/128]
// 1D grid 512: b = bid&7 (batch->XCD affinity), panel = bid>>3.
__global__ void prep_kernel(const float* __restrict__ x, float* __restrict__ xf,
                            float* __restrict__ nrm, _Float16* __restrict__ ext) {
  __shared__ float tile[64][129];
  __shared__ float part[64][4];
  __shared__ float rn_s[64];
  const int bid = blockIdx.x;
  const int b = bid & 7;
  const int p0 = (bid >> 3) * 64;
  const int tid = threadIdx.x;
  const int lane = tid & 63;
  const int q = tid >> 6;
  for (int cc = 0; cc < 32; ++cc) {
    int c = q * 32 + cc;
    tile[lane][c] = x[((size_t)(b * NC + c)) * 4096 + p0 + lane];
  }
  __syncthreads();
  float s = 0.f;
  for (int cc = 0; cc < 32; ++cc) {
    float v = tile[lane][q * 32 + cc];
    s += v * v;
  }
  part[lane][q] = s;
  __syncthreads();
  if (tid < 64) {
    float n = sqrtf(part[tid][0] + part[tid][1] + part[tid][2] + part[tid][3]);
    nrm[b * 4096 + p0 + tid] = n;
    rn_s[tid] = n;
  }
  __syncthreads();
  for (int it = 0; it < 8; ++it) {
    int idx = it * 256 + tid;
    int r = idx >> 5, e = (idx & 31) * 4;
    float4 v = make_float4(tile[r][e], tile[r][e + 1], tile[r][e + 2], tile[r][e + 3]);
    size_t o = (((size_t)b * 4096 + p0 + r) << 7) + e;
    *(float4*)&xf[o] = v;
    if (ext != nullptr) {
      float n = rn_s[r];
      int tok = p0 + r;
      bool isA = tok < 2048;
      _Float16* rw = ext + ((size_t)b * 4096 + tok) * 256;
      float mm[4] = {v.x / n, v.y / n, v.z / n, v.w / n};
      hf4 hv, ov;
#pragma unroll
      for (int u = 0; u < 4; ++u) {
        float m = mm[u];
        _Float16 h = (_Float16)m;
        float hf_ = (float)h;
        hv[u] = h;
        ov[u] = isA ? (_Float16)((m - hf_) * 128.0f)
                    : (_Float16)(hf_ * 0.0078125f);
      }
      *(hf4*)&rw[e] = hv;
      *(hf4*)&rw[128 + e] = ov;
    }
  }
}

// ------ MFMA candidate kernel: B-stationary LDS, A global->reg, K=256 -------
// Block: 4 waves, each wave = 64i x 64j. 4 blocks/CU (35.8KB LDS, <=128 VGPR).
// 1D grid: b = bid&7 (batch->XCD: per-batch 2MB working set L2-resident),
// jb = (bid>>3)&(NJB-1) (A-panel reuse), ib = (bid>>3)/NJB.
// Emits packed u64 top-2 per (row, 64-j chunk).
template <int WIDTH, int TT, int HH, int NJB>
__global__ __launch_bounds__(256, 4) void argmax_mfma6_kernel(
    const _Float16* __restrict__ ext, const float* __restrict__ swp,
    const float* __restrict__ dwp, unsigned long long* __restrict__ pu) {
  __shared__ _Float16 Bt[64][280];  // 35840 B; reused as reduce buffer
  const int bid = blockIdx.x;
  const int b = bid & 7;
  const int rr = bid >> 3;
  const int jb = rr & (NJB - 1);
  const int ib = rr / NJB;
  const int tid = threadIdx.x;
  const int w = tid >> 6, l = tid & 63;
  const int lg = l >> 4, lm = l & 15;
  const int ipan = ib * 256 + w * 64;
  const int j0 = jb * 64;
  const float sw = swp[0], dwv = dwp[0];
  const _Float16* extb = ext + (size_t)b * TT * 256;
  const _Float16* brow0 = extb + (size_t)(HH + j0) * 256;

  const _Float16* ap[4];
#pragma unroll
  for (int s = 0; s < 4; ++s)
    ap[s] = extb + (size_t)(ipan + s * 16 + lm) * 256 + lg * 8;

  // stage B tile once: 64 rows x 256 halfs
  for (int f = tid; f < 64 * 32; f += 256) {
    int r = f >> 5, c = f & 31;
    *(float4*)&Bt[r][c * 8] = *(const float4*)&brow0[(size_t)r * 256 + c * 8];
  }
  __syncthreads();

  fx4 acc[4][4];
#pragma unroll
  for (int i4 = 0; i4 < 4; ++i4)
#pragma unroll
    for (int j4 = 0; j4 < 4; ++j4) acc[i4][j4] = 0.f;

#pragma unroll
  for (int kc = 0; kc < 8; ++kc) {
    hf8 af[4], bf[4];
#pragma unroll
    for (int s = 0; s < 4; ++s)
      af[s] = *(const hf8*)(ap[s] + kc * 32);
#pragma unroll
    for (int s = 0; s < 4; ++s)
      bf[s] = *(const hf8*)&Bt[s * 16 + lm][kc * 32 + lg * 8];
    __builtin_amdgcn_s_setprio(1);
#pragma unroll
    for (int j4 = 0; j4 < 4; ++j4)
#pragma unroll
      for (int i4 = 0; i4 < 4; ++i4)
        acc[i4][j4] = __builtin_amdgcn_mfma_f32_16x16x32_f16(
            af[i4], bf[j4], acc[i4][j4], 0, 0, 0);
    __builtin_amdgcn_s_setprio(0);
  }

  // ---- epilogue: per-lane first-max over its 4 cols, per row ----
  // C/D layout: row = lg*4 + reg (+i4*16), col = lm (+j4*16).
  int jr4[4], jc4[4];
#pragma unroll
  for (int j4 = 0; j4 < 4; ++j4) {
    int tj = HH + j0 + j4 * 16 + lm;
    jr4[j4] = tj / WIDTH;
    jc4[j4] = tj % WIDTH;
  }
  __syncthreads();  // all waves done reading Bt -> reuse as reduce buffer
  unsigned long long* rwv = (unsigned long long*)&Bt[0][0] + (size_t)w * 64 * 17;
#pragma unroll
  for (int i4 = 0; i4 < 4; ++i4) {
#pragma unroll
    for (int rg = 0; rg < 4; ++rg) {
      int il = i4 * 16 + lg * 4 + rg;
      int ti = ipan + il;
      int ir = ti / WIDTH, ic = ti % WIDTH;
      float bv = -1e30f;
      int bj = 0;
#pragma unroll
      for (int j4 = 0; j4 < 4; ++j4) {  // ascending j -> first-max kept
        int dr = ir - jr4[j4], dc = ic - jc4[j4];
        float d2 = (float)(dr * dr + dc * dc);
        float sc = sw * acc[i4][j4][rg] + dwv * __builtin_amdgcn_rsqf(d2);
        int gj = j0 + j4 * 16 + lm;
        if (sc > bv) { bv = sc; bj = gj; }
      }
      rwv[il * 17 + lm] =
          ((unsigned long long)__float_as_uint(bv + 1.0f) << 32) |
          (unsigned)(~(unsigned)bj);
    }
  }
  __syncthreads();
  // lane l owns row l: top-2 over 16 lane-maxima (u64 packed order)
  unsigned long long t1 = 0ull, t2 = 0ull;
#pragma unroll
  for (int c = 0; c < 16; ++c) {
    unsigned long long u = rwv[l * 17 + c];
    if (u > t1) { t2 = t1; t1 = u; }
    else if (u > t2) { t2 = u; }
  }
  size_t row = (size_t)b * HH + ipan + l;
  pu[row * (HH / 32) + jb * 2 + 0] = t1;
  pu[row * (HH / 32) + jb * 2 + 1] = t2;
}

// --- fused top-4 + exact fp32 refine: one wave per row -> dst --------------
// 1D grid NB*HH/4: b = bid&7 (same-XCD as producer argmax -> pu L2-hot).
template <int WIDTH, int TT, int HH, int NCH2>
__global__ __launch_bounds__(256) void topkrefine_kernel(
    const unsigned long long* __restrict__ pu, const float* __restrict__ xf,
    const float* __restrict__ nrm, const float* __restrict__ swp,
    const float* __restrict__ dwp, int* __restrict__ dst) {
  const int bid = blockIdx.x;
  const int bb = bid & 7;
  const int row = bb * HH + (bid >> 3) * 4 + (threadIdx.x >> 6);
  const int lane = threadIdx.x & 63;
  // ---- top-4 candidates across chunks (packed u64 order) ----
  unsigned long long v = (lane < NCH2) ? pu[(size_t)row * NCH2 + lane] : 0ull;
  int candv[4];
#pragma unroll
  for (int t = 0; t < 4; ++t) {
    unsigned long long m = v;
#pragma unroll
    for (int off = 1; off < 64; off <<= 1) {
      unsigned long long o = __shfl_xor(m, off, 64);
      if (o > m) m = o;
    }
    candv[t] = (int)(~(unsigned)(m & 0xFFFFFFFFull));
    if (v == m) v = 0ull;  // packed u64 unique per j -> exact removal
  }
  // ---- exact fp32 scores for the 4 candidates; first-argmax semantics ----
  const int half = lane >> 5, ln = lane & 31;
  const int b = row / HH, i = row - b * HH;
  const float sw = swp[0], dwv = dwp[0];
  const float na = nrm[b * TT + i];
  float4 a4 = *(const float4*)&xf[((size_t)b * TT + i) * NC + ln * 4];
  a4.x /= na; a4.y /= na; a4.z /= na; a4.w /= na;
  const int ir = i / WIDTH, ic = i % WIDTH;
  float bv = -3.0e38f;
  int bj = 0x7fffffff;
#pragma unroll
  for (int c = 0; c < 4; c += 2) {
    int j = candv[c + half];
    float4 b4 = *(const float4*)&xf[((size_t)b * TT + HH + j) * NC + ln * 4];
    float p = a4.x * b4.x + a4.y * b4.y + a4.z * b4.z + a4.w * b4.w;
#pragma unroll
    for (int off = 1; off < 32; off <<= 1) p += __shfl_xor(p, off, 32);
    float nb = nrm[b * TT + HH + j];
    int tj = HH + j;
    int jr = tj / WIDTH;
    int dr = ir - jr, dc = ic - (tj - jr * WIDTH);
    float r = 1.0f / (sqrtf((float)(dr * dr + dc * dc)) + 1e-6f);
    float sc = sw * (p / nb) + dwv * r;
    if (sc > bv || (sc == bv && j < bj)) { bv = sc; bj = j; }
  }
  {
    float ov = __shfl_xor(bv, 32, 64);
    int oj = __shfl_xor(bj, 32, 64);
    if (ov > bv || (ov == bv && oj < bj)) { bv = ov; bj = oj; }
  }
  if (lane == 0) dst[row] = bj;
}

// ---------------- FALLBACK fp32 path (round-1 structure, proven) ------------
template <int WIDTH, int TT, int HH, int IT, int JC>
__global__ __launch_bounds__(256, 4) void argmax2_kernel(
    const float* __restrict__ xf, const float* __restrict__ nrm,
    const float* __restrict__ swp, const float* __restrict__ lut,
    float* __restrict__ pval, int* __restrict__ pidx) {
  constexpr int MI = IT / 16;
  constexpr int NTILE = JC / 128;
  __shared__ float At[32][IT + 4];
  __shared__ float Bt[32][132];
  __shared__ int ico[2][IT];
  __shared__ int jco[2][JC];

  const int b = blockIdx.z;
  const int it0 = blockIdx.x * IT;
  const int jb = blockIdx.y;
  const int j0g = jb * JC;
  const int tid = threadIdx.x;

  for (int t = tid; t < IT; t += 256) {
    int tok = it0 + t;
    ico[0][t] = tok / WIDTH;
    ico[1][t] = tok % WIDTH;
  }
  for (int t = tid; t < JC; t += 256) {
    int tok = HH + j0g + t;
    jco[0][t] = tok / WIDTH;
    jco[1][t] = tok % WIDTH;
  }
  const float sw = swp[0];
  const float* srcb = xf + (size_t)b * TT * NC;

  const int ty = tid >> 4, tx = tid & 15;
  const int i0l = ty * MI;
  const int j0l = tx * 8;

  float best[MI];
  int bidx[MI];
#pragma unroll
  for (int ii = 0; ii < MI; ++ii) { best[ii] = -1e30f; bidx[ii] = 0; }

  for (int jt = 0; jt < NTILE; ++jt) {
    float acc[MI][8];
#pragma unroll
    for (int ii = 0; ii < MI; ++ii)
#pragma unroll
      for (int jj = 0; jj < 8; ++jj) acc[ii][jj] = 0.f;

    for (int kc = 0; kc < 4; ++kc) {
      __syncthreads();
#pragma unroll
      for (int p = 0; p < IT / 32; ++p) {
        int f = p * 256 + tid;
        int r = f >> 3, kq = (f & 7) * 4;
        const float* row = srcb + (size_t)(it0 + r) * NC + kc * 32 + kq;
        float4 v = *(const float4*)row;
        float n = nrm[b * TT + it0 + r];
        v.x /= n; v.y /= n; v.z /= n; v.w /= n;
        At[kq + 0][r] = v.x; At[kq + 1][r] = v.y;
        At[kq + 2][r] = v.z; At[kq + 3][r] = v.w;
      }
#pragma unroll
      for (int p = 0; p < 4; ++p) {
        int f = p * 256 + tid;
        int r = f >> 3, kq = (f & 7) * 4;
        int tok = HH + j0g + jt * 128 + r;
        const float* row = srcb + (size_t)tok * NC + kc * 32 + kq;
        float4 v = *(const float4*)row;
        float n = nrm[b * TT + tok];
        v.x /= n; v.y /= n; v.z /= n; v.w /= n;
        Bt[kq + 0][r] = v.x; Bt[kq + 1][r] = v.y;
        Bt[kq + 2][r] = v.z; Bt[kq + 3][r] = v.w;
      }
      __syncthreads();

#pragma unroll 4
      for (int k = 0; k < 32; ++k) {
        float a[MI], bb[8];
#pragma unroll
        for (int qv = 0; qv < MI / 4; ++qv)
          *(float4*)&a[qv * 4] = *(const float4*)&At[k][i0l + qv * 4];
        *(float4*)&bb[0] = *(const float4*)&Bt[k][j0l];
        *(float4*)&bb[4] = *(const float4*)&Bt[k][j0l + 4];
#pragma unroll
        for (int ii = 0; ii < MI; ++ii)
#pragma unroll
          for (int jj = 0; jj < 8; ++jj) acc[ii][jj] += a[ii] * bb[jj];
      }
    }

#pragma unroll
    for (int ii = 0; ii < MI; ++ii) {
      int ir = ico[0][i0l + ii], ic = ico[1][i0l + ii];
#pragma unroll
      for (int jj = 0; jj < 8; ++jj) {
        int jl = jt * 128 + j0l + jj;
        int dr = ir - jco[0][jl];
        int dc = ic - jco[1][jl];
        float sc = sw * acc[ii][jj] + lut[dr * dr + dc * dc];
        if (sc > best[ii]) {
          best[ii] = sc;
          bidx[ii] = j0g + jl;
        }
      }
    }
  }

  __syncthreads();
  float* rv = &At[0][0];
  int* rj = (int*)&Bt[0][0];
#pragma unroll
  for (int ii = 0; ii < MI; ++ii) {
    rv[(i0l + ii) * 17 + tx] = best[ii];
    rj[(i0l + ii) * 17 + tx] = bidx[ii];
  }
  __syncthreads();
  if (tid < IT) {
    float bv = rv[tid * 17];
    int bj = rj[tid * 17];
    for (int t = 1; t < 16; ++t) {
      float v = rv[tid * 17 + t];
      int j = rj[tid * 17 + t];
      if (v > bv || (v == bv && j < bj)) { bv = v; bj = j; }
    }
    int row = b * HH + it0 + tid;
    pval[(size_t)row * 8 + jb] = bv;
    pidx[(size_t)row * 8 + jb] = bj;
  }
}

__global__ void argreduce_kernel(const float* __restrict__ pv,
                                 const int* __restrict__ pj,
                                 int* __restrict__ dst, int nrows, int w) {
  int r = blockIdx.x * 256 + threadIdx.x;
  if (r >= nrows) return;
  const float* vv = pv + (size_t)r * w;
  const int* jj = pj + (size_t)r * w;
  float bv = vv[0];
  int bj = jj[0];
  for (int t = 1; t < w; ++t) {
    float v = vv[t];
    int j = jj[t];
    if (v > bv || (v == bv && j < bj)) { bv = v; bj = j; }
  }
  dst[r] = bj;
}

// -------- merge: out = b-half copy, then atomic scatter of a rows, divide ---
// 1D grids, b = bid&7 (batch->XCD affinity; per-batch regions L2-resident).
__global__ void copy_init_kernel(const float* __restrict__ src,
                                 float* __restrict__ dstbuf,
                                 float* __restrict__ cnt, int HH, int TT) {
  const int b = blockIdx.x & 7;
  size_t local = (size_t)(blockIdx.x >> 3) * 256 + threadIdx.x;  // (row,e4)
  if (local >= (size_t)HH * 32) return;
  int j = (int)(local >> 5);
  int e = (int)(local & 31) * 4;
  float4 v = *(const float4*)&src[((size_t)b * TT + HH + j) * NC + e];
  *(float4*)&dstbuf[((size_t)b * HH + j) * NC + e] = v;
  if (e == 0) cnt[(size_t)b * HH + j] = 1.0f;
}

__global__ void scatter_kernel(const float* __restrict__ src,
                               const int* __restrict__ dst,
                               float* __restrict__ accbuf,
                               float* __restrict__ cnt, int HH, int TT) {
  const int b = blockIdx.x & 7;
  size_t local = (size_t)(blockIdx.x >> 3) * 256 + threadIdx.x;
  if (local >= (size_t)HH * 32) return;
  int i = (int)(local >> 5);
  int e = (int)(local & 31) * 4;
  float4 v = *(const float4*)&src[((size_t)b * TT + i) * NC + e];
  int d = dst[(size_t)b * HH + i];
  float* base = &accbuf[((size_t)b * HH + d) * NC + e];
  atomicAdd(base + 0, v.x);
  atomicAdd(base + 1, v.y);
  atomicAdd(base + 2, v.z);
  atomicAdd(base + 3, v.w);
  if (e == 0) atomicAdd(&cnt[(size_t)b * HH + d], 1.0f);
}

// finalize: divide by counts; optionally emit nrm + ext rows (K=256 enc) -----
// 1D grid nrows/2, b = bid&7; per-batch rows = 2*HH2.
__global__ void finalize_kernel(float* __restrict__ buf,
                                const float* __restrict__ cnt,
                                float* __restrict__ nrm,
                                _Float16* __restrict__ ext, int HH2) {
  const int b = blockIdx.x & 7;
  int row = b * (2 * HH2) + (blockIdx.x >> 3) * 2 + (threadIdx.x >> 7);
  int c = threadIdx.x & 127;
  float v = buf[(size_t)row * NC + c] / cnt[row];
  buf[(size_t)row * NC + c] = v;
  if (nrm != nullptr) {
    float s = v * v;
    for (int off = 32; off > 0; off >>= 1) s += __shfl_down(s, off, 64);
    __shared__ float p[4];
    __shared__ float ns[2];
    int w = threadIdx.x >> 6;
    if ((threadIdx.x & 63) == 0) p[w] = s;
    __syncthreads();
    if ((threadIdx.x & 127) == 0) {
      float n = sqrtf(p[w] + p[w + 1]);
      nrm[row] = n;
      ns[threadIdx.x >> 7] = n;
    }
    __syncthreads();
    if (ext != nullptr) {
      float n = ns[threadIdx.x >> 7];
      float m = v / n;
      _Float16 h = (_Float16)m;
      float hf = (float)h;
      _Float16 ep = (_Float16)((m - hf) * 128.0f);
      _Float16 hs = (_Float16)(hf * 0.0078125f);
      int t = row & (2 * HH2 - 1);
      bool isA = t < HH2;
      _Float16* rw = ext + (size_t)row * 256;
      rw[c] = h;
      rw[128 + c] = isA ? ep : hs;
    }
  }
}

// ---------------- 1x1 conv (128x128) + BN + SiLU -> out (B,128,32,32) -------
// 1D grid 128: b = bid&7, p0 = (bid>>3)*64.
__global__ __launch_bounds__(256) void conv_bn_silu_kernel(
    const float* __restrict__ xf3, const float* __restrict__ w,
    const float* __restrict__ gamma, const float* __restrict__ beta,
    const float* __restrict__ mean, const float* __restrict__ var,
    float* __restrict__ out) {
  __shared__ float X[64][132];
  __shared__ float Wt[128][68];
  const int b = blockIdx.x & 7, p0 = (blockIdx.x >> 3) * 64;
  const int tid = threadIdx.x, lane = tid & 63, q = tid >> 6;
  {
    const float* row = xf3 + ((size_t)b * 1024 + p0 + lane) * NC;
    for (int cc = 0; cc < 8; ++cc) {
      int c = q * 32 + cc * 4;
      *(float4*)&X[lane][c] = *(const float4*)&row[c];
    }
  }
  const int ti = tid >> 4, tj = tid & 15;
  const int i4 = ti * 4, j4 = tj * 4;
  for (int ot = 0; ot < 2; ++ot) {
    __syncthreads();
    {
      const float* row = w + (size_t)(ot * 64 + lane) * NC;
      for (int cc = 0; cc < 8; ++cc) {
        int c = q * 32 + cc * 4;
        float4 v = *(const float4*)&row[c];
        Wt[c + 0][lane] = v.x;
        Wt[c + 1][lane] = v.y;
        Wt[c + 2][lane] = v.z;
        Wt[c + 3][lane] = v.w;
      }
    }
    __syncthreads();
    float acc[4][4];
#pragma unroll
    for (int ii = 0; ii < 4; ++ii)
#pragma unroll
      for (int jj = 0; jj < 4; ++jj) acc[ii][jj] = 0.f;

    for (int k = 0; k < NC; k += 4) {
      float4 a0 = *(const float4*)&X[i4 + 0][k];
      float4 a1 = *(const float4*)&X[i4 + 1][k];
      float4 a2 = *(const float4*)&X[i4 + 2][k];
      float4 a3 = *(const float4*)&X[i4 + 3][k];
      float4 b0 = *(const float4*)&Wt[k + 0][j4];
      float4 b1 = *(const float4*)&Wt[k + 1][j4];
      float4 b2 = *(const float4*)&Wt[k + 2][j4];
      float4 b3 = *(const float4*)&Wt[k + 3][j4];
#define FMA16(AX, BV)                                                     \
  acc[0][0] += a0.AX * BV.x; acc[0][1] += a0.AX * BV.y;                   \
  acc[0][2] += a0.AX * BV.z; acc[0][3] += a0.AX * BV.w;                   \
  acc[1][0] += a1.AX * BV.x; acc[1][1] += a1.AX * BV.y;                   \
  acc[1][2] += a1.AX * BV.z; acc[1][3] += a1.AX * BV.w;                   \
  acc[2][0] += a2.AX * BV.x; acc[2][1] += a2.AX * BV.y;                   \
  acc[2][2] += a2.AX * BV.z; acc[2][3] += a2.AX * BV.w;                   \
  acc[3][0] += a3.AX * BV.x; acc[3][1] += a3.AX * BV.y;                   \
  acc[3][2] += a3.AX * BV.z; acc[3][3] += a3.AX * BV.w;
      FMA16(x, b0)
      FMA16(y, b1)
      FMA16(z, b2)
      FMA16(w, b3)
#undef FMA16
    }

#pragma unroll
    for (int jj = 0; jj < 4; ++jj) {
      int o = ot * 64 + j4 + jj;
      float sc = gamma[o] / sqrtf(var[o] + 1e-5f);
      float mn = mean[o], bt = beta[o];
      float4 r;
      float z;
      z = (acc[0][jj] - mn) * sc + bt; r.x = z / (1.f + expf(-z));
      z = (acc[1][jj] - mn) * sc + bt; r.y = z / (1.f + expf(-z));
      z = (acc[2][jj] - mn) * sc + bt; r.z = z / (1.f + expf(-z));
      z = (acc[3][jj] - mn) * sc + bt; r.w = z / (1.f + expf(-z));
      *(float4*)&out[((size_t)(b * NC + o)) * 1024 + p0 + i4] = r;
    }
  }
}

extern "C" void kernel_launch(void* const* d_in, const int* in_sizes, int n_in,
                              void* d_out, int out_size, void* d_ws,
                              size_t ws_size, hipStream_t stream) {
  const float* x = (const float*)d_in[0];
  const float* swp = (const float*)d_in[1];
  const float* dwp = (const float*)d_in[2];
  const float* convw = (const float*)d_in[3];
  const float* gamma = (const float*)d_in[4];
  const float* beta = (const float*)d_in[5];
  const float* mean = (const float*)d_in[6];
  const float* var = (const float*)d_in[7];
  float* out = (float*)d_out;

  float* ws = (float*)d_ws;
  size_t o = 0;
  float* xf1 = ws + o;  o += (size_t)8 * 4096 * 128;  // reused as xf3
  float* nrm1 = ws + o; o += 8 * 4096;
  float* xf2 = ws + o;  o += (size_t)8 * 2048 * 128;
  float* nrm2 = ws + o; o += 8 * 2048;
  float* cnt1 = ws + o; o += 8 * 2048;
  float* cnt2 = ws + o; o += 8 * 1024;
  int* dst1 = (int*)(ws + o); o += 8 * 2048;
  int* dst2 = (int*)(ws + o); o += 8 * 1024;
  float* lut = ws + o;  o += 8192;
  _Float16* ext1 = (_Float16*)(ws + o);
  _Float16* ext2 = ext1;  // ext1 dead after merge-1 candidate pass
  const size_t ext_floats = (size_t)8 * 4096 * 256 / 2;
  const bool mfma_ok = ws_size >= (o + ext_floats) * sizeof(float);
  float* xf3 = xf1;  // alias: xf1 dead before xf3 written
  // aliases into dead regions (lifetimes verified):
  // pu1 -> xf2 region (xf2 written only later, by copy_init after topkrefine)
  unsigned long long* pu1 = (unsigned long long*)xf2;
  // pu2 -> xf1 region (xf1/a-rows dead after merge-1 scatter; xf3 written later)
  unsigned long long* pu2 = (unsigned long long*)xf1;
  float* pv1 = xf2;
  int* pj1 = (int*)(xf2 + 8 * 2048 * 8);
  float* pv2 = xf1;
  int* pj2 = (int*)(xf1 + 8 * 1024 * 8);

  // ---- merge 1: T=4096, H=2048, width=64 ----
  prep_kernel<<<512, 256, 0, stream>>>(x, xf1, nrm1, mfma_ok ? ext1 : nullptr);
  if (mfma_ok) {
    argmax_mfma6_kernel<64, 4096, 2048, 32>
        <<<2048, 256, 0, stream>>>(ext1, swp, dwp, pu1);
    topkrefine_kernel<64, 4096, 2048, 64>
        <<<4096, 256, 0, stream>>>(pu1, xf1, nrm1, swp, dwp, dst1);
  } else {
    lut_kernel<<<32, 256, 0, stream>>>(lut, dwp, 7939);
    argmax2_kernel<64, 4096, 2048, 128, 256>
        <<<dim3(16, 8, 8), 256, 0, stream>>>(xf1, nrm1, swp, lut, pv1, pj1);
    argreduce_kernel<<<64, 256, 0, stream>>>(pv1, pj1, dst1, 8 * 2048, 8);
  }
  copy_init_kernel<<<2048, 256, 0, stream>>>(xf1, xf2, cnt1, 2048, 4096);
  scatter_kernel<<<2048, 256, 0, stream>>>(xf1, dst1, xf2, cnt1, 2048, 4096);
  finalize_kernel<<<8192, 256, 0, stream>>>(xf2, cnt1, nrm2,
                                            mfma_ok ? ext2 : nullptr, 1024);

  // ---- merge 2: T=2048, H=1024, width=int(sqrt(2048))=45 ----
  if (mfma_ok) {
    argmax_mfma6_kernel<45, 2048, 1024, 16>
        <<<512, 256, 0, stream>>>(ext2, swp, dwp, pu2);
    topkrefine_kernel<45, 2048, 1024, 32>
        <<<2048, 256, 0, stream>>>(pu2, xf2, nrm2, swp, dwp, dst2);
  } else {
    argmax2_kernel<45, 2048, 1024, 64, 128>
        <<<dim3(16, 8, 8), 256, 0, stream>>>(xf2, nrm2, swp, lut, pv2, pj2);
    argreduce_kernel<<<32, 256, 0, stream>>>(pv2, pj2, dst2, 8 * 1024, 8);
  }
  copy_init_kernel<<<1024, 256, 0, stream>>>(xf2, xf3, cnt2, 1024, 2048);
  scatter_kernel<<<1024, 256, 0, stream>>>(xf2, dst2, xf3, cnt2, 1024, 2048);
  finalize_kernel<<<4096, 256, 0, stream>>>(xf3, cnt2, nullptr, nullptr, 512);

  // ---- 1x1 conv + BN + SiLU ----
  conv_bn_silu_kernel<<<128, 256, 0, stream>>>(
      xf3, convw, gamma, beta, mean, var, out);
}

// Round 11
// 153.844 us; speedup vs baseline: 2.9160x; 1.1490x over previous
//
#include <hip/hip_runtime.h>
#include <math.h>

#define NB 8
#define NC 128

typedef _Float16 hf8 __attribute__((ext_vector_type(8)));
typedef _Float16 hf4 __attribute__((ext_vector_type(4)));
typedef float fx4 __attribute__((ext_vector_type(4)));

// ---------------- LUT: lut[d2] = dw * (1/(sqrt(d2)+1e-6)) (fallback only) ---
__global__ void lut_kernel(float* __restrict__ lut, const float* __restrict__ dwp,
                           int n) {
  int i = blockIdx.x * 256 + threadIdx.x;
  if (i < n) {
    float r = 1.0f / (sqrtf((float)i) + 1e-6f);
    lut[i] = dwp[0] * r;
  }
}

// ---- prep: x (B,C,4096) -> xf1, nrm1, ext1 (K=256 enc), + xf2/cnt1 init ----
// a-token row: [h | e] (e=(m-h)*128)   b-token row: [h | h/128]
// Fused: b-half rows (tok>=2048) are also written to xf2 (merge-1 init), cnt=1.
// 1D grid 512: b = bid&7 (batch->XCD affinity), panel = bid>>3.
__global__ void prep_kernel(const float* __restrict__ x, float* __restrict__ xf,
                            float* __restrict__ nrm, _Float16* __restrict__ ext,
                            float* __restrict__ xf2, float* __restrict__ cnt1) {
  __shared__ float tile[64][129];
  __shared__ float part[64][4];
  __shared__ float rn_s[64];
  const int bid = blockIdx.x;
  const int b = bid & 7;
  const int p0 = (bid >> 3) * 64;
  const int tid = threadIdx.x;
  const int lane = tid & 63;
  const int q = tid >> 6;
  for (int cc = 0; cc < 32; ++cc) {
    int c = q * 32 + cc;
    tile[lane][c] = x[((size_t)(b * NC + c)) * 4096 + p0 + lane];
  }
  __syncthreads();
  float s = 0.f;
  for (int cc = 0; cc < 32; ++cc) {
    float v = tile[lane][q * 32 + cc];
    s += v * v;
  }
  part[lane][q] = s;
  __syncthreads();
  if (tid < 64) {
    float n = sqrtf(part[tid][0] + part[tid][1] + part[tid][2] + part[tid][3]);
    nrm[b * 4096 + p0 + tid] = n;
    rn_s[tid] = n;
  }
  __syncthreads();
  for (int it = 0; it < 8; ++it) {
    int idx = it * 256 + tid;
    int r = idx >> 5, e = (idx & 31) * 4;
    float4 v = make_float4(tile[r][e], tile[r][e + 1], tile[r][e + 2], tile[r][e + 3]);
    size_t o = (((size_t)b * 4096 + p0 + r) << 7) + e;
    *(float4*)&xf[o] = v;
    int tok = p0 + r;
    if (tok >= 2048) {  // merge-1 accumulator init (replaces copy_init m1)
      size_t row2 = (size_t)b * 2048 + tok - 2048;
      *(float4*)&xf2[row2 * NC + e] = v;
      if (e == 0) cnt1[row2] = 1.0f;
    }
    if (ext != nullptr) {
      float n = rn_s[r];
      bool isA = tok < 2048;
      _Float16* rw = ext + ((size_t)b * 4096 + tok) * 256;
      float mm[4] = {v.x / n, v.y / n, v.z / n, v.w / n};
      hf4 hv, ov;
#pragma unroll
      for (int u = 0; u < 4; ++u) {
        float m = mm[u];
        _Float16 h = (_Float16)m;
        float hf_ = (float)h;
        hv[u] = h;
        ov[u] = isA ? (_Float16)((m - hf_) * 128.0f)
                    : (_Float16)(hf_ * 0.0078125f);
      }
      *(hf4*)&rw[e] = hv;
      *(hf4*)&rw[128 + e] = ov;
    }
  }
}

// ------ MFMA candidate kernel: B-stationary LDS, A global->reg, K=256 -------
// Block: 4 waves, each wave = 64i x 64j. 4 blocks/CU (35.8KB LDS, <=128 VGPR).
// 1D grid: b = bid&7 (batch->XCD), jb = (bid>>3)&(NJB-1), ib = (bid>>3)/NJB.
// Emits packed u64 top-2 per (row, 64-j chunk).
template <int WIDTH, int TT, int HH, int NJB>
__global__ __launch_bounds__(256, 4) void argmax_mfma6_kernel(
    const _Float16* __restrict__ ext, const float* __restrict__ swp,
    const float* __restrict__ dwp, unsigned long long* __restrict__ pu) {
  __shared__ _Float16 Bt[64][280];  // 35840 B; reused as reduce buffer
  const int bid = blockIdx.x;
  const int b = bid & 7;
  const int rr = bid >> 3;
  const int jb = rr & (NJB - 1);
  const int ib = rr / NJB;
  const int tid = threadIdx.x;
  const int w = tid >> 6, l = tid & 63;
  const int lg = l >> 4, lm = l & 15;
  const int ipan = ib * 256 + w * 64;
  const int j0 = jb * 64;
  const float sw = swp[0], dwv = dwp[0];
  const _Float16* extb = ext + (size_t)b * TT * 256;
  const _Float16* brow0 = extb + (size_t)(HH + j0) * 256;

  const _Float16* ap[4];
#pragma unroll
  for (int s = 0; s < 4; ++s)
    ap[s] = extb + (size_t)(ipan + s * 16 + lm) * 256 + lg * 8;

  // stage B tile once: 64 rows x 256 halfs
  for (int f = tid; f < 64 * 32; f += 256) {
    int r = f >> 5, c = f & 31;
    *(float4*)&Bt[r][c * 8] = *(const float4*)&brow0[(size_t)r * 256 + c * 8];
  }
  __syncthreads();

  fx4 acc[4][4];
#pragma unroll
  for (int i4 = 0; i4 < 4; ++i4)
#pragma unroll
    for (int j4 = 0; j4 < 4; ++j4) acc[i4][j4] = 0.f;

#pragma unroll
  for (int kc = 0; kc < 8; ++kc) {
    hf8 af[4], bf[4];
#pragma unroll
    for (int s = 0; s < 4; ++s)
      af[s] = *(const hf8*)(ap[s] + kc * 32);
#pragma unroll
    for (int s = 0; s < 4; ++s)
      bf[s] = *(const hf8*)&Bt[s * 16 + lm][kc * 32 + lg * 8];
    __builtin_amdgcn_s_setprio(1);
#pragma unroll
    for (int j4 = 0; j4 < 4; ++j4)
#pragma unroll
      for (int i4 = 0; i4 < 4; ++i4)
        acc[i4][j4] = __builtin_amdgcn_mfma_f32_16x16x32_f16(
            af[i4], bf[j4], acc[i4][j4], 0, 0, 0);
    __builtin_amdgcn_s_setprio(0);
  }

  // ---- epilogue: per-lane first-max over its 4 cols, per row ----
  // C/D layout: row = lg*4 + reg (+i4*16), col = lm (+j4*16).
  int jr4[4], jc4[4];
#pragma unroll
  for (int j4 = 0; j4 < 4; ++j4) {
    int tj = HH + j0 + j4 * 16 + lm;
    jr4[j4] = tj / WIDTH;
    jc4[j4] = tj % WIDTH;
  }
  __syncthreads();  // all waves done reading Bt -> reuse as reduce buffer
  unsigned long long* rwv = (unsigned long long*)&Bt[0][0] + (size_t)w * 64 * 17;
#pragma unroll
  for (int i4 = 0; i4 < 4; ++i4) {
#pragma unroll
    for (int rg = 0; rg < 4; ++rg) {
      int il = i4 * 16 + lg * 4 + rg;
      int ti = ipan + il;
      int ir = ti / WIDTH, ic = ti % WIDTH;
      float bv = -1e30f;
      int bj = 0;
#pragma unroll
      for (int j4 = 0; j4 < 4; ++j4) {  // ascending j -> first-max kept
        int dr = ir - jr4[j4], dc = ic - jc4[j4];
        float d2 = (float)(dr * dr + dc * dc);
        float sc = sw * acc[i4][j4][rg] + dwv * __builtin_amdgcn_rsqf(d2);
        int gj = j0 + j4 * 16 + lm;
        if (sc > bv) { bv = sc; bj = gj; }
      }
      rwv[il * 17 + lm] =
          ((unsigned long long)__float_as_uint(bv + 1.0f) << 32) |
          (unsigned)(~(unsigned)bj);
    }
  }
  __syncthreads();
  unsigned long long t1 = 0ull, t2 = 0ull;
#pragma unroll
  for (int c = 0; c < 16; ++c) {
    unsigned long long u = rwv[l * 17 + c];
    if (u > t1) { t2 = t1; t1 = u; }
    else if (u > t2) { t2 = u; }
  }
  size_t row = (size_t)b * HH + ipan + l;
  pu[row * (HH / 32) + jb * 2 + 0] = t1;
  pu[row * (HH / 32) + jb * 2 + 1] = t2;
}

// --- fused top-4 + exact fp32 refine + SCATTER: one wave per row ------------
// Computes first-argmax bj for its a-row, then atomically merges the raw
// a-row into accbuf[row bj] (+cnt). Replaces topkrefine + scatter kernels.
// 1D grid NB*HH/4: b = bid&7 (same-XCD as producer argmax -> pu L2-hot).
template <int WIDTH, int TT, int HH, int NCH2>
__global__ __launch_bounds__(256) void tkrscat_kernel(
    const unsigned long long* __restrict__ pu, const float* __restrict__ xf,
    const float* __restrict__ nrm, const float* __restrict__ swp,
    const float* __restrict__ dwp, float* __restrict__ accbuf,
    float* __restrict__ cnt) {
  const int bid = blockIdx.x;
  const int bb = bid & 7;
  const int row = bb * HH + (bid >> 3) * 4 + (threadIdx.x >> 6);
  const int lane = threadIdx.x & 63;
  // ---- top-4 candidates across chunks (packed u64 order) ----
  unsigned long long v = (lane < NCH2) ? pu[(size_t)row * NCH2 + lane] : 0ull;
  int candv[4];
#pragma unroll
  for (int t = 0; t < 4; ++t) {
    unsigned long long m = v;
#pragma unroll
    for (int off = 1; off < 64; off <<= 1) {
      unsigned long long o = __shfl_xor(m, off, 64);
      if (o > m) m = o;
    }
    candv[t] = (int)(~(unsigned)(m & 0xFFFFFFFFull));
    if (v == m) v = 0ull;  // packed u64 unique per j -> exact removal
  }
  // ---- exact fp32 scores for the 4 candidates; first-argmax semantics ----
  const int half = lane >> 5, ln = lane & 31;
  const int b = row / HH, i = row - b * HH;
  const float sw = swp[0], dwv = dwp[0];
  const float na = nrm[b * TT + i];
  float4 araw = *(const float4*)&xf[((size_t)b * TT + i) * NC + ln * 4];
  float4 a4 = make_float4(araw.x / na, araw.y / na, araw.z / na, araw.w / na);
  const int ir = i / WIDTH, ic = i % WIDTH;
  float bv = -3.0e38f;
  int bj = 0x7fffffff;
#pragma unroll
  for (int c = 0; c < 4; c += 2) {
    int j = candv[c + half];
    float4 b4 = *(const float4*)&xf[((size_t)b * TT + HH + j) * NC + ln * 4];
    float p = a4.x * b4.x + a4.y * b4.y + a4.z * b4.z + a4.w * b4.w;
#pragma unroll
    for (int off = 1; off < 32; off <<= 1) p += __shfl_xor(p, off, 32);
    float nb = nrm[b * TT + HH + j];
    int tj = HH + j;
    int jr = tj / WIDTH;
    int dr = ir - jr, dc = ic - (tj - jr * WIDTH);
    float r = 1.0f / (sqrtf((float)(dr * dr + dc * dc)) + 1e-6f);
    float sc = sw * (p / nb) + dwv * r;
    if (sc > bv || (sc == bv && j < bj)) { bv = sc; bj = j; }
  }
  {
    float ov = __shfl_xor(bv, 32, 64);
    int oj = __shfl_xor(bj, 32, 64);
    if (ov > bv || (ov == bv && oj < bj)) { bv = ov; bj = oj; }
  }
  // ---- scatter (half 0 lanes carry the full 128-float row) ----
  if (half == 0) {
    float* base = &accbuf[((size_t)b * HH + bj) * NC + ln * 4];
    atomicAdd(base + 0, araw.x);
    atomicAdd(base + 1, araw.y);
    atomicAdd(base + 2, araw.z);
    atomicAdd(base + 3, araw.w);
    if (ln == 0) atomicAdd(&cnt[(size_t)b * HH + bj], 1.0f);
  }
}

// ---------------- FALLBACK fp32 path (round-1 structure, proven) ------------
template <int WIDTH, int TT, int HH, int IT, int JC>
__global__ __launch_bounds__(256, 4) void argmax2_kernel(
    const float* __restrict__ xf, const float* __restrict__ nrm,
    const float* __restrict__ swp, const float* __restrict__ lut,
    float* __restrict__ pval, int* __restrict__ pidx) {
  constexpr int MI = IT / 16;
  constexpr int NTILE = JC / 128;
  __shared__ float At[32][IT + 4];
  __shared__ float Bt[32][132];
  __shared__ int ico[2][IT];
  __shared__ int jco[2][JC];

  const int b = blockIdx.z;
  const int it0 = blockIdx.x * IT;
  const int jb = blockIdx.y;
  const int j0g = jb * JC;
  const int tid = threadIdx.x;

  for (int t = tid; t < IT; t += 256) {
    int tok = it0 + t;
    ico[0][t] = tok / WIDTH;
    ico[1][t] = tok % WIDTH;
  }
  for (int t = tid; t < JC; t += 256) {
    int tok = HH + j0g + t;
    jco[0][t] = tok / WIDTH;
    jco[1][t] = tok % WIDTH;
  }
  const float sw = swp[0];
  const float* srcb = xf + (size_t)b * TT * NC;

  const int ty = tid >> 4, tx = tid & 15;
  const int i0l = ty * MI;
  const int j0l = tx * 8;

  float best[MI];
  int bidx[MI];
#pragma unroll
  for (int ii = 0; ii < MI; ++ii) { best[ii] = -1e30f; bidx[ii] = 0; }

  for (int jt = 0; jt < NTILE; ++jt) {
    float acc[MI][8];
#pragma unroll
    for (int ii = 0; ii < MI; ++ii)
#pragma unroll
      for (int jj = 0; jj < 8; ++jj) acc[ii][jj] = 0.f;

    for (int kc = 0; kc < 4; ++kc) {
      __syncthreads();
#pragma unroll
      for (int p = 0; p < IT / 32; ++p) {
        int f = p * 256 + tid;
        int r = f >> 3, kq = (f & 7) * 4;
        const float* row = srcb + (size_t)(it0 + r) * NC + kc * 32 + kq;
        float4 v = *(const float4*)row;
        float n = nrm[b * TT + it0 + r];
        v.x /= n; v.y /= n; v.z /= n; v.w /= n;
        At[kq + 0][r] = v.x; At[kq + 1][r] = v.y;
        At[kq + 2][r] = v.z; At[kq + 3][r] = v.w;
      }
#pragma unroll
      for (int p = 0; p < 4; ++p) {
        int f = p * 256 + tid;
        int r = f >> 3, kq = (f & 7) * 4;
        int tok = HH + j0g + jt * 128 + r;
        const float* row = srcb + (size_t)tok * NC + kc * 32 + kq;
        float4 v = *(const float4*)row;
        float n = nrm[b * TT + tok];
        v.x /= n; v.y /= n; v.z /= n; v.w /= n;
        Bt[kq + 0][r] = v.x; Bt[kq + 1][r] = v.y;
        Bt[kq + 2][r] = v.z; Bt[kq + 3][r] = v.w;
      }
      __syncthreads();

#pragma unroll 4
      for (int k = 0; k < 32; ++k) {
        float a[MI], bb[8];
#pragma unroll
        for (int qv = 0; qv < MI / 4; ++qv)
          *(float4*)&a[qv * 4] = *(const float4*)&At[k][i0l + qv * 4];
        *(float4*)&bb[0] = *(const float4*)&Bt[k][j0l];
        *(float4*)&bb[4] = *(const float4*)&Bt[k][j0l + 4];
#pragma unroll
        for (int ii = 0; ii < MI; ++ii)
#pragma unroll
          for (int jj = 0; jj < 8; ++jj) acc[ii][jj] += a[ii] * bb[jj];
      }
    }

#pragma unroll
    for (int ii = 0; ii < MI; ++ii) {
      int ir = ico[0][i0l + ii], ic = ico[1][i0l + ii];
#pragma unroll
      for (int jj = 0; jj < 8; ++jj) {
        int jl = jt * 128 + j0l + jj;
        int dr = ir - jco[0][jl];
        int dc = ic - jco[1][jl];
        float sc = sw * acc[ii][jj] + lut[dr * dr + dc * dc];
        if (sc > best[ii]) {
          best[ii] = sc;
          bidx[ii] = j0g + jl;
        }
      }
    }
  }

  __syncthreads();
  float* rv = &At[0][0];
  int* rj = (int*)&Bt[0][0];
#pragma unroll
  for (int ii = 0; ii < MI; ++ii) {
    rv[(i0l + ii) * 17 + tx] = best[ii];
    rj[(i0l + ii) * 17 + tx] = bidx[ii];
  }
  __syncthreads();
  if (tid < IT) {
    float bv = rv[tid * 17];
    int bj = rj[tid * 17];
    for (int t = 1; t < 16; ++t) {
      float v = rv[tid * 17 + t];
      int j = rj[tid * 17 + t];
      if (v > bv || (v == bv && j < bj)) { bv = v; bj = j; }
    }
    int row = b * HH + it0 + tid;
    pval[(size_t)row * 8 + jb] = bv;
    pidx[(size_t)row * 8 + jb] = bj;
  }
}

__global__ void argreduce_kernel(const float* __restrict__ pv,
                                 const int* __restrict__ pj,
                                 int* __restrict__ dst, int nrows, int w) {
  int r = blockIdx.x * 256 + threadIdx.x;
  if (r >= nrows) return;
  const float* vv = pv + (size_t)r * w;
  const int* jj = pj + (size_t)r * w;
  float bv = vv[0];
  int bj = jj[0];
  for (int t = 1; t < w; ++t) {
    float v = vv[t];
    int j = jj[t];
    if (v > bv || (v == bv && j < bj)) { bv = v; bj = j; }
  }
  dst[r] = bj;
}

// fallback scatter (uses precomputed dst)
__global__ void scatter_kernel(const float* __restrict__ src,
                               const int* __restrict__ dst,
                               float* __restrict__ accbuf,
                               float* __restrict__ cnt, int HH, int TT) {
  const int b = blockIdx.x & 7;
  size_t local = (size_t)(blockIdx.x >> 3) * 256 + threadIdx.x;
  if (local >= (size_t)HH * 32) return;
  int i = (int)(local >> 5);
  int e = (int)(local & 31) * 4;
  float4 v = *(const float4*)&src[((size_t)b * TT + i) * NC + e];
  int d = dst[(size_t)b * HH + i];
  float* base = &accbuf[((size_t)b * HH + d) * NC + e];
  atomicAdd(base + 0, v.x);
  atomicAdd(base + 1, v.y);
  atomicAdd(base + 2, v.z);
  atomicAdd(base + 3, v.w);
  if (e == 0) atomicAdd(&cnt[(size_t)b * HH + d], 1.0f);
}

// finalize merge-1: divide xf2 by cnt1, emit nrm2 (+ ext2 rows, K=256 enc),
// AND init merge-2 accumulator: b-half rows (t>=1024) copied to xf3, cnt2=1.
// 1D grid 8192, b = bid&7; rows per batch = 2048.
__global__ void finalize1_kernel(float* __restrict__ buf,
                                 const float* __restrict__ cnt,
                                 float* __restrict__ nrm,
                                 _Float16* __restrict__ ext,
                                 float* __restrict__ xf3,
                                 float* __restrict__ cnt2) {
  const int b = blockIdx.x & 7;
  int row = b * 2048 + (blockIdx.x >> 3) * 2 + (threadIdx.x >> 7);
  int c = threadIdx.x & 127;
  float v = buf[(size_t)row * NC + c] / cnt[row];
  buf[(size_t)row * NC + c] = v;
  int t = row & 2047;
  if (t >= 1024) {  // merge-2 accumulator init (replaces copy_init m2)
    size_t r3 = (size_t)b * 1024 + t - 1024;
    xf3[r3 * NC + c] = v;
    if (c == 0) cnt2[r3] = 1.0f;
  }
  {
    float s = v * v;
    for (int off = 32; off > 0; off >>= 1) s += __shfl_down(s, off, 64);
    __shared__ float p[4];
    __shared__ float ns[2];
    int w = threadIdx.x >> 6;
    if ((threadIdx.x & 63) == 0) p[w] = s;
    __syncthreads();
    if ((threadIdx.x & 127) == 0) {
      float n = sqrtf(p[w] + p[w + 1]);
      nrm[row] = n;
      ns[threadIdx.x >> 7] = n;
    }
    __syncthreads();
    if (ext != nullptr) {
      float n = ns[threadIdx.x >> 7];
      float m = v / n;
      _Float16 h = (_Float16)m;
      float hf = (float)h;
      _Float16 ep = (_Float16)((m - hf) * 128.0f);
      _Float16 hs = (_Float16)(hf * 0.0078125f);
      bool isA = t < 1024;
      _Float16* rw = ext + (size_t)row * 256;
      rw[c] = h;
      rw[128 + c] = isA ? ep : hs;
    }
  }
}

// --- 1x1 conv (128x128) + BN + SiLU, with fused cnt2-divide (finalize m2) ---
// 1D grid 128: b = bid&7, p0 = (bid>>3)*64.
__global__ __launch_bounds__(256) void conv_bn_silu_kernel(
    const float* __restrict__ xf3, const float* __restrict__ cnt2,
    const float* __restrict__ w, const float* __restrict__ gamma,
    const float* __restrict__ beta, const float* __restrict__ mean,
    const float* __restrict__ var, float* __restrict__ out) {
  __shared__ float X[64][132];
  __shared__ float Wt[128][68];
  const int b = blockIdx.x & 7, p0 = (blockIdx.x >> 3) * 64;
  const int tid = threadIdx.x, lane = tid & 63, q = tid >> 6;
  {
    const float cn = cnt2[(size_t)b * 1024 + p0 + lane];
    const float* row = xf3 + ((size_t)b * 1024 + p0 + lane) * NC;
    for (int cc = 0; cc < 8; ++cc) {
      int c = q * 32 + cc * 4;
      float4 v = *(const float4*)&row[c];
      X[lane][c + 0] = v.x / cn;
      X[lane][c + 1] = v.y / cn;
      X[lane][c + 2] = v.z / cn;
      X[lane][c + 3] = v.w / cn;
    }
  }
  const int ti = tid >> 4, tj = tid & 15;
  const int i4 = ti * 4, j4 = tj * 4;
  for (int ot = 0; ot < 2; ++ot) {
    __syncthreads();
    {
      const float* row = w + (size_t)(ot * 64 + lane) * NC;
      for (int cc = 0; cc < 8; ++cc) {
        int c = q * 32 + cc * 4;
        float4 v = *(const float4*)&row[c];
        Wt[c + 0][lane] = v.x;
        Wt[c + 1][lane] = v.y;
        Wt[c + 2][lane] = v.z;
        Wt[c + 3][lane] = v.w;
      }
    }
    __syncthreads();
    float acc[4][4];
#pragma unroll
    for (int ii = 0; ii < 4; ++ii)
#pragma unroll
      for (int jj = 0; jj < 4; ++jj) acc[ii][jj] = 0.f;

    for (int k = 0; k < NC; k += 4) {
      float4 a0 = *(const float4*)&X[i4 + 0][k];
      float4 a1 = *(const float4*)&X[i4 + 1][k];
      float4 a2 = *(const float4*)&X[i4 + 2][k];
      float4 a3 = *(const float4*)&X[i4 + 3][k];
      float4 b0 = *(const float4*)&Wt[k + 0][j4];
      float4 b1 = *(const float4*)&Wt[k + 1][j4];
      float4 b2 = *(const float4*)&Wt[k + 2][j4];
      float4 b3 = *(const float4*)&Wt[k + 3][j4];
#define FMA16(AX, BV)                                                     \
  acc[0][0] += a0.AX * BV.x; acc[0][1] += a0.AX * BV.y;                   \
  acc[0][2] += a0.AX * BV.z; acc[0][3] += a0.AX * BV.w;                   \
  acc[1][0] += a1.AX * BV.x; acc[1][1] += a1.AX * BV.y;                   \
  acc[1][2] += a1.AX * BV.z; acc[1][3] += a1.AX * BV.w;                   \
  acc[2][0] += a2.AX * BV.x; acc[2][1] += a2.AX * BV.y;                   \
  acc[2][2] += a2.AX * BV.z; acc[2][3] += a2.AX * BV.w;                   \
  acc[3][0] += a3.AX * BV.x; acc[3][1] += a3.AX * BV.y;                   \
  acc[3][2] += a3.AX * BV.z; acc[3][3] += a3.AX * BV.w;
      FMA16(x, b0)
      FMA16(y, b1)
      FMA16(z, b2)
      FMA16(w, b3)
#undef FMA16
    }

#pragma unroll
    for (int jj = 0; jj < 4; ++jj) {
      int o = ot * 64 + j4 + jj;
      float sc = gamma[o] / sqrtf(var[o] + 1e-5f);
      float mn = mean[o], bt = beta[o];
      float4 r;
      float z;
      z = (acc[0][jj] - mn) * sc + bt; r.x = z / (1.f + expf(-z));
      z = (acc[1][jj] - mn) * sc + bt; r.y = z / (1.f + expf(-z));
      z = (acc[2][jj] - mn) * sc + bt; r.z = z / (1.f + expf(-z));
      z = (acc[3][jj] - mn) * sc + bt; r.w = z / (1.f + expf(-z));
      *(float4*)&out[((size_t)(b * NC + o)) * 1024 + p0 + i4] = r;
    }
  }
}

extern "C" void kernel_launch(void* const* d_in, const int* in_sizes, int n_in,
                              void* d_out, int out_size, void* d_ws,
                              size_t ws_size, hipStream_t stream) {
  const float* x = (const float*)d_in[0];
  const float* swp = (const float*)d_in[1];
  const float* dwp = (const float*)d_in[2];
  const float* convw = (const float*)d_in[3];
  const float* gamma = (const float*)d_in[4];
  const float* beta = (const float*)d_in[5];
  const float* mean = (const float*)d_in[6];
  const float* var = (const float*)d_in[7];
  float* out = (float*)d_out;

  float* ws = (float*)d_ws;
  size_t o = 0;
  float* xf1 = ws + o;  o += (size_t)8 * 4096 * 128;  // reused as xf3
  float* nrm1 = ws + o; o += 8 * 4096;
  float* xf2 = ws + o;  o += (size_t)8 * 2048 * 128;
  float* nrm2 = ws + o; o += 8 * 2048;
  float* cnt1 = ws + o; o += 8 * 2048;
  float* cnt2 = ws + o; o += 8 * 1024;
  int* dst1 = (int*)(ws + o); o += 8 * 2048;        // fallback only
  int* dst2 = (int*)(ws + o); o += 8 * 1024;        // fallback only
  float* lut = ws + o;  o += 8192;                  // fallback only
  unsigned long long* pu1 = (unsigned long long*)(ws + o);
  o += (size_t)8 * 2048 * 64 * 2;                   // 16384 rows x 64 u64
  unsigned long long* pu2 = (unsigned long long*)(ws + o);
  o += (size_t)8 * 1024 * 32 * 2;                   // 8192 rows x 32 u64
  _Float16* ext1 = (_Float16*)(ws + o);
  _Float16* ext2 = ext1;  // ext1 dead after merge-1 candidate pass
  const size_t ext_floats = (size_t)8 * 4096 * 256 / 2;
  const bool mfma_ok = ws_size >= (o + ext_floats) * sizeof(float);
  float* xf3 = xf1;  // alias: xf1 dead (tkrscat1 done) before xf3 written
  // fallback pv/pj alias the (unused-in-fallback) pu regions
  float* pv1 = (float*)pu1;
  int* pj1 = (int*)(pv1 + 8 * 2048 * 8);
  float* pv2 = (float*)pu2;
  int* pj2 = (int*)(pv2 + 8 * 1024 * 8);

  // ---- merge 1: T=4096, H=2048, width=64 ----
  prep_kernel<<<512, 256, 0, stream>>>(x, xf1, nrm1, mfma_ok ? ext1 : nullptr,
                                       xf2, cnt1);
  if (mfma_ok) {
    argmax_mfma6_kernel<64, 4096, 2048, 32>
        <<<2048, 256, 0, stream>>>(ext1, swp, dwp, pu1);
    tkrscat_kernel<64, 4096, 2048, 64>
        <<<4096, 256, 0, stream>>>(pu1, xf1, nrm1, swp, dwp, xf2, cnt1);
  } else {
    lut_kernel<<<32, 256, 0, stream>>>(lut, dwp, 7939);
    argmax2_kernel<64, 4096, 2048, 128, 256>
        <<<dim3(16, 8, 8), 256, 0, stream>>>(xf1, nrm1, swp, lut, pv1, pj1);
    argreduce_kernel<<<64, 256, 0, stream>>>(pv1, pj1, dst1, 8 * 2048, 8);
    scatter_kernel<<<2048, 256, 0, stream>>>(xf1, dst1, xf2, cnt1, 2048, 4096);
  }
  finalize1_kernel<<<8192, 256, 0, stream>>>(xf2, cnt1, nrm2,
                                             mfma_ok ? ext2 : nullptr,
                                             xf3, cnt2);

  // ---- merge 2: T=2048, H=1024, width=int(sqrt(2048))=45 ----
  if (mfma_ok) {
    argmax_mfma6_kernel<45, 2048, 1024, 16>
        <<<512, 256, 0, stream>>>(ext2, swp, dwp, pu2);
    tkrscat_kernel<45, 2048, 1024, 32>
        <<<2048, 256, 0, stream>>>(pu2, xf2, nrm2, swp, dwp, xf3, cnt2);
  } else {
    argmax2_kernel<45, 2048, 1024, 64, 128>
        <<<dim3(16, 8, 8), 256, 0, stream>>>(xf2, nrm2, swp, lut, pv2, pj2);
    argreduce_kernel<<<32, 256, 0, stream>>>(pv2, pj2, dst2, 8 * 1024, 8);
    scatter_kernel<<<1024, 256, 0, stream>>>(xf2, dst2, xf3, cnt2, 1024, 2048);
  }

  // ---- 1x1 conv + BN + SiLU (divides by cnt2 on load) ----
  conv_bn_silu_kernel<<<128, 256, 0, stream>>>(
      xf3, cnt2, convw, gamma, beta, mean, var, out);
}